// Round 9
// baseline (10988.749 us; speedup 1.0000x reference)
//
#include <hip/hip_runtime.h>
#include <stdint.h>
#include <math.h>

#define NBATCH 16
#define NNODE 207
#define TLEN 23990
#define EMBD 100
#define L1LEN 23981   // T-9
#define L2LEN 23972   // T-18
#define DIMFC 383552  // 16*L2
#define DMEAN 16128   // P*D
#define NSQ 42849     // N*N
#define KSEL 2070     // K*N
#define BNEPS 1e-5f

// output offsets (floats)
#define O_HID  1371168ull
#define O_KNN  54787104ull
#define O_SAMP 55472688ull

__device__ __forceinline__ float waveReduce(float v) {
#pragma unroll
  for (int o = 32; o > 0; o >>= 1) v += __shfl_down(v, o);
  return v;
}

__device__ __forceinline__ double waveReduceD(double v) {
#pragma unroll
  for (int o = 32; o > 0; o >>= 1) v += __shfl_down(v, o);
  return v;
}

__device__ __forceinline__ unsigned int sortableKey(float f) {
  unsigned int u = __float_as_uint(f);
  return (u & 0x80000000u) ? ~u : (u | 0x80000000u);
}

// JAX threefry2x32-20 with key (0, 42)
__device__ __forceinline__ void threefry(uint32_t x0, uint32_t x1, uint32_t& o0, uint32_t& o1) {
  const uint32_t k0 = 0u, k1 = 42u;
  const uint32_t k2 = k0 ^ k1 ^ 0x1BD11BDAu;
  x0 += k0; x1 += k1;
#define TFR(r) { x0 += x1; x1 = (x1 << r) | (x1 >> (32 - r)); x1 ^= x0; }
  TFR(13) TFR(15) TFR(26) TFR(6)   x0 += k1; x1 += k2 + 1u;
  TFR(17) TFR(29) TFR(16) TFR(24)  x0 += k2; x1 += k0 + 2u;
  TFR(13) TFR(15) TFR(26) TFR(6)   x0 += k0; x1 += k1 + 3u;
  TFR(17) TFR(29) TFR(16) TFR(24)  x0 += k1; x1 += k2 + 4u;
  TFR(13) TFR(15) TFR(26) TFR(6)   x0 += k2; x1 += k0 + 5u;
#undef TFR
  o0 = x0; o1 = x1;
}

// jax_threefry_partitionable bit stream: element i -> threefry(key,(0,i)), XOR-fold.
__device__ __forceinline__ float uniform_part(uint32_t m) {
  uint32_t o0, o1;
  threefry(0u, m, o0, o1);
  uint32_t bits = o0 ^ o1;
  return __uint_as_float((bits >> 9) | 0x3f800000u) - 1.0f;
}

// ---------------- K9: copy hidden -> out, row sumsq -> norms ----------------
__global__ __launch_bounds__(256) void k_copynorm(const float* __restrict__ h,
                                                  float* __restrict__ out,
                                                  float* __restrict__ norms) {
  const size_t row = blockIdx.x; // 0..3311
  const float4* src = reinterpret_cast<const float4*>(h + row * (size_t)DMEAN);
  float4* dst = reinterpret_cast<float4*>(out + O_HID + row * (size_t)DMEAN);
  float s = 0.f;
  for (int i = threadIdx.x; i < DMEAN / 4; i += 256) {
    float4 v = src[i];
    dst[i] = v;
    s += v.x * v.x + v.y * v.y + v.z * v.z + v.w * v.w;
  }
  __shared__ float red[4];
  float w = waveReduce(s);
  if ((threadIdx.x & 63) == 0) red[threadIdx.x >> 6] = w;
  __syncthreads();
  if (threadIdx.x == 0) norms[row] = sqrtf(red[0] + red[1] + red[2] + red[3]);
}

// ---------------- K10: sim = hn @ hn^T per batch (64x64 tiles, K-chunk 32) ----------------
__global__ __launch_bounds__(256) void k_sim(const float* __restrict__ h,
                                             const float* __restrict__ norms,
                                             float* __restrict__ sim) {
  const int b = blockIdx.y;
  const int ti = blockIdx.x >> 2, tj = blockIdx.x & 3;
  __shared__ float sA[32][64], sB[32][64];
  __shared__ float dA[64], dB[64];
  if (threadIdx.x < 64) {
    int n = ti * 64 + threadIdx.x;
    dA[threadIdx.x] = (n < NNODE) ? (norms[b * NNODE + n] + 1e-10f) : 1.f;
  } else if (threadIdx.x < 128) {
    int tl = threadIdx.x - 64;
    int n = tj * 64 + tl;
    dB[tl] = (n < NNODE) ? (norms[b * NNODE + n] + 1e-10f) : 1.f;
  }
  __syncthreads();
  float acc[4][4];
#pragma unroll
  for (int p = 0; p < 4; p++)
#pragma unroll
    for (int q = 0; q < 4; q++) acc[p][q] = 0.f;
  const int tx = threadIdx.x & 15, ty = threadIdx.x >> 4;
  const int r = threadIdx.x >> 2, c4 = threadIdx.x & 3;
  const float* hb = h + (size_t)b * NNODE * DMEAN;
  for (int k0 = 0; k0 < DMEAN; k0 += 32) {
    __syncthreads();
    {
      int n = ti * 64 + r;
      float4 v1 = make_float4(0.f, 0.f, 0.f, 0.f), v2 = v1;
      if (n < NNODE) {
        v1 = *reinterpret_cast<const float4*>(&hb[(size_t)n * DMEAN + k0 + c4 * 4]);
        v2 = *reinterpret_cast<const float4*>(&hb[(size_t)n * DMEAN + k0 + 16 + c4 * 4]);
      }
      float d = dA[r];
      sA[c4 * 4 + 0][r] = v1.x / d;
      sA[c4 * 4 + 1][r] = v1.y / d;
      sA[c4 * 4 + 2][r] = v1.z / d;
      sA[c4 * 4 + 3][r] = v1.w / d;
      sA[16 + c4 * 4 + 0][r] = v2.x / d;
      sA[16 + c4 * 4 + 1][r] = v2.y / d;
      sA[16 + c4 * 4 + 2][r] = v2.z / d;
      sA[16 + c4 * 4 + 3][r] = v2.w / d;
      int n2 = tj * 64 + r;
      float4 u1 = make_float4(0.f, 0.f, 0.f, 0.f), u2 = u1;
      if (n2 < NNODE) {
        u1 = *reinterpret_cast<const float4*>(&hb[(size_t)n2 * DMEAN + k0 + c4 * 4]);
        u2 = *reinterpret_cast<const float4*>(&hb[(size_t)n2 * DMEAN + k0 + 16 + c4 * 4]);
      }
      float d2 = dB[r];
      sB[c4 * 4 + 0][r] = u1.x / d2;
      sB[c4 * 4 + 1][r] = u1.y / d2;
      sB[c4 * 4 + 2][r] = u1.z / d2;
      sB[c4 * 4 + 3][r] = u1.w / d2;
      sB[16 + c4 * 4 + 0][r] = u2.x / d2;
      sB[16 + c4 * 4 + 1][r] = u2.y / d2;
      sB[16 + c4 * 4 + 2][r] = u2.z / d2;
      sB[16 + c4 * 4 + 3][r] = u2.w / d2;
    }
    __syncthreads();
#pragma unroll
    for (int kk = 0; kk < 32; kk++) {
      float4 av = *reinterpret_cast<const float4*>(&sA[kk][ty * 4]);
      float4 bv = *reinterpret_cast<const float4*>(&sB[kk][tx * 4]);
      acc[0][0] = fmaf(av.x, bv.x, acc[0][0]);
      acc[0][1] = fmaf(av.x, bv.y, acc[0][1]);
      acc[0][2] = fmaf(av.x, bv.z, acc[0][2]);
      acc[0][3] = fmaf(av.x, bv.w, acc[0][3]);
      acc[1][0] = fmaf(av.y, bv.x, acc[1][0]);
      acc[1][1] = fmaf(av.y, bv.y, acc[1][1]);
      acc[1][2] = fmaf(av.y, bv.z, acc[1][2]);
      acc[1][3] = fmaf(av.y, bv.w, acc[1][3]);
      acc[2][0] = fmaf(av.z, bv.x, acc[2][0]);
      acc[2][1] = fmaf(av.z, bv.y, acc[2][1]);
      acc[2][2] = fmaf(av.z, bv.z, acc[2][2]);
      acc[2][3] = fmaf(av.z, bv.w, acc[2][3]);
      acc[3][0] = fmaf(av.w, bv.x, acc[3][0]);
      acc[3][1] = fmaf(av.w, bv.y, acc[3][1]);
      acc[3][2] = fmaf(av.w, bv.z, acc[3][2]);
      acc[3][3] = fmaf(av.w, bv.w, acc[3][3]);
    }
  }
#pragma unroll
  for (int p = 0; p < 4; p++) {
    int ii = ti * 64 + ty * 4 + p;
    if (ii < NNODE) {
#pragma unroll
      for (int q = 0; q < 4; q++) {
        int jj = tj * 64 + tx * 4 + q;
        if (jj < NNODE) sim[(size_t)b * NSQ + ii * NNODE + jj] = acc[p][q];
      }
    }
  }
}

// ---------------- K11: exact top-k (radix select + index-ordered tie fill), 1024 thr ----------------
__global__ __launch_bounds__(1024) void k_topk(const float* __restrict__ sim,
                                               float* __restrict__ out) {
  const int b = blockIdx.x;
  const float* s = sim + (size_t)b * NSQ;
  float* knn = out + O_KNN + (size_t)b * NSQ;
  __shared__ unsigned int hist[256];
  __shared__ unsigned int cnts[1024];
  __shared__ unsigned int sh_prefix, sh_kneed;
  if (threadIdx.x == 0) { sh_prefix = 0u; sh_kneed = KSEL; }
  __syncthreads();
  const int lo = threadIdx.x * 42;
  const int hi = min(lo + 42, NSQ);
  for (int pass = 0; pass < 4; pass++) {
    const int shift = 24 - pass * 8;
    if (threadIdx.x < 256) hist[threadIdx.x] = 0u;
    __syncthreads();
    unsigned int pref = sh_prefix;
    unsigned int hmask = (pass == 0) ? 0u : (0xFFFFFFFFu << (shift + 8));
    for (int i = lo; i < hi; i++) {
      unsigned int key = sortableKey(s[i]);
      if ((key & hmask) == pref) atomicAdd(&hist[(key >> shift) & 255], 1u);
    }
    __syncthreads();
    if (threadIdx.x == 0) {
      unsigned int need = sh_kneed, cum = 0;
      for (int bkt = 255; bkt >= 0; bkt--) {
        unsigned int c = hist[bkt];
        if (cum + c >= need) {
          sh_prefix = pref | ((unsigned int)bkt << shift);
          sh_kneed = need - cum;
          break;
        }
        cum += c;
      }
    }
    __syncthreads();
  }
  const unsigned int kth = sh_prefix;
  const unsigned int need_eq = sh_kneed;
  unsigned int myeq = 0;
  for (int i = lo; i < hi; i++) {
    float v = s[i];
    unsigned int key = sortableKey(v);
    float o = 0.f;
    if (key > kth) {
      int ii = i / NNODE, jj = i - ii * NNODE;
      o = (v != 0.f && ii != jj) ? 1.f : 0.f;
    } else if (key == kth) {
      myeq++;
    }
    knn[i] = o;
  }
  cnts[threadIdx.x] = myeq;
  __syncthreads();
  if (threadIdx.x == 0) {
    unsigned int run = 0;
    for (int t = 0; t < 1024; t++) { unsigned int c = cnts[t]; cnts[t] = run; run += c; }
  }
  __syncthreads();
  unsigned int rank = cnts[threadIdx.x];
  for (int i = lo; i < hi && rank < need_eq; i++) {
    float v = s[i];
    if (sortableKey(v) == kth) {
      if (rank < need_eq) {
        int ii = i / NNODE, jj = i - ii * NNODE;
        knn[i] = (v != 0.f && ii != jj) ? 1.f : 0.f;
      }
      rank++;
    }
  }
}

// ---------------- K1: conv1+relu stats partials ----------------
__global__ __launch_bounds__(256) void k_c1stats(const float* __restrict__ nf,
                                                 const float* __restrict__ c1w,
                                                 const float* __restrict__ c1b,
                                                 float* __restrict__ part1) {
  __shared__ float sw[80], sb[8];
  if (threadIdx.x < 80) sw[threadIdx.x] = c1w[threadIdx.x];
  if (threadIdx.x < 8) sb[threadIdx.x] = c1b[threadIdx.x];
  __syncthreads();
  const int t0 = blockIdx.x * 128;
  const int cnt = min(128, L1LEN - t0);
  float s[8], sq[8];
#pragma unroll
  for (int c = 0; c < 8; c++) { s[c] = 0.f; sq[c] = 0.f; }
  for (int idx = threadIdx.x; idx < cnt * NNODE; idx += 256) {
    int tl = idx / NNODE;
    int n = idx - tl * NNODE;
    const float* p = nf + (size_t)(t0 + tl) * NNODE + n;
    float in[10];
#pragma unroll
    for (int k = 0; k < 10; k++) in[k] = p[k * NNODE];
#pragma unroll
    for (int c = 0; c < 8; c++) {
      float a = sb[c];
#pragma unroll
      for (int k = 0; k < 10; k++) a = fmaf(sw[c * 10 + k], in[k], a);
      a = fmaxf(a, 0.f);
      s[c] += a;
      sq[c] = fmaf(a, a, sq[c]);
    }
  }
  __shared__ float red[4][16];
  int lane = threadIdx.x & 63, wv = threadIdx.x >> 6;
#pragma unroll
  for (int c = 0; c < 8; c++) {
    float a = waveReduce(s[c]);
    float q = waveReduce(sq[c]);
    if (lane == 0) { red[wv][c * 2] = a; red[wv][c * 2 + 1] = q; }
  }
  __syncthreads();
  if (threadIdx.x < 16)
    part1[blockIdx.x * 16 + threadIdx.x] =
        red[0][threadIdx.x] + red[1][threadIdx.x] + red[2][threadIdx.x] + red[3][threadIdx.x];
}

// ---------------- K2: reduce bn1 stats (f64) -> a1/be1 doubles ----------------
__global__ void k_red1(const float* __restrict__ part1, const float* __restrict__ g1,
                       const float* __restrict__ b1, double* __restrict__ foldd) {
  __shared__ double sums[16];
  if (threadIdx.x < 16) {
    double s = 0.0;
    for (int i = 0; i < 188; i++) s += (double)part1[i * 16 + threadIdx.x];
    sums[threadIdx.x] = s;
  }
  __syncthreads();
  if (threadIdx.x < 8) {
    const double cnt = 207.0 * 23981.0;
    int c = threadIdx.x;
    double m = sums[c * 2] / cnt;
    double ex2 = sums[c * 2 + 1] / cnt;
    double var = ex2 - m * m;
    double sc = (double)g1[c] / sqrt(var + (double)BNEPS);
    foldd[c] = sc;            // a1
    foldd[8 + c] = (double)b1[c] - m * sc;  // be1
  }
}

// ---------------- K3: conv2+relu stats partials ----------------
__global__ __launch_bounds__(256) void k_c2stats(const float* __restrict__ nf,
                                                 const float* __restrict__ c1w,
                                                 const float* __restrict__ c1b,
                                                 const float* __restrict__ c2w,
                                                 const float* __restrict__ c2b,
                                                 const double* __restrict__ foldd,
                                                 float* __restrict__ part2) {
  const int n = blockIdx.y;
  const int l0 = blockIdx.x * 1024;
  const int len = min(1024, L2LEN - l0);
  __shared__ float s_nf[1042];
  __shared__ float s_o1[8][1034];
  __shared__ float s_w2t[1280];
  __shared__ float s_b2[16];
  __shared__ float s_c1w[80], s_c1b[8];
  __shared__ float s_a1[8], s_be1[8];
  for (int i = threadIdx.x; i < 1280; i += 256) {
    int co = i / 80, r = i - co * 80;
    s_w2t[r * 16 + co] = c2w[i];
  }
  if (threadIdx.x < 16) s_b2[threadIdx.x] = c2b[threadIdx.x];
  if (threadIdx.x < 80) s_c1w[threadIdx.x] = c1w[threadIdx.x];
  if (threadIdx.x < 8) {
    s_c1b[threadIdx.x] = c1b[threadIdx.x];
    s_a1[threadIdx.x] = (float)foldd[threadIdx.x];
    s_be1[threadIdx.x] = (float)foldd[8 + threadIdx.x];
  }
  __syncthreads();
  const int nfl = len + 18;
  for (int i = threadIdx.x; i < nfl; i += 256) s_nf[i] = nf[(size_t)(l0 + i) * NNODE + n];
  __syncthreads();
  const int o1l = len + 9;
  for (int i = threadIdx.x; i < 8 * o1l; i += 256) {
    int c = i / o1l, t = i - c * o1l;
    float a = s_c1b[c];
#pragma unroll
    for (int k = 0; k < 10; k++) a = fmaf(s_c1w[c * 10 + k], s_nf[t + k], a);
    s_o1[c][t] = fmaxf(a, 0.f) * s_a1[c] + s_be1[c];
  }
  __syncthreads();
  const int co = threadIdx.x & 15, lg = threadIdx.x >> 4;
  float sum = 0.f, ssq = 0.f;
  for (int pass = 0; pass < 4; pass++) {
    int lb = pass * 256 + lg * 16;
    if (lb >= len) continue;
    int nl = min(16, len - lb);
    float y[16];
#pragma unroll
    for (int l = 0; l < 16; l++) y[l] = s_b2[co];
#pragma unroll
    for (int ci = 0; ci < 8; ci++) {
      float win[25];
#pragma unroll
      for (int w = 0; w < 25; w++) win[w] = s_o1[ci][lb + w];
#pragma unroll
      for (int k = 0; k < 10; k++) {
        float wv = s_w2t[(ci * 10 + k) * 16 + co];
#pragma unroll
        for (int l = 0; l < 16; l++) y[l] = fmaf(wv, win[l + k], y[l]);
      }
    }
#pragma unroll
    for (int l = 0; l < 16; l++) {
      if (l < nl) {
        float v = fmaxf(y[l], 0.f);
        sum += v;
        ssq = fmaf(v, v, ssq);
      }
    }
  }
  __shared__ float rs[16][16], rq[16][16];
  rs[lg][co] = sum;
  rq[lg][co] = ssq;
  __syncthreads();
  if (threadIdx.x < 16) {
    float a = 0.f, q = 0.f;
    for (int g = 0; g < 16; g++) { a += rs[g][threadIdx.x]; q += rq[g][threadIdx.x]; }
    int blk = blockIdx.y * gridDim.x + blockIdx.x;
    part2[blk * 32 + threadIdx.x * 2] = a;
    part2[blk * 32 + threadIdx.x * 2 + 1] = q;
  }
}

// ---------------- K4: reduce bn2 stats (f64) -> s2/t2 doubles ----------------
__global__ void k_red2(const float* __restrict__ part2, const float* __restrict__ g2,
                       const float* __restrict__ b2, double* __restrict__ foldd) {
  __shared__ double acc8[8][32];
  const int grp = threadIdx.x >> 5, v = threadIdx.x & 31;
  double s = 0.0;
  for (int i = grp; i < 4968; i += 8) s += (double)part2[i * 32 + v];
  acc8[grp][v] = s;
  __syncthreads();
  if (threadIdx.x < 32) {
    double t = 0.0;
    for (int g = 0; g < 8; g++) t += acc8[g][threadIdx.x];
    acc8[0][threadIdx.x] = t;
  }
  __syncthreads();
  if (threadIdx.x < 16) {
    const double cnt = 207.0 * 23972.0;
    int c = threadIdx.x;
    double m = acc8[0][c * 2] / cnt;
    double ex2 = acc8[0][c * 2 + 1] / cnt;
    double var = ex2 - m * m;
    double sc = (double)g2[c] / sqrt(var + (double)BNEPS);
    foldd[16 + c] = sc;                       // s2
    foldd[32 + c] = (double)b2[c] - m * sc;   // t2
  }
}

// ---------------- K5: fused conv1->conv2->bn2->fc GEMM (fc weights from global, 3 barriers/ls) ----------------
__global__ __launch_bounds__(512, 2) void k_gemm(const float* __restrict__ nf,
                                                 const float* __restrict__ c1w,
                                                 const float* __restrict__ c1b,
                                                 const float* __restrict__ c2w,
                                                 const float* __restrict__ c2b,
                                                 const double* __restrict__ foldd,
                                                 const float* __restrict__ fcw,
                                                 float* __restrict__ part) {
  const int ks = blockIdx.x;  // 0..93 l-chunk of 256
  const int nt = blockIdx.y;  // 0..3  n-tile of 52
  const int l0 = ks * 256;
  const int n0 = nt * 52;

  __shared__ float s_nf[26][56];
  __shared__ float s_o1[8][17][56];   // bn1-applied conv1 (f32)
  __shared__ float s_x2[16][8][64];   // bn2-applied conv2 (f32)
  __shared__ float s_w2t[1280];
  __shared__ float s_c1w[80], s_c1b[8], s_c2b[16];
  __shared__ float s_a1f[8], s_be1f[8], s_s2f[16], s_t2f[16];

  for (int i = threadIdx.x; i < 1280; i += 512) {
    int co = i / 80, r = i - co * 80;
    s_w2t[r * 16 + co] = c2w[i];
  }
  if (threadIdx.x < 80) s_c1w[threadIdx.x] = c1w[threadIdx.x];
  if (threadIdx.x < 8) {
    s_c1b[threadIdx.x] = c1b[threadIdx.x];
    s_a1f[threadIdx.x] = (float)foldd[threadIdx.x];
    s_be1f[threadIdx.x] = (float)foldd[8 + threadIdx.x];
  }
  if (threadIdx.x < 16) {
    s_c2b[threadIdx.x] = c2b[threadIdx.x];
    s_s2f[threadIdx.x] = (float)foldd[16 + threadIdx.x];
    s_t2f[threadIdx.x] = (float)foldd[32 + threadIdx.x];
  }

  double acc[7][2];
#pragma unroll
  for (int m = 0; m < 7; m++)
#pragma unroll
    for (int q = 0; q < 2; q++) acc[m][q] = 0.0;

  const int te = threadIdx.x & 15;   // e-lane
  const int tn = threadIdx.x >> 4;   // 0..31
  const int nl = threadIdx.x & 63;   // conv2 node lane
  const int c0 = (threadIdx.x >> 6) & 7;  // conv2 co base

  for (int ls = 0; ls < 32; ls++) {
    const int lb = l0 + ls * 8;
    if (lb >= L2LEN) break;
    for (int i = threadIdx.x; i < 26 * 56; i += 512) {
      int r = i / 56, cc = i - r * 56;
      int t = lb + r, n = n0 + cc;
      float v = 0.f;
      if (t < TLEN && n < NNODE) v = nf[(size_t)t * NNODE + n];
      s_nf[r][cc] = v;
    }
    __syncthreads();
    // conv1 + bn1 (f32)
    for (int i = threadIdx.x; i < 8 * 17 * 56; i += 512) {
      int c = i / (17 * 56);
      int rem = i - c * 17 * 56;
      int t = rem / 56, n = rem - t * 56;
      float a = s_c1b[c];
#pragma unroll
      for (int k = 0; k < 10; k++) a = fmaf(s_c1w[c * 10 + k], s_nf[t + k][n], a);
      s_o1[c][t][n] = fmaxf(a, 0.f) * s_a1f[c] + s_be1f[c];
    }
    __syncthreads();
    // conv2 + relu + bn2 (f32, named scalars, shared 17-wide window)
    {
      const bool valid = (nl < 52) && (n0 + nl < NNODE);
      if (valid) {
        const float bA = s_c2b[c0], bB = s_c2b[c0 + 8];
        float y00 = bA, y01 = bA, y02 = bA, y03 = bA;
        float y10 = bA, y11 = bA, y12 = bA, y13 = bA;
        float y20 = bB, y21 = bB, y22 = bB, y23 = bB;
        float y30 = bB, y31 = bB, y32 = bB, y33 = bB;
        for (int ci = 0; ci < 8; ci++) {
          float ww0 = s_o1[ci][0][nl],  ww1 = s_o1[ci][1][nl],  ww2 = s_o1[ci][2][nl];
          float ww3 = s_o1[ci][3][nl],  ww4 = s_o1[ci][4][nl],  ww5 = s_o1[ci][5][nl];
          float ww6 = s_o1[ci][6][nl],  ww7 = s_o1[ci][7][nl],  ww8 = s_o1[ci][8][nl];
          float ww9 = s_o1[ci][9][nl],  wwa = s_o1[ci][10][nl], wwb = s_o1[ci][11][nl];
          float wwc = s_o1[ci][12][nl], wwd = s_o1[ci][13][nl], wwe = s_o1[ci][14][nl];
          float wwf = s_o1[ci][15][nl], wwg = s_o1[ci][16][nl];
          const float* wpA = &s_w2t[ci * 160 + c0];
          const float* wpB = wpA + 8;
          float v, u;
#define C2STEP(K, A0, A1, A2, A3, B0, B1, B2, B3)                                   \
          v = wpA[(K) * 16]; u = wpB[(K) * 16];                                     \
          y00 = fmaf(v, A0, y00); y01 = fmaf(v, A1, y01);                           \
          y02 = fmaf(v, A2, y02); y03 = fmaf(v, A3, y03);                           \
          y10 = fmaf(v, B0, y10); y11 = fmaf(v, B1, y11);                           \
          y12 = fmaf(v, B2, y12); y13 = fmaf(v, B3, y13);                           \
          y20 = fmaf(u, A0, y20); y21 = fmaf(u, A1, y21);                           \
          y22 = fmaf(u, A2, y22); y23 = fmaf(u, A3, y23);                           \
          y30 = fmaf(u, B0, y30); y31 = fmaf(u, B1, y31);                           \
          y32 = fmaf(u, B2, y32); y33 = fmaf(u, B3, y33);
          C2STEP(0, ww0, ww1, ww2, ww3, ww4, ww5, ww6, ww7)
          C2STEP(1, ww1, ww2, ww3, ww4, ww5, ww6, ww7, ww8)
          C2STEP(2, ww2, ww3, ww4, ww5, ww6, ww7, ww8, ww9)
          C2STEP(3, ww3, ww4, ww5, ww6, ww7, ww8, ww9, wwa)
          C2STEP(4, ww4, ww5, ww6, ww7, ww8, ww9, wwa, wwb)
          C2STEP(5, ww5, ww6, ww7, ww8, ww9, wwa, wwb, wwc)
          C2STEP(6, ww6, ww7, ww8, ww9, wwa, wwb, wwc, wwd)
          C2STEP(7, ww7, ww8, ww9, wwa, wwb, wwc, wwd, wwe)
          C2STEP(8, ww8, ww9, wwa, wwb, wwc, wwd, wwe, wwf)
          C2STEP(9, ww9, wwa, wwb, wwc, wwd, wwe, wwf, wwg)
#undef C2STEP
        }
        const float scA = s_s2f[c0], tbA = s_t2f[c0];
        const float scB = s_s2f[c0 + 8], tbB = s_t2f[c0 + 8];
        s_x2[c0][0][nl] = (lb + 0 < L2LEN) ? fmaf(fmaxf(y00, 0.f), scA, tbA) : 0.f;
        s_x2[c0][1][nl] = (lb + 1 < L2LEN) ? fmaf(fmaxf(y01, 0.f), scA, tbA) : 0.f;
        s_x2[c0][2][nl] = (lb + 2 < L2LEN) ? fmaf(fmaxf(y02, 0.f), scA, tbA) : 0.f;
        s_x2[c0][3][nl] = (lb + 3 < L2LEN) ? fmaf(fmaxf(y03, 0.f), scA, tbA) : 0.f;
        s_x2[c0][4][nl] = (lb + 4 < L2LEN) ? fmaf(fmaxf(y10, 0.f), scA, tbA) : 0.f;
        s_x2[c0][5][nl] = (lb + 5 < L2LEN) ? fmaf(fmaxf(y11, 0.f), scA, tbA) : 0.f;
        s_x2[c0][6][nl] = (lb + 6 < L2LEN) ? fmaf(fmaxf(y12, 0.f), scA, tbA) : 0.f;
        s_x2[c0][7][nl] = (lb + 7 < L2LEN) ? fmaf(fmaxf(y13, 0.f), scA, tbA) : 0.f;
        s_x2[c0 + 8][0][nl] = (lb + 0 < L2LEN) ? fmaf(fmaxf(y20, 0.f), scB, tbB) : 0.f;
        s_x2[c0 + 8][1][nl] = (lb + 1 < L2LEN) ? fmaf(fmaxf(y21, 0.f), scB, tbB) : 0.f;
        s_x2[c0 + 8][2][nl] = (lb + 2 < L2LEN) ? fmaf(fmaxf(y22, 0.f), scB, tbB) : 0.f;
        s_x2[c0 + 8][3][nl] = (lb + 3 < L2LEN) ? fmaf(fmaxf(y23, 0.f), scB, tbB) : 0.f;
        s_x2[c0 + 8][4][nl] = (lb + 4 < L2LEN) ? fmaf(fmaxf(y30, 0.f), scB, tbB) : 0.f;
        s_x2[c0 + 8][5][nl] = (lb + 5 < L2LEN) ? fmaf(fmaxf(y31, 0.f), scB, tbB) : 0.f;
        s_x2[c0 + 8][6][nl] = (lb + 6 < L2LEN) ? fmaf(fmaxf(y32, 0.f), scB, tbB) : 0.f;
        s_x2[c0 + 8][7][nl] = (lb + 7 < L2LEN) ? fmaf(fmaxf(y33, 0.f), scB, tbB) : 0.f;
      } else {
#pragma unroll
        for (int l = 0; l < 8; l++) {
          s_x2[c0][l][nl] = 0.f;
          s_x2[c0 + 8][l][nl] = 0.f;
        }
      }
    }
    __syncthreads();
    // fc: weights straight from global (same addr across tn -> coalesced/L1 broadcast);
    // f32 8-term chunks per (c,m), kk ascending, folded into f64 accumulators. No barriers.
    {
      const bool full = (lb + 8 <= L2LEN);
      for (int c = 0; c < 16; c++) {
        const float2 xv0 = *reinterpret_cast<const float2*>(&s_x2[c][0][tn * 2]);
        const float2 xv1 = *reinterpret_cast<const float2*>(&s_x2[c][1][tn * 2]);
        const float2 xv2 = *reinterpret_cast<const float2*>(&s_x2[c][2][tn * 2]);
        const float2 xv3 = *reinterpret_cast<const float2*>(&s_x2[c][3][tn * 2]);
        const float2 xv4 = *reinterpret_cast<const float2*>(&s_x2[c][4][tn * 2]);
        const float2 xv5 = *reinterpret_cast<const float2*>(&s_x2[c][5][tn * 2]);
        const float2 xv6 = *reinterpret_cast<const float2*>(&s_x2[c][6][tn * 2]);
        const float2 xv7 = *reinterpret_cast<const float2*>(&s_x2[c][7][tn * 2]);
        const float* fbase = fcw + (size_t)te * DIMFC + (size_t)c * L2LEN + lb;
#pragma unroll
        for (int m = 0; m < 7; m++) {
          if (te + 16 * m < EMBD) {
            const float* fp = fbase + (size_t)(16 * m) * DIMFC;
            float4 wa, wb;
            if (full) {
              wa = *reinterpret_cast<const float4*>(fp);
              wb = *reinterpret_cast<const float4*>(fp + 4);
            } else {
              wa.x = (lb + 0 < L2LEN) ? fp[0] : 0.f;
              wa.y = (lb + 1 < L2LEN) ? fp[1] : 0.f;
              wa.z = (lb + 2 < L2LEN) ? fp[2] : 0.f;
              wa.w = (lb + 3 < L2LEN) ? fp[3] : 0.f;
              wb.x = (lb + 4 < L2LEN) ? fp[4] : 0.f;
              wb.y = (lb + 5 < L2LEN) ? fp[5] : 0.f;
              wb.z = (lb + 6 < L2LEN) ? fp[6] : 0.f;
              wb.w = (lb + 7 < L2LEN) ? fp[7] : 0.f;
            }
            float a0 = 0.f, a1 = 0.f;
            a0 = fmaf(wa.x, xv0.x, a0); a1 = fmaf(wa.x, xv0.y, a1);
            a0 = fmaf(wa.y, xv1.x, a0); a1 = fmaf(wa.y, xv1.y, a1);
            a0 = fmaf(wa.z, xv2.x, a0); a1 = fmaf(wa.z, xv2.y, a1);
            a0 = fmaf(wa.w, xv3.x, a0); a1 = fmaf(wa.w, xv3.y, a1);
            a0 = fmaf(wb.x, xv4.x, a0); a1 = fmaf(wb.x, xv4.y, a1);
            a0 = fmaf(wb.y, xv5.x, a0); a1 = fmaf(wb.y, xv5.y, a1);
            a0 = fmaf(wb.z, xv6.x, a0); a1 = fmaf(wb.z, xv6.y, a1);
            a0 = fmaf(wb.w, xv7.x, a0); a1 = fmaf(wb.w, xv7.y, a1);
            acc[m][0] += (double)a0;
            acc[m][1] += (double)a1;
          }
        }
      }
    }
  }
  for (int m = 0; m < 7; m++) {
    int e = te + 16 * m;
    if (e < EMBD) {
      for (int q = 0; q < 2; q++) {
        int nl2 = tn * 2 + q;
        if (nl2 < 52) part[(((size_t)ks * 4 + nt) * 100 + e) * 52 + nl2] = (float)acc[m][q];
      }
    }
  }
}

// ---------------- K6: reduce split-K (f64), +bias, relu, bn3 -> x (f64) ----------------
__global__ __launch_bounds__(256) void k_bn3(const float* __restrict__ part,
                                             const float* __restrict__ fcb,
                                             const float* __restrict__ g3,
                                             const float* __restrict__ b3,
                                             double* __restrict__ xd) {
  const int e = blockIdx.x;
  const int n = threadIdx.x;
  double v = 0.0;
  if (n < NNODE) {
    int nt = n / 52, nl = n - nt * 52;
    const size_t stride = 4 * 100 * 52;
    const float* p = part + ((size_t)nt * 100 + e) * 52 + nl;
    for (int ks = 0; ks < 94; ks++) v += (double)p[ks * stride];
    v = fmax(v + (double)fcb[e], 0.0);
  }
  __shared__ double redA[4], redB[4];
  __shared__ double s_m, s_sd;
  int lane = threadIdx.x & 63, wid = threadIdx.x >> 6;
  double w = waveReduceD(v);
  if (lane == 0) redA[wid] = w;
  __syncthreads();
  if (threadIdx.x == 0) s_m = (redA[0] + redA[1] + redA[2] + redA[3]) / 207.0;
  __syncthreads();
  double m = s_m;
  double d = (n < NNODE) ? (v - m) : 0.0;
  double wq = waveReduceD(d * d);
  if (lane == 0) redB[wid] = wq;
  __syncthreads();
  if (threadIdx.x == 0) s_sd = sqrt((redB[0] + redB[1] + redB[2] + redB[3]) / 207.0 + (double)BNEPS);
  __syncthreads();
  if (n < NNODE) xd[n * 100 + e] = (v - m) / s_sd * (double)g3[e] + (double)b3[e];
}

// ---------------- K7: ps = x@Ws^T, pr = x@Wr^T (f64) ----------------
__global__ void k_pspr(const double* __restrict__ xd, const float* __restrict__ wout,
                       double* __restrict__ psd, double* __restrict__ prd) {
  const int n = blockIdx.x;
  __shared__ double sx[100];
  if (threadIdx.x < 100) sx[threadIdx.x] = xd[n * 100 + threadIdx.x];
  __syncthreads();
  const int e = threadIdx.x;
  if (e < 100) {
    double a = 0.0, b = 0.0;
    for (int j = 0; j < 100; j++) {
      double xv = sx[j];
      a = fma(xv, (double)wout[e * 200 + j], a);
      b = fma(xv, (double)wout[e * 200 + 100 + j], b);
    }
    psd[n * 100 + e] = a;
    prd[n * 100 + e] = b;
  }
}

// ---------------- K8a: edge logits b0/b1 per pij (f64) + bern output ----------------
__global__ __launch_bounds__(256) void k_edge(const double* __restrict__ psd,
                                              const double* __restrict__ prd,
                                              const float* __restrict__ bo,
                                              const float* __restrict__ wc,
                                              const float* __restrict__ cb,
                                              double* __restrict__ bd,
                                              float* __restrict__ out) {
  const int pij = blockIdx.x * 256 + threadIdx.x;
  if (pij >= NSQ) return;
  const int i = pij / NNODE, j = pij - i * NNODE;
  const double* pri = prd + i * 100;
  const double* psj = psd + j * 100;
  double b0 = 0.0, b1 = 0.0;
  for (int e = 0; e < 100; e++) {
    double ed = fmax(pri[e] + psj[e] + (double)bo[e], 0.0);
    b0 = fma(ed, (double)wc[e], b0);
    b1 = fma(ed, (double)wc[100 + e], b1);
  }
  b0 += (double)cb[0];
  b1 += (double)cb[1];
  bd[pij * 2] = b0;
  bd[pij * 2 + 1] = b1;
  const float b0f = (float)b0, b1f = (float)b1;
  for (int b = 0; b < NBATCH; b++) {
    size_t base = (size_t)b * (2 * NSQ) + (size_t)pij * 2;
    out[base] = b0f;
    out[base + 1] = b1f;
  }
}

// ---------------- K8b: gumbel sample per (b,pij) ----------------
__global__ __launch_bounds__(256) void k_samp(const double* __restrict__ bd,
                                              float* __restrict__ out) {
  const int gid = blockIdx.x * 256 + threadIdx.x;
  if (gid >= NBATCH * NSQ) return;
  const int b = gid / NSQ;
  const int pij = gid - b * NSQ;
  const int i = pij / NNODE, j = pij - i * NNODE;
  const double b0 = bd[pij * 2], b1 = bd[pij * 2 + 1];
  uint32_t base = (uint32_t)b * (2u * NSQ) + (uint32_t)pij * 2u;
  float u0 = uniform_part(base);
  float u1 = uniform_part(base + 1u);
  double g0 = -log(-log((double)u0 + 1e-20) + 1e-20);
  double g1 = -log(-log((double)u1 + 1e-20) + 1e-20);
  float v = ((b0 + g0) >= (b1 + g1)) ? 1.0f : 0.0f;
  if (i == j) v = 0.f;
  out[O_SAMP + (size_t)b * NSQ + pij] = v;
}

extern "C" void kernel_launch(void* const* d_in, const int* in_sizes, int n_in,
                              void* d_out, int out_size, void* d_ws, size_t ws_size,
                              hipStream_t stream) {
  const float* hid = (const float*)d_in[0];
  const float* nf = (const float*)d_in[1];
  const float* c1w = (const float*)d_in[2];
  const float* c1b = (const float*)d_in[3];
  const float* c2w = (const float*)d_in[4];
  const float* c2b = (const float*)d_in[5];
  const float* g1 = (const float*)d_in[6];
  const float* b1 = (const float*)d_in[7];
  const float* g2 = (const float*)d_in[8];
  const float* b2 = (const float*)d_in[9];
  const float* fcw = (const float*)d_in[10];
  const float* fcb = (const float*)d_in[11];
  const float* g3 = (const float*)d_in[12];
  const float* b3 = (const float*)d_in[13];
  // d_in[14], d_in[15]: fc_mean_w / fc_mean_b are dead code in the reference
  const float* wout = (const float*)d_in[16];
  const float* bout = (const float*)d_in[17];
  const float* wc = (const float*)d_in[18];
  const float* cbb = (const float*)d_in[19];
  float* out = (float*)d_out;
  float* ws = (float*)d_ws;

  float* w_norm = ws + 0;                       // 3312 f
  float* w_sim = ws + 8192;                     // 685584 f
  float* w_p1 = ws + 704512;                    // 3008 f
  float* w_p2 = ws + 712704;                    // 158976 f (dead after k_red2)
  double* w_bd = (double*)(ws + 712704);        // 85698 d  (reuses w_p2 region, fits 187392 f gap)
  double* w_foldd = (double*)(ws + 900096);     // 48 d
  float* w_part = ws + 1048576;                 // 1955200 f
  double* w_xd = (double*)(ws + 3145728);       // 20700 d
  double* w_psd = (double*)(ws + 3200000);      // 20700 d
  double* w_prd = (double*)(ws + 3250176);      // 20700 d

  // sim / knn branch
  k_copynorm<<<NBATCH * NNODE, 256, 0, stream>>>(hid, out, w_norm);
  k_sim<<<dim3(16, NBATCH), 256, 0, stream>>>(hid, w_norm, w_sim);
  k_topk<<<NBATCH, 1024, 0, stream>>>(w_sim, out);

  // conv -> fc -> edge branch
  k_c1stats<<<188, 256, 0, stream>>>(nf, c1w, c1b, w_p1);
  k_red1<<<1, 64, 0, stream>>>(w_p1, g1, b1, w_foldd);
  k_c2stats<<<dim3(24, NNODE), 256, 0, stream>>>(nf, c1w, c1b, c2w, c2b, w_foldd, w_p2);
  k_red2<<<1, 256, 0, stream>>>(w_p2, g2, b2, w_foldd);
  k_gemm<<<dim3(94, 4), 512, 0, stream>>>(nf, c1w, c1b, c2w, c2b, w_foldd, fcw, w_part);
  k_bn3<<<EMBD, 256, 0, stream>>>(w_part, fcb, g3, b3, w_xd);
  k_pspr<<<NNODE, 128, 0, stream>>>(w_xd, wout, w_psd, w_prd);
  k_edge<<<(NSQ + 255) / 256, 256, 0, stream>>>(w_psd, w_prd, bout, wc, cbb, w_bd, out);
  k_samp<<<(NBATCH * NSQ + 255) / 256, 256, 0, stream>>>(w_bd, out);
}

// Round 10
// 3551.893 us; speedup vs baseline: 3.0938x; 3.0938x over previous
//
#include <hip/hip_runtime.h>
#include <stdint.h>
#include <math.h>

#define NBATCH 16
#define NNODE 207
#define TLEN 23990
#define EMBD 100
#define L1LEN 23981   // T-9
#define L2LEN 23972   // T-18
#define DIMFC 383552  // 16*L2
#define DMEAN 16128   // P*D
#define NSQ 42849     // N*N
#define KSEL 2070     // K*N
#define BNEPS 1e-5f

// output offsets (floats)
#define O_HID  1371168ull
#define O_KNN  54787104ull
#define O_SAMP 55472688ull

__device__ __forceinline__ float waveReduce(float v) {
#pragma unroll
  for (int o = 32; o > 0; o >>= 1) v += __shfl_down(v, o);
  return v;
}

__device__ __forceinline__ double waveReduceD(double v) {
#pragma unroll
  for (int o = 32; o > 0; o >>= 1) v += __shfl_down(v, o);
  return v;
}

__device__ __forceinline__ unsigned int sortableKey(float f) {
  unsigned int u = __float_as_uint(f);
  return (u & 0x80000000u) ? ~u : (u | 0x80000000u);
}

// JAX threefry2x32-20 with key (0, 42)
__device__ __forceinline__ void threefry(uint32_t x0, uint32_t x1, uint32_t& o0, uint32_t& o1) {
  const uint32_t k0 = 0u, k1 = 42u;
  const uint32_t k2 = k0 ^ k1 ^ 0x1BD11BDAu;
  x0 += k0; x1 += k1;
#define TFR(r) { x0 += x1; x1 = (x1 << r) | (x1 >> (32 - r)); x1 ^= x0; }
  TFR(13) TFR(15) TFR(26) TFR(6)   x0 += k1; x1 += k2 + 1u;
  TFR(17) TFR(29) TFR(16) TFR(24)  x0 += k2; x1 += k0 + 2u;
  TFR(13) TFR(15) TFR(26) TFR(6)   x0 += k0; x1 += k1 + 3u;
  TFR(17) TFR(29) TFR(16) TFR(24)  x0 += k1; x1 += k2 + 4u;
  TFR(13) TFR(15) TFR(26) TFR(6)   x0 += k2; x1 += k0 + 5u;
#undef TFR
  o0 = x0; o1 = x1;
}

// jax_threefry_partitionable bit stream: element i -> threefry(key,(0,i)), XOR-fold.
__device__ __forceinline__ float uniform_part(uint32_t m) {
  uint32_t o0, o1;
  threefry(0u, m, o0, o1);
  uint32_t bits = o0 ^ o1;
  return __uint_as_float((bits >> 9) | 0x3f800000u) - 1.0f;
}

// ---------------- K9: copy hidden -> out, row sumsq -> norms ----------------
__global__ __launch_bounds__(256) void k_copynorm(const float* __restrict__ h,
                                                  float* __restrict__ out,
                                                  float* __restrict__ norms) {
  const size_t row = blockIdx.x; // 0..3311
  const float4* src = reinterpret_cast<const float4*>(h + row * (size_t)DMEAN);
  float4* dst = reinterpret_cast<float4*>(out + O_HID + row * (size_t)DMEAN);
  float s = 0.f;
  for (int i = threadIdx.x; i < DMEAN / 4; i += 256) {
    float4 v = src[i];
    dst[i] = v;
    s += v.x * v.x + v.y * v.y + v.z * v.z + v.w * v.w;
  }
  __shared__ float red[4];
  float w = waveReduce(s);
  if ((threadIdx.x & 63) == 0) red[threadIdx.x >> 6] = w;
  __syncthreads();
  if (threadIdx.x == 0) norms[row] = sqrtf(red[0] + red[1] + red[2] + red[3]);
}

// ---------------- K10: sim = hn @ hn^T per batch (64x64 tiles, K-chunk 32) ----------------
__global__ __launch_bounds__(256) void k_sim(const float* __restrict__ h,
                                             const float* __restrict__ norms,
                                             float* __restrict__ sim) {
  const int b = blockIdx.y;
  const int ti = blockIdx.x >> 2, tj = blockIdx.x & 3;
  __shared__ float sA[32][64], sB[32][64];
  __shared__ float dA[64], dB[64];
  if (threadIdx.x < 64) {
    int n = ti * 64 + threadIdx.x;
    dA[threadIdx.x] = (n < NNODE) ? (norms[b * NNODE + n] + 1e-10f) : 1.f;
  } else if (threadIdx.x < 128) {
    int tl = threadIdx.x - 64;
    int n = tj * 64 + tl;
    dB[tl] = (n < NNODE) ? (norms[b * NNODE + n] + 1e-10f) : 1.f;
  }
  __syncthreads();
  float acc[4][4];
#pragma unroll
  for (int p = 0; p < 4; p++)
#pragma unroll
    for (int q = 0; q < 4; q++) acc[p][q] = 0.f;
  const int tx = threadIdx.x & 15, ty = threadIdx.x >> 4;
  const int r = threadIdx.x >> 2, c4 = threadIdx.x & 3;
  const float* hb = h + (size_t)b * NNODE * DMEAN;
  for (int k0 = 0; k0 < DMEAN; k0 += 32) {
    __syncthreads();
    {
      int n = ti * 64 + r;
      float4 v1 = make_float4(0.f, 0.f, 0.f, 0.f), v2 = v1;
      if (n < NNODE) {
        v1 = *reinterpret_cast<const float4*>(&hb[(size_t)n * DMEAN + k0 + c4 * 4]);
        v2 = *reinterpret_cast<const float4*>(&hb[(size_t)n * DMEAN + k0 + 16 + c4 * 4]);
      }
      float d = dA[r];
      sA[c4 * 4 + 0][r] = v1.x / d;
      sA[c4 * 4 + 1][r] = v1.y / d;
      sA[c4 * 4 + 2][r] = v1.z / d;
      sA[c4 * 4 + 3][r] = v1.w / d;
      sA[16 + c4 * 4 + 0][r] = v2.x / d;
      sA[16 + c4 * 4 + 1][r] = v2.y / d;
      sA[16 + c4 * 4 + 2][r] = v2.z / d;
      sA[16 + c4 * 4 + 3][r] = v2.w / d;
      int n2 = tj * 64 + r;
      float4 u1 = make_float4(0.f, 0.f, 0.f, 0.f), u2 = u1;
      if (n2 < NNODE) {
        u1 = *reinterpret_cast<const float4*>(&hb[(size_t)n2 * DMEAN + k0 + c4 * 4]);
        u2 = *reinterpret_cast<const float4*>(&hb[(size_t)n2 * DMEAN + k0 + 16 + c4 * 4]);
      }
      float d2 = dB[r];
      sB[c4 * 4 + 0][r] = u1.x / d2;
      sB[c4 * 4 + 1][r] = u1.y / d2;
      sB[c4 * 4 + 2][r] = u1.z / d2;
      sB[c4 * 4 + 3][r] = u1.w / d2;
      sB[16 + c4 * 4 + 0][r] = u2.x / d2;
      sB[16 + c4 * 4 + 1][r] = u2.y / d2;
      sB[16 + c4 * 4 + 2][r] = u2.z / d2;
      sB[16 + c4 * 4 + 3][r] = u2.w / d2;
    }
    __syncthreads();
#pragma unroll
    for (int kk = 0; kk < 32; kk++) {
      float4 av = *reinterpret_cast<const float4*>(&sA[kk][ty * 4]);
      float4 bv = *reinterpret_cast<const float4*>(&sB[kk][tx * 4]);
      acc[0][0] = fmaf(av.x, bv.x, acc[0][0]);
      acc[0][1] = fmaf(av.x, bv.y, acc[0][1]);
      acc[0][2] = fmaf(av.x, bv.z, acc[0][2]);
      acc[0][3] = fmaf(av.x, bv.w, acc[0][3]);
      acc[1][0] = fmaf(av.y, bv.x, acc[1][0]);
      acc[1][1] = fmaf(av.y, bv.y, acc[1][1]);
      acc[1][2] = fmaf(av.y, bv.z, acc[1][2]);
      acc[1][3] = fmaf(av.y, bv.w, acc[1][3]);
      acc[2][0] = fmaf(av.z, bv.x, acc[2][0]);
      acc[2][1] = fmaf(av.z, bv.y, acc[2][1]);
      acc[2][2] = fmaf(av.z, bv.z, acc[2][2]);
      acc[2][3] = fmaf(av.z, bv.w, acc[2][3]);
      acc[3][0] = fmaf(av.w, bv.x, acc[3][0]);
      acc[3][1] = fmaf(av.w, bv.y, acc[3][1]);
      acc[3][2] = fmaf(av.w, bv.z, acc[3][2]);
      acc[3][3] = fmaf(av.w, bv.w, acc[3][3]);
    }
  }
#pragma unroll
  for (int p = 0; p < 4; p++) {
    int ii = ti * 64 + ty * 4 + p;
    if (ii < NNODE) {
#pragma unroll
      for (int q = 0; q < 4; q++) {
        int jj = tj * 64 + tx * 4 + q;
        if (jj < NNODE) sim[(size_t)b * NSQ + ii * NNODE + jj] = acc[p][q];
      }
    }
  }
}

// ---------------- K11: exact top-k (radix select + index-ordered tie fill), 1024 thr ----------------
__global__ __launch_bounds__(1024) void k_topk(const float* __restrict__ sim,
                                               float* __restrict__ out) {
  const int b = blockIdx.x;
  const float* s = sim + (size_t)b * NSQ;
  float* knn = out + O_KNN + (size_t)b * NSQ;
  __shared__ unsigned int hist[256];
  __shared__ unsigned int cnts[1024];
  __shared__ unsigned int sh_prefix, sh_kneed;
  if (threadIdx.x == 0) { sh_prefix = 0u; sh_kneed = KSEL; }
  __syncthreads();
  const int lo = threadIdx.x * 42;
  const int hi = min(lo + 42, NSQ);
  for (int pass = 0; pass < 4; pass++) {
    const int shift = 24 - pass * 8;
    if (threadIdx.x < 256) hist[threadIdx.x] = 0u;
    __syncthreads();
    unsigned int pref = sh_prefix;
    unsigned int hmask = (pass == 0) ? 0u : (0xFFFFFFFFu << (shift + 8));
    for (int i = lo; i < hi; i++) {
      unsigned int key = sortableKey(s[i]);
      if ((key & hmask) == pref) atomicAdd(&hist[(key >> shift) & 255], 1u);
    }
    __syncthreads();
    if (threadIdx.x == 0) {
      unsigned int need = sh_kneed, cum = 0;
      for (int bkt = 255; bkt >= 0; bkt--) {
        unsigned int c = hist[bkt];
        if (cum + c >= need) {
          sh_prefix = pref | ((unsigned int)bkt << shift);
          sh_kneed = need - cum;
          break;
        }
        cum += c;
      }
    }
    __syncthreads();
  }
  const unsigned int kth = sh_prefix;
  const unsigned int need_eq = sh_kneed;
  unsigned int myeq = 0;
  for (int i = lo; i < hi; i++) {
    float v = s[i];
    unsigned int key = sortableKey(v);
    float o = 0.f;
    if (key > kth) {
      int ii = i / NNODE, jj = i - ii * NNODE;
      o = (v != 0.f && ii != jj) ? 1.f : 0.f;
    } else if (key == kth) {
      myeq++;
    }
    knn[i] = o;
  }
  cnts[threadIdx.x] = myeq;
  __syncthreads();
  if (threadIdx.x == 0) {
    unsigned int run = 0;
    for (int t = 0; t < 1024; t++) { unsigned int c = cnts[t]; cnts[t] = run; run += c; }
  }
  __syncthreads();
  unsigned int rank = cnts[threadIdx.x];
  for (int i = lo; i < hi && rank < need_eq; i++) {
    float v = s[i];
    if (sortableKey(v) == kth) {
      if (rank < need_eq) {
        int ii = i / NNODE, jj = i - ii * NNODE;
        knn[i] = (v != 0.f && ii != jj) ? 1.f : 0.f;
      }
      rank++;
    }
  }
}

// ---------------- K1: conv1+relu stats partials ----------------
__global__ __launch_bounds__(256) void k_c1stats(const float* __restrict__ nf,
                                                 const float* __restrict__ c1w,
                                                 const float* __restrict__ c1b,
                                                 float* __restrict__ part1) {
  __shared__ float sw[80], sb[8];
  if (threadIdx.x < 80) sw[threadIdx.x] = c1w[threadIdx.x];
  if (threadIdx.x < 8) sb[threadIdx.x] = c1b[threadIdx.x];
  __syncthreads();
  const int t0 = blockIdx.x * 128;
  const int cnt = min(128, L1LEN - t0);
  float s[8], sq[8];
#pragma unroll
  for (int c = 0; c < 8; c++) { s[c] = 0.f; sq[c] = 0.f; }
  for (int idx = threadIdx.x; idx < cnt * NNODE; idx += 256) {
    int tl = idx / NNODE;
    int n = idx - tl * NNODE;
    const float* p = nf + (size_t)(t0 + tl) * NNODE + n;
    float in[10];
#pragma unroll
    for (int k = 0; k < 10; k++) in[k] = p[k * NNODE];
#pragma unroll
    for (int c = 0; c < 8; c++) {
      float a = sb[c];
#pragma unroll
      for (int k = 0; k < 10; k++) a = fmaf(sw[c * 10 + k], in[k], a);
      a = fmaxf(a, 0.f);
      s[c] += a;
      sq[c] = fmaf(a, a, sq[c]);
    }
  }
  __shared__ float red[4][16];
  int lane = threadIdx.x & 63, wv = threadIdx.x >> 6;
#pragma unroll
  for (int c = 0; c < 8; c++) {
    float a = waveReduce(s[c]);
    float q = waveReduce(sq[c]);
    if (lane == 0) { red[wv][c * 2] = a; red[wv][c * 2 + 1] = q; }
  }
  __syncthreads();
  if (threadIdx.x < 16)
    part1[blockIdx.x * 16 + threadIdx.x] =
        red[0][threadIdx.x] + red[1][threadIdx.x] + red[2][threadIdx.x] + red[3][threadIdx.x];
}

// ---------------- K2: reduce bn1 stats (f64) -> a1/be1 doubles ----------------
__global__ void k_red1(const float* __restrict__ part1, const float* __restrict__ g1,
                       const float* __restrict__ b1, double* __restrict__ foldd) {
  __shared__ double sums[16];
  if (threadIdx.x < 16) {
    double s = 0.0;
    for (int i = 0; i < 188; i++) s += (double)part1[i * 16 + threadIdx.x];
    sums[threadIdx.x] = s;
  }
  __syncthreads();
  if (threadIdx.x < 8) {
    const double cnt = 207.0 * 23981.0;
    int c = threadIdx.x;
    double m = sums[c * 2] / cnt;
    double ex2 = sums[c * 2 + 1] / cnt;
    double var = ex2 - m * m;
    double sc = (double)g1[c] / sqrt(var + (double)BNEPS);
    foldd[c] = sc;            // a1
    foldd[8 + c] = (double)b1[c] - m * sc;  // be1
  }
}

// ---------------- K3: conv2+relu stats partials ----------------
__global__ __launch_bounds__(256) void k_c2stats(const float* __restrict__ nf,
                                                 const float* __restrict__ c1w,
                                                 const float* __restrict__ c1b,
                                                 const float* __restrict__ c2w,
                                                 const float* __restrict__ c2b,
                                                 const double* __restrict__ foldd,
                                                 float* __restrict__ part2) {
  const int n = blockIdx.y;
  const int l0 = blockIdx.x * 1024;
  const int len = min(1024, L2LEN - l0);
  __shared__ float s_nf[1042];
  __shared__ float s_o1[8][1034];
  __shared__ float s_w2t[1280];
  __shared__ float s_b2[16];
  __shared__ float s_c1w[80], s_c1b[8];
  __shared__ float s_a1[8], s_be1[8];
  for (int i = threadIdx.x; i < 1280; i += 256) {
    int co = i / 80, r = i - co * 80;
    s_w2t[r * 16 + co] = c2w[i];
  }
  if (threadIdx.x < 16) s_b2[threadIdx.x] = c2b[threadIdx.x];
  if (threadIdx.x < 80) s_c1w[threadIdx.x] = c1w[threadIdx.x];
  if (threadIdx.x < 8) {
    s_c1b[threadIdx.x] = c1b[threadIdx.x];
    s_a1[threadIdx.x] = (float)foldd[threadIdx.x];
    s_be1[threadIdx.x] = (float)foldd[8 + threadIdx.x];
  }
  __syncthreads();
  const int nfl = len + 18;
  for (int i = threadIdx.x; i < nfl; i += 256) s_nf[i] = nf[(size_t)(l0 + i) * NNODE + n];
  __syncthreads();
  const int o1l = len + 9;
  for (int i = threadIdx.x; i < 8 * o1l; i += 256) {
    int c = i / o1l, t = i - c * o1l;
    float a = s_c1b[c];
#pragma unroll
    for (int k = 0; k < 10; k++) a = fmaf(s_c1w[c * 10 + k], s_nf[t + k], a);
    s_o1[c][t] = fmaxf(a, 0.f) * s_a1[c] + s_be1[c];
  }
  __syncthreads();
  const int co = threadIdx.x & 15, lg = threadIdx.x >> 4;
  float sum = 0.f, ssq = 0.f;
  for (int pass = 0; pass < 4; pass++) {
    int lb = pass * 256 + lg * 16;
    if (lb >= len) continue;
    int nl = min(16, len - lb);
    float y[16];
#pragma unroll
    for (int l = 0; l < 16; l++) y[l] = s_b2[co];
#pragma unroll
    for (int ci = 0; ci < 8; ci++) {
      float win[25];
#pragma unroll
      for (int w = 0; w < 25; w++) win[w] = s_o1[ci][lb + w];
#pragma unroll
      for (int k = 0; k < 10; k++) {
        float wv = s_w2t[(ci * 10 + k) * 16 + co];
#pragma unroll
        for (int l = 0; l < 16; l++) y[l] = fmaf(wv, win[l + k], y[l]);
      }
    }
#pragma unroll
    for (int l = 0; l < 16; l++) {
      if (l < nl) {
        float v = fmaxf(y[l], 0.f);
        sum += v;
        ssq = fmaf(v, v, ssq);
      }
    }
  }
  __shared__ float rs[16][16], rq[16][16];
  rs[lg][co] = sum;
  rq[lg][co] = ssq;
  __syncthreads();
  if (threadIdx.x < 16) {
    float a = 0.f, q = 0.f;
    for (int g = 0; g < 16; g++) { a += rs[g][threadIdx.x]; q += rq[g][threadIdx.x]; }
    int blk = blockIdx.y * gridDim.x + blockIdx.x;
    part2[blk * 32 + threadIdx.x * 2] = a;
    part2[blk * 32 + threadIdx.x * 2 + 1] = q;
  }
}

// ---------------- K4: reduce bn2 stats (f64) -> s2/t2 doubles ----------------
__global__ void k_red2(const float* __restrict__ part2, const float* __restrict__ g2,
                       const float* __restrict__ b2, double* __restrict__ foldd) {
  __shared__ double acc8[8][32];
  const int grp = threadIdx.x >> 5, v = threadIdx.x & 31;
  double s = 0.0;
  for (int i = grp; i < 4968; i += 8) s += (double)part2[i * 32 + v];
  acc8[grp][v] = s;
  __syncthreads();
  if (threadIdx.x < 32) {
    double t = 0.0;
    for (int g = 0; g < 8; g++) t += acc8[g][threadIdx.x];
    acc8[0][threadIdx.x] = t;
  }
  __syncthreads();
  if (threadIdx.x < 16) {
    const double cnt = 207.0 * 23972.0;
    int c = threadIdx.x;
    double m = acc8[0][c * 2] / cnt;
    double ex2 = acc8[0][c * 2 + 1] / cnt;
    double var = ex2 - m * m;
    double sc = (double)g2[c] / sqrt(var + (double)BNEPS);
    foldd[16 + c] = sc;                       // s2
    foldd[32 + c] = (double)b2[c] - m * sc;   // t2
  }
}

// ---------------- K5: fused conv1->conv2->bn2->fc GEMM (LDS fc weights, double-buffered) ----------------
__global__ __launch_bounds__(512, 2) void k_gemm(const float* __restrict__ nf,
                                                 const float* __restrict__ c1w,
                                                 const float* __restrict__ c1b,
                                                 const float* __restrict__ c2w,
                                                 const float* __restrict__ c2b,
                                                 const double* __restrict__ foldd,
                                                 const float* __restrict__ fcw,
                                                 float* __restrict__ part) {
  const int ks = blockIdx.x;  // 0..93 l-chunk of 256
  const int nt = blockIdx.y;  // 0..3  n-tile of 52
  const int l0 = ks * 256;
  const int n0 = nt * 52;

  __shared__ float s_nf[26][52];
  __shared__ float s_o1[8][17][52];   // bn1-applied conv1 (f32)
  __shared__ float s_x2[16][8][64];   // bn2-applied conv2 (f32)
  __shared__ float s_wT[2][112][10];  // fc weights [buf][e][kk], pad 10 (conflict-free, 8B-aligned)
  __shared__ float s_w2t[1280];
  __shared__ float s_c1w[80], s_c1b[8], s_c2b[16];
  __shared__ float s_a1f[8], s_be1f[8], s_s2f[16], s_t2f[16];

  for (int i = threadIdx.x; i < 1280; i += 512) {
    int co = i / 80, r = i - co * 80;
    s_w2t[r * 16 + co] = c2w[i];
  }
  if (threadIdx.x < 80) s_c1w[threadIdx.x] = c1w[threadIdx.x];
  if (threadIdx.x < 8) {
    s_c1b[threadIdx.x] = c1b[threadIdx.x];
    s_a1f[threadIdx.x] = (float)foldd[threadIdx.x];
    s_be1f[threadIdx.x] = (float)foldd[8 + threadIdx.x];
  }
  if (threadIdx.x < 16) {
    s_c2b[threadIdx.x] = c2b[threadIdx.x];
    s_s2f[threadIdx.x] = (float)foldd[16 + threadIdx.x];
    s_t2f[threadIdx.x] = (float)foldd[32 + threadIdx.x];
  }

  double acc[7][2];
#pragma unroll
  for (int m = 0; m < 7; m++)
#pragma unroll
    for (int q = 0; q < 2; q++) acc[m][q] = 0.0;

  const int te = threadIdx.x & 15;   // e-lane
  const int tn = threadIdx.x >> 4;   // 0..31
  const int nl = threadIdx.x & 63;   // conv2 node lane
  const int c0 = (threadIdx.x >> 6) & 7;  // conv2 co base
  const bool doload = threadIdx.x < 448;  // fc staging lanes
  const int e_ld = threadIdx.x >> 2;      // 0..111
  const int k2 = (threadIdx.x & 3) * 2;   // 0,2,4,6

  for (int ls = 0; ls < 32; ls++) {
    const int lb = l0 + ls * 8;
    if (lb >= L2LEN) break;
    const bool lfull = (lb + 8 <= L2LEN);
    for (int i = threadIdx.x; i < 26 * 52; i += 512) {
      int r = i / 52, cc = i - r * 52;
      int t = lb + r, n = n0 + cc;
      float v = 0.f;
      if (t < TLEN && n < NNODE) v = nf[(size_t)t * NNODE + n];
      s_nf[r][cc] = v;
    }
    __syncthreads();
    // conv1 + bn1 (f32)
    for (int i = threadIdx.x; i < 8 * 17 * 52; i += 512) {
      int c = i / (17 * 52);
      int rem = i - c * 17 * 52;
      int t = rem / 52, n = rem - t * 52;
      float a = s_c1b[c];
#pragma unroll
      for (int k = 0; k < 10; k++) a = fmaf(s_c1w[c * 10 + k], s_nf[t + k][n], a);
      s_o1[c][t][n] = fmaxf(a, 0.f) * s_a1f[c] + s_be1f[c];
    }
    __syncthreads();
    // conv2 + relu + bn2 (f32, named scalars, shared 17-wide window)
    {
      const bool valid = (nl < 52) && (n0 + nl < NNODE);
      if (valid) {
        const float bA = s_c2b[c0], bB = s_c2b[c0 + 8];
        float y00 = bA, y01 = bA, y02 = bA, y03 = bA;
        float y10 = bA, y11 = bA, y12 = bA, y13 = bA;
        float y20 = bB, y21 = bB, y22 = bB, y23 = bB;
        float y30 = bB, y31 = bB, y32 = bB, y33 = bB;
        for (int ci = 0; ci < 8; ci++) {
          float ww0 = s_o1[ci][0][nl],  ww1 = s_o1[ci][1][nl],  ww2 = s_o1[ci][2][nl];
          float ww3 = s_o1[ci][3][nl],  ww4 = s_o1[ci][4][nl],  ww5 = s_o1[ci][5][nl];
          float ww6 = s_o1[ci][6][nl],  ww7 = s_o1[ci][7][nl],  ww8 = s_o1[ci][8][nl];
          float ww9 = s_o1[ci][9][nl],  wwa = s_o1[ci][10][nl], wwb = s_o1[ci][11][nl];
          float wwc = s_o1[ci][12][nl], wwd = s_o1[ci][13][nl], wwe = s_o1[ci][14][nl];
          float wwf = s_o1[ci][15][nl], wwg = s_o1[ci][16][nl];
          const float* wpA = &s_w2t[ci * 160 + c0];
          const float* wpB = wpA + 8;
          float v, u;
#define C2STEP(K, A0, A1, A2, A3, B0, B1, B2, B3)                                   \
          v = wpA[(K) * 16]; u = wpB[(K) * 16];                                     \
          y00 = fmaf(v, A0, y00); y01 = fmaf(v, A1, y01);                           \
          y02 = fmaf(v, A2, y02); y03 = fmaf(v, A3, y03);                           \
          y10 = fmaf(v, B0, y10); y11 = fmaf(v, B1, y11);                           \
          y12 = fmaf(v, B2, y12); y13 = fmaf(v, B3, y13);                           \
          y20 = fmaf(u, A0, y20); y21 = fmaf(u, A1, y21);                           \
          y22 = fmaf(u, A2, y22); y23 = fmaf(u, A3, y23);                           \
          y30 = fmaf(u, B0, y30); y31 = fmaf(u, B1, y31);                           \
          y32 = fmaf(u, B2, y32); y33 = fmaf(u, B3, y33);
          C2STEP(0, ww0, ww1, ww2, ww3, ww4, ww5, ww6, ww7)
          C2STEP(1, ww1, ww2, ww3, ww4, ww5, ww6, ww7, ww8)
          C2STEP(2, ww2, ww3, ww4, ww5, ww6, ww7, ww8, ww9)
          C2STEP(3, ww3, ww4, ww5, ww6, ww7, ww8, ww9, wwa)
          C2STEP(4, ww4, ww5, ww6, ww7, ww8, ww9, wwa, wwb)
          C2STEP(5, ww5, ww6, ww7, ww8, ww9, wwa, wwb, wwc)
          C2STEP(6, ww6, ww7, ww8, ww9, wwa, wwb, wwc, wwd)
          C2STEP(7, ww7, ww8, ww9, wwa, wwb, wwc, wwd, wwe)
          C2STEP(8, ww8, ww9, wwa, wwb, wwc, wwd, wwe, wwf)
          C2STEP(9, ww9, wwa, wwb, wwc, wwd, wwe, wwf, wwg)
#undef C2STEP
        }
        const float scA = s_s2f[c0], tbA = s_t2f[c0];
        const float scB = s_s2f[c0 + 8], tbB = s_t2f[c0 + 8];
        s_x2[c0][0][nl] = (lb + 0 < L2LEN) ? fmaf(fmaxf(y00, 0.f), scA, tbA) : 0.f;
        s_x2[c0][1][nl] = (lb + 1 < L2LEN) ? fmaf(fmaxf(y01, 0.f), scA, tbA) : 0.f;
        s_x2[c0][2][nl] = (lb + 2 < L2LEN) ? fmaf(fmaxf(y02, 0.f), scA, tbA) : 0.f;
        s_x2[c0][3][nl] = (lb + 3 < L2LEN) ? fmaf(fmaxf(y03, 0.f), scA, tbA) : 0.f;
        s_x2[c0][4][nl] = (lb + 4 < L2LEN) ? fmaf(fmaxf(y10, 0.f), scA, tbA) : 0.f;
        s_x2[c0][5][nl] = (lb + 5 < L2LEN) ? fmaf(fmaxf(y11, 0.f), scA, tbA) : 0.f;
        s_x2[c0][6][nl] = (lb + 6 < L2LEN) ? fmaf(fmaxf(y12, 0.f), scA, tbA) : 0.f;
        s_x2[c0][7][nl] = (lb + 7 < L2LEN) ? fmaf(fmaxf(y13, 0.f), scA, tbA) : 0.f;
        s_x2[c0 + 8][0][nl] = (lb + 0 < L2LEN) ? fmaf(fmaxf(y20, 0.f), scB, tbB) : 0.f;
        s_x2[c0 + 8][1][nl] = (lb + 1 < L2LEN) ? fmaf(fmaxf(y21, 0.f), scB, tbB) : 0.f;
        s_x2[c0 + 8][2][nl] = (lb + 2 < L2LEN) ? fmaf(fmaxf(y22, 0.f), scB, tbB) : 0.f;
        s_x2[c0 + 8][3][nl] = (lb + 3 < L2LEN) ? fmaf(fmaxf(y23, 0.f), scB, tbB) : 0.f;
        s_x2[c0 + 8][4][nl] = (lb + 4 < L2LEN) ? fmaf(fmaxf(y30, 0.f), scB, tbB) : 0.f;
        s_x2[c0 + 8][5][nl] = (lb + 5 < L2LEN) ? fmaf(fmaxf(y31, 0.f), scB, tbB) : 0.f;
        s_x2[c0 + 8][6][nl] = (lb + 6 < L2LEN) ? fmaf(fmaxf(y32, 0.f), scB, tbB) : 0.f;
        s_x2[c0 + 8][7][nl] = (lb + 7 < L2LEN) ? fmaf(fmaxf(y33, 0.f), scB, tbB) : 0.f;
      } else {
#pragma unroll
        for (int l = 0; l < 8; l++) {
          s_x2[c0][l][nl] = 0.f;
          s_x2[c0 + 8][l][nl] = 0.f;
        }
      }
    }
    // prologue: load fc weights for c=0 (overlaps conv2 barrier)
    float2 wld = make_float2(0.f, 0.f);
    if (doload && e_ld < EMBD) {
      const float* fp = fcw + (size_t)e_ld * DIMFC + lb + k2;  // c = 0
      if (lfull) wld = *reinterpret_cast<const float2*>(fp);
      else {
        wld.x = (lb + k2 < L2LEN) ? fp[0] : 0.f;
        wld.y = (lb + k2 + 1 < L2LEN) ? fp[1] : 0.f;
      }
    }
    __syncthreads();  // s_x2 visible
    if (doload) *reinterpret_cast<float2*>(&s_wT[0][e_ld][k2]) = wld;
    // fc c-loop: 1 barrier per c, next-c weights prefetched during compute
    for (int c = 0; c < 16; c++) {
      __syncthreads();  // s_wT[c&1] ready; prev readers of s_wT[(c+1)&1] done
      float2 wnext = make_float2(0.f, 0.f);
      if (c < 15 && doload && e_ld < EMBD) {
        const float* fp = fcw + (size_t)e_ld * DIMFC + (size_t)(c + 1) * L2LEN + lb + k2;
        if (lfull) wnext = *reinterpret_cast<const float2*>(fp);
        else {
          wnext.x = (lb + k2 < L2LEN) ? fp[0] : 0.f;
          wnext.y = (lb + k2 + 1 < L2LEN) ? fp[1] : 0.f;
        }
      }
      const int bsel = c & 1;
      const float2 xv0 = *reinterpret_cast<const float2*>(&s_x2[c][0][tn * 2]);
      const float2 xv1 = *reinterpret_cast<const float2*>(&s_x2[c][1][tn * 2]);
      const float2 xv2 = *reinterpret_cast<const float2*>(&s_x2[c][2][tn * 2]);
      const float2 xv3 = *reinterpret_cast<const float2*>(&s_x2[c][3][tn * 2]);
      const float2 xv4 = *reinterpret_cast<const float2*>(&s_x2[c][4][tn * 2]);
      const float2 xv5 = *reinterpret_cast<const float2*>(&s_x2[c][5][tn * 2]);
      const float2 xv6 = *reinterpret_cast<const float2*>(&s_x2[c][6][tn * 2]);
      const float2 xv7 = *reinterpret_cast<const float2*>(&s_x2[c][7][tn * 2]);
#pragma unroll
      for (int m = 0; m < 7; m++) {
        const float* wp = &s_wT[bsel][te + 16 * m][0];
        const float2 wv01 = *reinterpret_cast<const float2*>(&wp[0]);
        const float2 wv23 = *reinterpret_cast<const float2*>(&wp[2]);
        const float2 wv45 = *reinterpret_cast<const float2*>(&wp[4]);
        const float2 wv67 = *reinterpret_cast<const float2*>(&wp[6]);
        float a0 = 0.f, a1 = 0.f;
        a0 = fmaf(wv01.x, xv0.x, a0); a1 = fmaf(wv01.x, xv0.y, a1);
        a0 = fmaf(wv01.y, xv1.x, a0); a1 = fmaf(wv01.y, xv1.y, a1);
        a0 = fmaf(wv23.x, xv2.x, a0); a1 = fmaf(wv23.x, xv2.y, a1);
        a0 = fmaf(wv23.y, xv3.x, a0); a1 = fmaf(wv23.y, xv3.y, a1);
        a0 = fmaf(wv45.x, xv4.x, a0); a1 = fmaf(wv45.x, xv4.y, a1);
        a0 = fmaf(wv45.y, xv5.x, a0); a1 = fmaf(wv45.y, xv5.y, a1);
        a0 = fmaf(wv67.x, xv6.x, a0); a1 = fmaf(wv67.x, xv6.y, a1);
        a0 = fmaf(wv67.y, xv7.x, a0); a1 = fmaf(wv67.y, xv7.y, a1);
        acc[m][0] += (double)a0;
        acc[m][1] += (double)a1;
      }
      if (c < 15 && doload)
        *reinterpret_cast<float2*>(&s_wT[(c + 1) & 1][e_ld][k2]) = wnext;
    }
  }
  for (int m = 0; m < 7; m++) {
    int e = te + 16 * m;
    if (e < EMBD) {
      for (int q = 0; q < 2; q++) {
        int nl2 = tn * 2 + q;
        if (nl2 < 52) part[(((size_t)ks * 4 + nt) * 100 + e) * 52 + nl2] = (float)acc[m][q];
      }
    }
  }
}

// ---------------- K6: reduce split-K (f64), +bias, relu, bn3 -> x (f64) ----------------
__global__ __launch_bounds__(256) void k_bn3(const float* __restrict__ part,
                                             const float* __restrict__ fcb,
                                             const float* __restrict__ g3,
                                             const float* __restrict__ b3,
                                             double* __restrict__ xd) {
  const int e = blockIdx.x;
  const int n = threadIdx.x;
  double v = 0.0;
  if (n < NNODE) {
    int nt = n / 52, nl = n - nt * 52;
    const size_t stride = 4 * 100 * 52;
    const float* p = part + ((size_t)nt * 100 + e) * 52 + nl;
    for (int ks = 0; ks < 94; ks++) v += (double)p[ks * stride];
    v = fmax(v + (double)fcb[e], 0.0);
  }
  __shared__ double redA[4], redB[4];
  __shared__ double s_m, s_sd;
  int lane = threadIdx.x & 63, wid = threadIdx.x >> 6;
  double w = waveReduceD(v);
  if (lane == 0) redA[wid] = w;
  __syncthreads();
  if (threadIdx.x == 0) s_m = (redA[0] + redA[1] + redA[2] + redA[3]) / 207.0;
  __syncthreads();
  double m = s_m;
  double d = (n < NNODE) ? (v - m) : 0.0;
  double wq = waveReduceD(d * d);
  if (lane == 0) redB[wid] = wq;
  __syncthreads();
  if (threadIdx.x == 0) s_sd = sqrt((redB[0] + redB[1] + redB[2] + redB[3]) / 207.0 + (double)BNEPS);
  __syncthreads();
  if (n < NNODE) xd[n * 100 + e] = (v - m) / s_sd * (double)g3[e] + (double)b3[e];
}

// ---------------- K7: ps = x@Ws^T, pr = x@Wr^T (f64) ----------------
__global__ void k_pspr(const double* __restrict__ xd, const float* __restrict__ wout,
                       double* __restrict__ psd, double* __restrict__ prd) {
  const int n = blockIdx.x;
  __shared__ double sx[100];
  if (threadIdx.x < 100) sx[threadIdx.x] = xd[n * 100 + threadIdx.x];
  __syncthreads();
  const int e = threadIdx.x;
  if (e < 100) {
    double a = 0.0, b = 0.0;
    for (int j = 0; j < 100; j++) {
      double xv = sx[j];
      a = fma(xv, (double)wout[e * 200 + j], a);
      b = fma(xv, (double)wout[e * 200 + 100 + j], b);
    }
    psd[n * 100 + e] = a;
    prd[n * 100 + e] = b;
  }
}

// ---------------- K8a: edge logits b0/b1 per pij (f64) + bern output ----------------
__global__ __launch_bounds__(256) void k_edge(const double* __restrict__ psd,
                                              const double* __restrict__ prd,
                                              const float* __restrict__ bo,
                                              const float* __restrict__ wc,
                                              const float* __restrict__ cb,
                                              double* __restrict__ bd,
                                              float* __restrict__ out) {
  const int pij = blockIdx.x * 256 + threadIdx.x;
  if (pij >= NSQ) return;
  const int i = pij / NNODE, j = pij - i * NNODE;
  const double* pri = prd + i * 100;
  const double* psj = psd + j * 100;
  double b0 = 0.0, b1 = 0.0;
  for (int e = 0; e < 100; e++) {
    double ed = fmax(pri[e] + psj[e] + (double)bo[e], 0.0);
    b0 = fma(ed, (double)wc[e], b0);
    b1 = fma(ed, (double)wc[100 + e], b1);
  }
  b0 += (double)cb[0];
  b1 += (double)cb[1];
  bd[pij * 2] = b0;
  bd[pij * 2 + 1] = b1;
  const float b0f = (float)b0, b1f = (float)b1;
  for (int b = 0; b < NBATCH; b++) {
    size_t base = (size_t)b * (2 * NSQ) + (size_t)pij * 2;
    out[base] = b0f;
    out[base + 1] = b1f;
  }
}

// ---------------- K8b: gumbel sample per (b,pij) ----------------
__global__ __launch_bounds__(256) void k_samp(const double* __restrict__ bd,
                                              float* __restrict__ out) {
  const int gid = blockIdx.x * 256 + threadIdx.x;
  if (gid >= NBATCH * NSQ) return;
  const int b = gid / NSQ;
  const int pij = gid - b * NSQ;
  const int i = pij / NNODE, j = pij - i * NNODE;
  const double b0 = bd[pij * 2], b1 = bd[pij * 2 + 1];
  uint32_t base = (uint32_t)b * (2u * NSQ) + (uint32_t)pij * 2u;
  float u0 = uniform_part(base);
  float u1 = uniform_part(base + 1u);
  double g0 = -log(-log((double)u0 + 1e-20) + 1e-20);
  double g1 = -log(-log((double)u1 + 1e-20) + 1e-20);
  float v = ((b0 + g0) >= (b1 + g1)) ? 1.0f : 0.0f;
  if (i == j) v = 0.f;
  out[O_SAMP + (size_t)b * NSQ + pij] = v;
}

extern "C" void kernel_launch(void* const* d_in, const int* in_sizes, int n_in,
                              void* d_out, int out_size, void* d_ws, size_t ws_size,
                              hipStream_t stream) {
  const float* hid = (const float*)d_in[0];
  const float* nf = (const float*)d_in[1];
  const float* c1w = (const float*)d_in[2];
  const float* c1b = (const float*)d_in[3];
  const float* c2w = (const float*)d_in[4];
  const float* c2b = (const float*)d_in[5];
  const float* g1 = (const float*)d_in[6];
  const float* b1 = (const float*)d_in[7];
  const float* g2 = (const float*)d_in[8];
  const float* b2 = (const float*)d_in[9];
  const float* fcw = (const float*)d_in[10];
  const float* fcb = (const float*)d_in[11];
  const float* g3 = (const float*)d_in[12];
  const float* b3 = (const float*)d_in[13];
  // d_in[14], d_in[15]: fc_mean_w / fc_mean_b are dead code in the reference
  const float* wout = (const float*)d_in[16];
  const float* bout = (const float*)d_in[17];
  const float* wc = (const float*)d_in[18];
  const float* cbb = (const float*)d_in[19];
  float* out = (float*)d_out;
  float* ws = (float*)d_ws;

  float* w_norm = ws + 0;                       // 3312 f
  float* w_sim = ws + 8192;                     // 685584 f
  float* w_p1 = ws + 704512;                    // 3008 f
  float* w_p2 = ws + 712704;                    // 158976 f (dead after k_red2)
  double* w_bd = (double*)(ws + 712704);        // 85698 d (reuses w_p2 region)
  double* w_foldd = (double*)(ws + 900096);     // 48 d
  float* w_part = ws + 1048576;                 // 1955200 f
  double* w_xd = (double*)(ws + 3145728);       // 20700 d
  double* w_psd = (double*)(ws + 3200000);      // 20700 d
  double* w_prd = (double*)(ws + 3250176);      // 20700 d

  // sim / knn branch
  k_copynorm<<<NBATCH * NNODE, 256, 0, stream>>>(hid, out, w_norm);
  k_sim<<<dim3(16, NBATCH), 256, 0, stream>>>(hid, w_norm, w_sim);
  k_topk<<<NBATCH, 1024, 0, stream>>>(w_sim, out);

  // conv -> fc -> edge branch
  k_c1stats<<<188, 256, 0, stream>>>(nf, c1w, c1b, w_p1);
  k_red1<<<1, 64, 0, stream>>>(w_p1, g1, b1, w_foldd);
  k_c2stats<<<dim3(24, NNODE), 256, 0, stream>>>(nf, c1w, c1b, c2w, c2b, w_foldd, w_p2);
  k_red2<<<1, 256, 0, stream>>>(w_p2, g2, b2, w_foldd);
  k_gemm<<<dim3(94, 4), 512, 0, stream>>>(nf, c1w, c1b, c2w, c2b, w_foldd, fcw, w_part);
  k_bn3<<<EMBD, 256, 0, stream>>>(w_part, fcb, g3, b3, w_xd);
  k_pspr<<<NNODE, 128, 0, stream>>>(w_xd, wout, w_psd, w_prd);
  k_edge<<<(NSQ + 255) / 256, 256, 0, stream>>>(w_psd, w_prd, bout, wc, cbb, w_bd, out);
  k_samp<<<(NBATCH * NSQ + 255) / 256, 256, 0, stream>>>(w_bd, out);
}

// Round 11
// 3020.912 us; speedup vs baseline: 3.6376x; 1.1758x over previous
//
#include <hip/hip_runtime.h>
#include <stdint.h>
#include <math.h>

#define NBATCH 16
#define NNODE 207
#define TLEN 23990
#define EMBD 100
#define L1LEN 23981   // T-9
#define L2LEN 23972   // T-18
#define DIMFC 383552  // 16*L2
#define DMEAN 16128   // P*D
#define NSQ 42849     // N*N
#define KSEL 2070     // K*N
#define BNEPS 1e-5f
#define NKS 125       // split-K chunks (l-chunk 192 = 24*8)

// output offsets (floats)
#define O_HID  1371168ull
#define O_KNN  54787104ull
#define O_SAMP 55472688ull

__device__ __forceinline__ float waveReduce(float v) {
#pragma unroll
  for (int o = 32; o > 0; o >>= 1) v += __shfl_down(v, o);
  return v;
}

__device__ __forceinline__ double waveReduceD(double v) {
#pragma unroll
  for (int o = 32; o > 0; o >>= 1) v += __shfl_down(v, o);
  return v;
}

__device__ __forceinline__ unsigned int sortableKey(float f) {
  unsigned int u = __float_as_uint(f);
  return (u & 0x80000000u) ? ~u : (u | 0x80000000u);
}

// JAX threefry2x32-20 with key (0, 42)
__device__ __forceinline__ void threefry(uint32_t x0, uint32_t x1, uint32_t& o0, uint32_t& o1) {
  const uint32_t k0 = 0u, k1 = 42u;
  const uint32_t k2 = k0 ^ k1 ^ 0x1BD11BDAu;
  x0 += k0; x1 += k1;
#define TFR(r) { x0 += x1; x1 = (x1 << r) | (x1 >> (32 - r)); x1 ^= x0; }
  TFR(13) TFR(15) TFR(26) TFR(6)   x0 += k1; x1 += k2 + 1u;
  TFR(17) TFR(29) TFR(16) TFR(24)  x0 += k2; x1 += k0 + 2u;
  TFR(13) TFR(15) TFR(26) TFR(6)   x0 += k0; x1 += k1 + 3u;
  TFR(17) TFR(29) TFR(16) TFR(24)  x0 += k1; x1 += k2 + 4u;
  TFR(13) TFR(15) TFR(26) TFR(6)   x0 += k2; x1 += k0 + 5u;
#undef TFR
  o0 = x0; o1 = x1;
}

// jax_threefry_partitionable bit stream: element i -> threefry(key,(0,i)), XOR-fold.
__device__ __forceinline__ float uniform_part(uint32_t m) {
  uint32_t o0, o1;
  threefry(0u, m, o0, o1);
  uint32_t bits = o0 ^ o1;
  return __uint_as_float((bits >> 9) | 0x3f800000u) - 1.0f;
}

// ---------------- K9: copy hidden -> out, row sumsq -> norms ----------------
__global__ __launch_bounds__(256) void k_copynorm(const float* __restrict__ h,
                                                  float* __restrict__ out,
                                                  float* __restrict__ norms) {
  const size_t row = blockIdx.x; // 0..3311
  const float4* src = reinterpret_cast<const float4*>(h + row * (size_t)DMEAN);
  float4* dst = reinterpret_cast<float4*>(out + O_HID + row * (size_t)DMEAN);
  float s = 0.f;
  for (int i = threadIdx.x; i < DMEAN / 4; i += 256) {
    float4 v = src[i];
    dst[i] = v;
    s += v.x * v.x + v.y * v.y + v.z * v.z + v.w * v.w;
  }
  __shared__ float red[4];
  float w = waveReduce(s);
  if ((threadIdx.x & 63) == 0) red[threadIdx.x >> 6] = w;
  __syncthreads();
  if (threadIdx.x == 0) norms[row] = sqrtf(red[0] + red[1] + red[2] + red[3]);
}

// ---------------- K10: sim = hn @ hn^T per batch (64x64 tiles, 512 thr, K-chunk 32) ----------------
__global__ __launch_bounds__(512) void k_sim(const float* __restrict__ h,
                                             const float* __restrict__ norms,
                                             float* __restrict__ sim) {
  const int b = blockIdx.y;
  const int ti = blockIdx.x >> 2, tj = blockIdx.x & 3;
  __shared__ float sA[32][64], sB[32][64];
  __shared__ float dA[64], dB[64];
  if (threadIdx.x < 64) {
    int n = ti * 64 + threadIdx.x;
    dA[threadIdx.x] = (n < NNODE) ? (norms[b * NNODE + n] + 1e-10f) : 1.f;
  } else if (threadIdx.x < 128) {
    int tl = threadIdx.x - 64;
    int n = tj * 64 + tl;
    dB[tl] = (n < NNODE) ? (norms[b * NNODE + n] + 1e-10f) : 1.f;
  }
  __syncthreads();
  float acc[2][4];
#pragma unroll
  for (int p = 0; p < 2; p++)
#pragma unroll
    for (int q = 0; q < 4; q++) acc[p][q] = 0.f;
  const int tx = threadIdx.x & 15, tyr = threadIdx.x >> 4;  // cols tx*4, rows tyr*2..+1
  const int r = threadIdx.x >> 3, c4 = threadIdx.x & 7;     // load map: row r, cols c4*4
  const float* hb = h + (size_t)b * NNODE * DMEAN;
  for (int k0 = 0; k0 < DMEAN; k0 += 32) {
    __syncthreads();
    {
      int n = ti * 64 + r;
      float4 v1 = make_float4(0.f, 0.f, 0.f, 0.f);
      if (n < NNODE) v1 = *reinterpret_cast<const float4*>(&hb[(size_t)n * DMEAN + k0 + c4 * 4]);
      float d = dA[r];
      sA[c4 * 4 + 0][r] = v1.x / d;
      sA[c4 * 4 + 1][r] = v1.y / d;
      sA[c4 * 4 + 2][r] = v1.z / d;
      sA[c4 * 4 + 3][r] = v1.w / d;
      int n2 = tj * 64 + r;
      float4 u1 = make_float4(0.f, 0.f, 0.f, 0.f);
      if (n2 < NNODE) u1 = *reinterpret_cast<const float4*>(&hb[(size_t)n2 * DMEAN + k0 + c4 * 4]);
      float d2 = dB[r];
      sB[c4 * 4 + 0][r] = u1.x / d2;
      sB[c4 * 4 + 1][r] = u1.y / d2;
      sB[c4 * 4 + 2][r] = u1.z / d2;
      sB[c4 * 4 + 3][r] = u1.w / d2;
    }
    __syncthreads();
#pragma unroll
    for (int kk = 0; kk < 32; kk++) {
      float2 av = *reinterpret_cast<const float2*>(&sA[kk][tyr * 2]);
      float4 bv = *reinterpret_cast<const float4*>(&sB[kk][tx * 4]);
      acc[0][0] = fmaf(av.x, bv.x, acc[0][0]);
      acc[0][1] = fmaf(av.x, bv.y, acc[0][1]);
      acc[0][2] = fmaf(av.x, bv.z, acc[0][2]);
      acc[0][3] = fmaf(av.x, bv.w, acc[0][3]);
      acc[1][0] = fmaf(av.y, bv.x, acc[1][0]);
      acc[1][1] = fmaf(av.y, bv.y, acc[1][1]);
      acc[1][2] = fmaf(av.y, bv.z, acc[1][2]);
      acc[1][3] = fmaf(av.y, bv.w, acc[1][3]);
    }
  }
#pragma unroll
  for (int p = 0; p < 2; p++) {
    int ii = ti * 64 + tyr * 2 + p;
    if (ii < NNODE) {
#pragma unroll
      for (int q = 0; q < 4; q++) {
        int jj = tj * 64 + tx * 4 + q;
        if (jj < NNODE) sim[(size_t)b * NSQ + ii * NNODE + jj] = acc[p][q];
      }
    }
  }
}

// ---------------- K11: exact top-k (radix select + index-ordered tie fill), 1024 thr ----------------
__global__ __launch_bounds__(1024) void k_topk(const float* __restrict__ sim,
                                               float* __restrict__ out) {
  const int b = blockIdx.x;
  const float* s = sim + (size_t)b * NSQ;
  float* knn = out + O_KNN + (size_t)b * NSQ;
  __shared__ unsigned int hist[256];
  __shared__ unsigned int cnts[1024];
  __shared__ unsigned int sh_prefix, sh_kneed;
  if (threadIdx.x == 0) { sh_prefix = 0u; sh_kneed = KSEL; }
  __syncthreads();
  const int lo = threadIdx.x * 42;
  const int hi = min(lo + 42, NSQ);
  for (int pass = 0; pass < 4; pass++) {
    const int shift = 24 - pass * 8;
    if (threadIdx.x < 256) hist[threadIdx.x] = 0u;
    __syncthreads();
    unsigned int pref = sh_prefix;
    unsigned int hmask = (pass == 0) ? 0u : (0xFFFFFFFFu << (shift + 8));
    for (int i = lo; i < hi; i++) {
      unsigned int key = sortableKey(s[i]);
      if ((key & hmask) == pref) atomicAdd(&hist[(key >> shift) & 255], 1u);
    }
    __syncthreads();
    if (threadIdx.x == 0) {
      unsigned int need = sh_kneed, cum = 0;
      for (int bkt = 255; bkt >= 0; bkt--) {
        unsigned int c = hist[bkt];
        if (cum + c >= need) {
          sh_prefix = pref | ((unsigned int)bkt << shift);
          sh_kneed = need - cum;
          break;
        }
        cum += c;
      }
    }
    __syncthreads();
  }
  const unsigned int kth = sh_prefix;
  const unsigned int need_eq = sh_kneed;
  unsigned int myeq = 0;
  for (int i = lo; i < hi; i++) {
    float v = s[i];
    unsigned int key = sortableKey(v);
    float o = 0.f;
    if (key > kth) {
      int ii = i / NNODE, jj = i - ii * NNODE;
      o = (v != 0.f && ii != jj) ? 1.f : 0.f;
    } else if (key == kth) {
      myeq++;
    }
    knn[i] = o;
  }
  cnts[threadIdx.x] = myeq;
  __syncthreads();
  if (threadIdx.x == 0) {
    unsigned int run = 0;
    for (int t = 0; t < 1024; t++) { unsigned int c = cnts[t]; cnts[t] = run; run += c; }
  }
  __syncthreads();
  unsigned int rank = cnts[threadIdx.x];
  for (int i = lo; i < hi && rank < need_eq; i++) {
    float v = s[i];
    if (sortableKey(v) == kth) {
      if (rank < need_eq) {
        int ii = i / NNODE, jj = i - ii * NNODE;
        knn[i] = (v != 0.f && ii != jj) ? 1.f : 0.f;
      }
      rank++;
    }
  }
}

// ---------------- K1: conv1+relu stats partials ----------------
__global__ __launch_bounds__(256) void k_c1stats(const float* __restrict__ nf,
                                                 const float* __restrict__ c1w,
                                                 const float* __restrict__ c1b,
                                                 float* __restrict__ part1) {
  __shared__ float sw[80], sb[8];
  if (threadIdx.x < 80) sw[threadIdx.x] = c1w[threadIdx.x];
  if (threadIdx.x < 8) sb[threadIdx.x] = c1b[threadIdx.x];
  __syncthreads();
  const int t0 = blockIdx.x * 128;
  const int cnt = min(128, L1LEN - t0);
  float s[8], sq[8];
#pragma unroll
  for (int c = 0; c < 8; c++) { s[c] = 0.f; sq[c] = 0.f; }
  for (int idx = threadIdx.x; idx < cnt * NNODE; idx += 256) {
    int tl = idx / NNODE;
    int n = idx - tl * NNODE;
    const float* p = nf + (size_t)(t0 + tl) * NNODE + n;
    float in[10];
#pragma unroll
    for (int k = 0; k < 10; k++) in[k] = p[k * NNODE];
#pragma unroll
    for (int c = 0; c < 8; c++) {
      float a = sb[c];
#pragma unroll
      for (int k = 0; k < 10; k++) a = fmaf(sw[c * 10 + k], in[k], a);
      a = fmaxf(a, 0.f);
      s[c] += a;
      sq[c] = fmaf(a, a, sq[c]);
    }
  }
  __shared__ float red[4][16];
  int lane = threadIdx.x & 63, wv = threadIdx.x >> 6;
#pragma unroll
  for (int c = 0; c < 8; c++) {
    float a = waveReduce(s[c]);
    float q = waveReduce(sq[c]);
    if (lane == 0) { red[wv][c * 2] = a; red[wv][c * 2 + 1] = q; }
  }
  __syncthreads();
  if (threadIdx.x < 16)
    part1[blockIdx.x * 16 + threadIdx.x] =
        red[0][threadIdx.x] + red[1][threadIdx.x] + red[2][threadIdx.x] + red[3][threadIdx.x];
}

// ---------------- K2: reduce bn1 stats (f64) -> a1/be1 doubles ----------------
__global__ void k_red1(const float* __restrict__ part1, const float* __restrict__ g1,
                       const float* __restrict__ b1, double* __restrict__ foldd) {
  __shared__ double sums[16];
  if (threadIdx.x < 16) {
    double s = 0.0;
    for (int i = 0; i < 188; i++) s += (double)part1[i * 16 + threadIdx.x];
    sums[threadIdx.x] = s;
  }
  __syncthreads();
  if (threadIdx.x < 8) {
    const double cnt = 207.0 * 23981.0;
    int c = threadIdx.x;
    double m = sums[c * 2] / cnt;
    double ex2 = sums[c * 2 + 1] / cnt;
    double var = ex2 - m * m;
    double sc = (double)g1[c] / sqrt(var + (double)BNEPS);
    foldd[c] = sc;            // a1
    foldd[8 + c] = (double)b1[c] - m * sc;  // be1
  }
}

// ---------------- K3: conv2+relu stats partials ----------------
__global__ __launch_bounds__(256) void k_c2stats(const float* __restrict__ nf,
                                                 const float* __restrict__ c1w,
                                                 const float* __restrict__ c1b,
                                                 const float* __restrict__ c2w,
                                                 const float* __restrict__ c2b,
                                                 const double* __restrict__ foldd,
                                                 float* __restrict__ part2) {
  const int n = blockIdx.y;
  const int l0 = blockIdx.x * 1024;
  const int len = min(1024, L2LEN - l0);
  __shared__ float s_nf[1042];
  __shared__ float s_o1[8][1034];
  __shared__ float s_w2t[1280];
  __shared__ float s_b2[16];
  __shared__ float s_c1w[80], s_c1b[8];
  __shared__ float s_a1[8], s_be1[8];
  for (int i = threadIdx.x; i < 1280; i += 256) {
    int co = i / 80, r = i - co * 80;
    s_w2t[r * 16 + co] = c2w[i];
  }
  if (threadIdx.x < 16) s_b2[threadIdx.x] = c2b[threadIdx.x];
  if (threadIdx.x < 80) s_c1w[threadIdx.x] = c1w[threadIdx.x];
  if (threadIdx.x < 8) {
    s_c1b[threadIdx.x] = c1b[threadIdx.x];
    s_a1[threadIdx.x] = (float)foldd[threadIdx.x];
    s_be1[threadIdx.x] = (float)foldd[8 + threadIdx.x];
  }
  __syncthreads();
  const int nfl = len + 18;
  for (int i = threadIdx.x; i < nfl; i += 256) s_nf[i] = nf[(size_t)(l0 + i) * NNODE + n];
  __syncthreads();
  const int o1l = len + 9;
  for (int i = threadIdx.x; i < 8 * o1l; i += 256) {
    int c = i / o1l, t = i - c * o1l;
    float a = s_c1b[c];
#pragma unroll
    for (int k = 0; k < 10; k++) a = fmaf(s_c1w[c * 10 + k], s_nf[t + k], a);
    s_o1[c][t] = fmaxf(a, 0.f) * s_a1[c] + s_be1[c];
  }
  __syncthreads();
  const int co = threadIdx.x & 15, lg = threadIdx.x >> 4;
  float sum = 0.f, ssq = 0.f;
  for (int pass = 0; pass < 4; pass++) {
    int lb = pass * 256 + lg * 16;
    if (lb >= len) continue;
    int nl = min(16, len - lb);
    float y[16];
#pragma unroll
    for (int l = 0; l < 16; l++) y[l] = s_b2[co];
#pragma unroll
    for (int ci = 0; ci < 8; ci++) {
      float win[25];
#pragma unroll
      for (int w = 0; w < 25; w++) win[w] = s_o1[ci][lb + w];
#pragma unroll
      for (int k = 0; k < 10; k++) {
        float wv = s_w2t[(ci * 10 + k) * 16 + co];
#pragma unroll
        for (int l = 0; l < 16; l++) y[l] = fmaf(wv, win[l + k], y[l]);
      }
    }
#pragma unroll
    for (int l = 0; l < 16; l++) {
      if (l < nl) {
        float v = fmaxf(y[l], 0.f);
        sum += v;
        ssq = fmaf(v, v, ssq);
      }
    }
  }
  __shared__ float rs[16][16], rq[16][16];
  rs[lg][co] = sum;
  rq[lg][co] = ssq;
  __syncthreads();
  if (threadIdx.x < 16) {
    float a = 0.f, q = 0.f;
    for (int g = 0; g < 16; g++) { a += rs[g][threadIdx.x]; q += rq[g][threadIdx.x]; }
    int blk = blockIdx.y * gridDim.x + blockIdx.x;
    part2[blk * 32 + threadIdx.x * 2] = a;
    part2[blk * 32 + threadIdx.x * 2 + 1] = q;
  }
}

// ---------------- K4: reduce bn2 stats (f64) -> s2/t2 doubles ----------------
__global__ void k_red2(const float* __restrict__ part2, const float* __restrict__ g2,
                       const float* __restrict__ b2, double* __restrict__ foldd) {
  __shared__ double acc8[8][32];
  const int grp = threadIdx.x >> 5, v = threadIdx.x & 31;
  double s = 0.0;
  for (int i = grp; i < 4968; i += 8) s += (double)part2[i * 32 + v];
  acc8[grp][v] = s;
  __syncthreads();
  if (threadIdx.x < 32) {
    double t = 0.0;
    for (int g = 0; g < 8; g++) t += acc8[g][threadIdx.x];
    acc8[0][threadIdx.x] = t;
  }
  __syncthreads();
  if (threadIdx.x < 16) {
    const double cnt = 207.0 * 23972.0;
    int c = threadIdx.x;
    double m = acc8[0][c * 2] / cnt;
    double ex2 = acc8[0][c * 2 + 1] / cnt;
    double var = ex2 - m * m;
    double sc = (double)g2[c] / sqrt(var + (double)BNEPS);
    foldd[16 + c] = sc;                       // s2
    foldd[32 + c] = (double)b2[c] - m * sc;   // t2
  }
}

// ---------------- K5: fused conv1->conv2->bn2->fc GEMM (balanced 500 blocks, dbuf fc) ----------------
__global__ __launch_bounds__(512, 2) void k_gemm(const float* __restrict__ nf,
                                                 const float* __restrict__ c1w,
                                                 const float* __restrict__ c1b,
                                                 const float* __restrict__ c2w,
                                                 const float* __restrict__ c2b,
                                                 const double* __restrict__ foldd,
                                                 const float* __restrict__ fcw,
                                                 float* __restrict__ part) {
  const int ks = blockIdx.x;  // 0..124 l-chunk of 192
  const int nt = blockIdx.y;  // 0..3  n-tile of 52
  const int l0 = ks * 192;
  const int n0 = nt * 52;

  __shared__ float s_nf[26][52];
  __shared__ float s_o1[8][17][52];   // bn1-applied conv1 (f32)
  __shared__ float s_x2[16][8][64];   // bn2-applied conv2 (f32)
  __shared__ float s_wT[2][112][10];  // fc weights [buf][e][kk]
  __shared__ float s_w2t[1280];
  __shared__ float s_c1w[80], s_c1b[8], s_c2b[16];
  __shared__ float s_a1f[8], s_be1f[8], s_s2f[16], s_t2f[16];

  for (int i = threadIdx.x; i < 1280; i += 512) {
    int co = i / 80, r = i - co * 80;
    s_w2t[r * 16 + co] = c2w[i];
  }
  if (threadIdx.x < 80) s_c1w[threadIdx.x] = c1w[threadIdx.x];
  if (threadIdx.x < 8) {
    s_c1b[threadIdx.x] = c1b[threadIdx.x];
    s_a1f[threadIdx.x] = (float)foldd[threadIdx.x];
    s_be1f[threadIdx.x] = (float)foldd[8 + threadIdx.x];
  }
  if (threadIdx.x < 16) {
    s_c2b[threadIdx.x] = c2b[threadIdx.x];
    s_s2f[threadIdx.x] = (float)foldd[16 + threadIdx.x];
    s_t2f[threadIdx.x] = (float)foldd[32 + threadIdx.x];
  }

  double acc[7][2];
#pragma unroll
  for (int m = 0; m < 7; m++)
#pragma unroll
    for (int q = 0; q < 2; q++) acc[m][q] = 0.0;

  const int te = threadIdx.x & 15;   // e-lane
  const int tn = threadIdx.x >> 4;   // 0..31
  const int nl = threadIdx.x & 63;   // conv2 node lane
  const int c0 = (threadIdx.x >> 6) & 7;  // conv2 co base
  const bool doload = threadIdx.x < 448;  // fc staging lanes
  const int e_ld = threadIdx.x >> 2;      // 0..111
  const int k2 = (threadIdx.x & 3) * 2;   // 0,2,4,6

  for (int ls = 0; ls < 24; ls++) {
    const int lb = l0 + ls * 8;
    if (lb >= L2LEN) break;
    const bool lfull = (lb + 8 <= L2LEN);
    for (int i = threadIdx.x; i < 26 * 52; i += 512) {
      int r = i / 52, cc = i - r * 52;
      int t = lb + r, n = n0 + cc;
      float v = 0.f;
      if (t < TLEN && n < NNODE) v = nf[(size_t)t * NNODE + n];
      s_nf[r][cc] = v;
    }
    __syncthreads();
    // conv1 + bn1 (f32)
    for (int i = threadIdx.x; i < 8 * 17 * 52; i += 512) {
      int c = i / (17 * 52);
      int rem = i - c * 17 * 52;
      int t = rem / 52, n = rem - t * 52;
      float a = s_c1b[c];
#pragma unroll
      for (int k = 0; k < 10; k++) a = fmaf(s_c1w[c * 10 + k], s_nf[t + k][n], a);
      s_o1[c][t][n] = fmaxf(a, 0.f) * s_a1f[c] + s_be1f[c];
    }
    __syncthreads();
    // conv2 + relu + bn2 (f32, named scalars, shared 17-wide window)
    {
      const bool valid = (nl < 52) && (n0 + nl < NNODE);
      if (valid) {
        const float bA = s_c2b[c0], bB = s_c2b[c0 + 8];
        float y00 = bA, y01 = bA, y02 = bA, y03 = bA;
        float y10 = bA, y11 = bA, y12 = bA, y13 = bA;
        float y20 = bB, y21 = bB, y22 = bB, y23 = bB;
        float y30 = bB, y31 = bB, y32 = bB, y33 = bB;
        for (int ci = 0; ci < 8; ci++) {
          float ww0 = s_o1[ci][0][nl],  ww1 = s_o1[ci][1][nl],  ww2 = s_o1[ci][2][nl];
          float ww3 = s_o1[ci][3][nl],  ww4 = s_o1[ci][4][nl],  ww5 = s_o1[ci][5][nl];
          float ww6 = s_o1[ci][6][nl],  ww7 = s_o1[ci][7][nl],  ww8 = s_o1[ci][8][nl];
          float ww9 = s_o1[ci][9][nl],  wwa = s_o1[ci][10][nl], wwb = s_o1[ci][11][nl];
          float wwc = s_o1[ci][12][nl], wwd = s_o1[ci][13][nl], wwe = s_o1[ci][14][nl];
          float wwf = s_o1[ci][15][nl], wwg = s_o1[ci][16][nl];
          const float* wpA = &s_w2t[ci * 160 + c0];
          const float* wpB = wpA + 8;
          float v, u;
#define C2STEP(K, A0, A1, A2, A3, B0, B1, B2, B3)                                   \
          v = wpA[(K) * 16]; u = wpB[(K) * 16];                                     \
          y00 = fmaf(v, A0, y00); y01 = fmaf(v, A1, y01);                           \
          y02 = fmaf(v, A2, y02); y03 = fmaf(v, A3, y03);                           \
          y10 = fmaf(v, B0, y10); y11 = fmaf(v, B1, y11);                           \
          y12 = fmaf(v, B2, y12); y13 = fmaf(v, B3, y13);                           \
          y20 = fmaf(u, A0, y20); y21 = fmaf(u, A1, y21);                           \
          y22 = fmaf(u, A2, y22); y23 = fmaf(u, A3, y23);                           \
          y30 = fmaf(u, B0, y30); y31 = fmaf(u, B1, y31);                           \
          y32 = fmaf(u, B2, y32); y33 = fmaf(u, B3, y33);
          C2STEP(0, ww0, ww1, ww2, ww3, ww4, ww5, ww6, ww7)
          C2STEP(1, ww1, ww2, ww3, ww4, ww5, ww6, ww7, ww8)
          C2STEP(2, ww2, ww3, ww4, ww5, ww6, ww7, ww8, ww9)
          C2STEP(3, ww3, ww4, ww5, ww6, ww7, ww8, ww9, wwa)
          C2STEP(4, ww4, ww5, ww6, ww7, ww8, ww9, wwa, wwb)
          C2STEP(5, ww5, ww6, ww7, ww8, ww9, wwa, wwb, wwc)
          C2STEP(6, ww6, ww7, ww8, ww9, wwa, wwb, wwc, wwd)
          C2STEP(7, ww7, ww8, ww9, wwa, wwb, wwc, wwd, wwe)
          C2STEP(8, ww8, ww9, wwa, wwb, wwc, wwd, wwe, wwf)
          C2STEP(9, ww9, wwa, wwb, wwc, wwd, wwe, wwf, wwg)
#undef C2STEP
        }
        const float scA = s_s2f[c0], tbA = s_t2f[c0];
        const float scB = s_s2f[c0 + 8], tbB = s_t2f[c0 + 8];
        s_x2[c0][0][nl] = (lb + 0 < L2LEN) ? fmaf(fmaxf(y00, 0.f), scA, tbA) : 0.f;
        s_x2[c0][1][nl] = (lb + 1 < L2LEN) ? fmaf(fmaxf(y01, 0.f), scA, tbA) : 0.f;
        s_x2[c0][2][nl] = (lb + 2 < L2LEN) ? fmaf(fmaxf(y02, 0.f), scA, tbA) : 0.f;
        s_x2[c0][3][nl] = (lb + 3 < L2LEN) ? fmaf(fmaxf(y03, 0.f), scA, tbA) : 0.f;
        s_x2[c0][4][nl] = (lb + 4 < L2LEN) ? fmaf(fmaxf(y10, 0.f), scA, tbA) : 0.f;
        s_x2[c0][5][nl] = (lb + 5 < L2LEN) ? fmaf(fmaxf(y11, 0.f), scA, tbA) : 0.f;
        s_x2[c0][6][nl] = (lb + 6 < L2LEN) ? fmaf(fmaxf(y12, 0.f), scA, tbA) : 0.f;
        s_x2[c0][7][nl] = (lb + 7 < L2LEN) ? fmaf(fmaxf(y13, 0.f), scA, tbA) : 0.f;
        s_x2[c0 + 8][0][nl] = (lb + 0 < L2LEN) ? fmaf(fmaxf(y20, 0.f), scB, tbB) : 0.f;
        s_x2[c0 + 8][1][nl] = (lb + 1 < L2LEN) ? fmaf(fmaxf(y21, 0.f), scB, tbB) : 0.f;
        s_x2[c0 + 8][2][nl] = (lb + 2 < L2LEN) ? fmaf(fmaxf(y22, 0.f), scB, tbB) : 0.f;
        s_x2[c0 + 8][3][nl] = (lb + 3 < L2LEN) ? fmaf(fmaxf(y23, 0.f), scB, tbB) : 0.f;
        s_x2[c0 + 8][4][nl] = (lb + 4 < L2LEN) ? fmaf(fmaxf(y30, 0.f), scB, tbB) : 0.f;
        s_x2[c0 + 8][5][nl] = (lb + 5 < L2LEN) ? fmaf(fmaxf(y31, 0.f), scB, tbB) : 0.f;
        s_x2[c0 + 8][6][nl] = (lb + 6 < L2LEN) ? fmaf(fmaxf(y32, 0.f), scB, tbB) : 0.f;
        s_x2[c0 + 8][7][nl] = (lb + 7 < L2LEN) ? fmaf(fmaxf(y33, 0.f), scB, tbB) : 0.f;
      } else {
#pragma unroll
        for (int l = 0; l < 8; l++) {
          s_x2[c0][l][nl] = 0.f;
          s_x2[c0 + 8][l][nl] = 0.f;
        }
      }
    }
    // prologue: load fc weights for c=0 (overlaps conv2 barrier)
    float2 wld = make_float2(0.f, 0.f);
    if (doload && e_ld < EMBD) {
      const float* fp = fcw + (size_t)e_ld * DIMFC + lb + k2;  // c = 0
      if (lfull) wld = *reinterpret_cast<const float2*>(fp);
      else {
        wld.x = (lb + k2 < L2LEN) ? fp[0] : 0.f;
        wld.y = (lb + k2 + 1 < L2LEN) ? fp[1] : 0.f;
      }
    }
    __syncthreads();  // s_x2 visible
    if (doload) *reinterpret_cast<float2*>(&s_wT[0][e_ld][k2]) = wld;
    // fc c-loop: 1 barrier per c, next-c weights prefetched during compute
    for (int c = 0; c < 16; c++) {
      __syncthreads();  // s_wT[c&1] ready; prev readers of s_wT[(c+1)&1] done
      float2 wnext = make_float2(0.f, 0.f);
      if (c < 15 && doload && e_ld < EMBD) {
        const float* fp = fcw + (size_t)e_ld * DIMFC + (size_t)(c + 1) * L2LEN + lb + k2;
        if (lfull) wnext = *reinterpret_cast<const float2*>(fp);
        else {
          wnext.x = (lb + k2 < L2LEN) ? fp[0] : 0.f;
          wnext.y = (lb + k2 + 1 < L2LEN) ? fp[1] : 0.f;
        }
      }
      const int bsel = c & 1;
      const float2 xv0 = *reinterpret_cast<const float2*>(&s_x2[c][0][tn * 2]);
      const float2 xv1 = *reinterpret_cast<const float2*>(&s_x2[c][1][tn * 2]);
      const float2 xv2 = *reinterpret_cast<const float2*>(&s_x2[c][2][tn * 2]);
      const float2 xv3 = *reinterpret_cast<const float2*>(&s_x2[c][3][tn * 2]);
      const float2 xv4 = *reinterpret_cast<const float2*>(&s_x2[c][4][tn * 2]);
      const float2 xv5 = *reinterpret_cast<const float2*>(&s_x2[c][5][tn * 2]);
      const float2 xv6 = *reinterpret_cast<const float2*>(&s_x2[c][6][tn * 2]);
      const float2 xv7 = *reinterpret_cast<const float2*>(&s_x2[c][7][tn * 2]);
#pragma unroll
      for (int m = 0; m < 7; m++) {
        const float* wp = &s_wT[bsel][te + 16 * m][0];
        const float2 wv01 = *reinterpret_cast<const float2*>(&wp[0]);
        const float2 wv23 = *reinterpret_cast<const float2*>(&wp[2]);
        const float2 wv45 = *reinterpret_cast<const float2*>(&wp[4]);
        const float2 wv67 = *reinterpret_cast<const float2*>(&wp[6]);
        float a0 = 0.f, a1 = 0.f;
        a0 = fmaf(wv01.x, xv0.x, a0); a1 = fmaf(wv01.x, xv0.y, a1);
        a0 = fmaf(wv01.y, xv1.x, a0); a1 = fmaf(wv01.y, xv1.y, a1);
        a0 = fmaf(wv23.x, xv2.x, a0); a1 = fmaf(wv23.x, xv2.y, a1);
        a0 = fmaf(wv23.y, xv3.x, a0); a1 = fmaf(wv23.y, xv3.y, a1);
        a0 = fmaf(wv45.x, xv4.x, a0); a1 = fmaf(wv45.x, xv4.y, a1);
        a0 = fmaf(wv45.y, xv5.x, a0); a1 = fmaf(wv45.y, xv5.y, a1);
        a0 = fmaf(wv67.x, xv6.x, a0); a1 = fmaf(wv67.x, xv6.y, a1);
        a0 = fmaf(wv67.y, xv7.x, a0); a1 = fmaf(wv67.y, xv7.y, a1);
        acc[m][0] += (double)a0;
        acc[m][1] += (double)a1;
      }
      if (c < 15 && doload)
        *reinterpret_cast<float2*>(&s_wT[(c + 1) & 1][e_ld][k2]) = wnext;
    }
  }
  for (int m = 0; m < 7; m++) {
    int e = te + 16 * m;
    if (e < EMBD) {
      for (int q = 0; q < 2; q++) {
        int nl2 = tn * 2 + q;
        if (nl2 < 52) part[(((size_t)ks * 4 + nt) * 100 + e) * 52 + nl2] = (float)acc[m][q];
      }
    }
  }
}

// ---------------- K6: reduce split-K (f64), +bias, relu, bn3 -> x (f64) ----------------
__global__ __launch_bounds__(256) void k_bn3(const float* __restrict__ part,
                                             const float* __restrict__ fcb,
                                             const float* __restrict__ g3,
                                             const float* __restrict__ b3,
                                             double* __restrict__ xd) {
  const int e = blockIdx.x;
  const int n = threadIdx.x;
  double v = 0.0;
  if (n < NNODE) {
    int nt = n / 52, nl = n - nt * 52;
    const size_t stride = 4 * 100 * 52;
    const float* p = part + ((size_t)nt * 100 + e) * 52 + nl;
    for (int ks = 0; ks < NKS; ks++) v += (double)p[ks * stride];
    v = fmax(v + (double)fcb[e], 0.0);
  }
  __shared__ double redA[4], redB[4];
  __shared__ double s_m, s_sd;
  int lane = threadIdx.x & 63, wid = threadIdx.x >> 6;
  double w = waveReduceD(v);
  if (lane == 0) redA[wid] = w;
  __syncthreads();
  if (threadIdx.x == 0) s_m = (redA[0] + redA[1] + redA[2] + redA[3]) / 207.0;
  __syncthreads();
  double m = s_m;
  double d = (n < NNODE) ? (v - m) : 0.0;
  double wq = waveReduceD(d * d);
  if (lane == 0) redB[wid] = wq;
  __syncthreads();
  if (threadIdx.x == 0) s_sd = sqrt((redB[0] + redB[1] + redB[2] + redB[3]) / 207.0 + (double)BNEPS);
  __syncthreads();
  if (n < NNODE) xd[n * 100 + e] = (v - m) / s_sd * (double)g3[e] + (double)b3[e];
}

// ---------------- K7: ps = x@Ws^T, pr = x@Wr^T (f64) ----------------
__global__ void k_pspr(const double* __restrict__ xd, const float* __restrict__ wout,
                       double* __restrict__ psd, double* __restrict__ prd) {
  const int n = blockIdx.x;
  __shared__ double sx[100];
  if (threadIdx.x < 100) sx[threadIdx.x] = xd[n * 100 + threadIdx.x];
  __syncthreads();
  const int e = threadIdx.x;
  if (e < 100) {
    double a = 0.0, b = 0.0;
    for (int j = 0; j < 100; j++) {
      double xv = sx[j];
      a = fma(xv, (double)wout[e * 200 + j], a);
      b = fma(xv, (double)wout[e * 200 + 100 + j], b);
    }
    psd[n * 100 + e] = a;
    prd[n * 100 + e] = b;
  }
}

// ---------------- K8a: edge logits b0/b1 per pij (f64) + bern output ----------------
__global__ __launch_bounds__(256) void k_edge(const double* __restrict__ psd,
                                              const double* __restrict__ prd,
                                              const float* __restrict__ bo,
                                              const float* __restrict__ wc,
                                              const float* __restrict__ cb,
                                              double* __restrict__ bd,
                                              float* __restrict__ out) {
  const int pij = blockIdx.x * 256 + threadIdx.x;
  if (pij >= NSQ) return;
  const int i = pij / NNODE, j = pij - i * NNODE;
  const double* pri = prd + i * 100;
  const double* psj = psd + j * 100;
  double b0 = 0.0, b1 = 0.0;
  for (int e = 0; e < 100; e++) {
    double ed = fmax(pri[e] + psj[e] + (double)bo[e], 0.0);
    b0 = fma(ed, (double)wc[e], b0);
    b1 = fma(ed, (double)wc[100 + e], b1);
  }
  b0 += (double)cb[0];
  b1 += (double)cb[1];
  bd[pij * 2] = b0;
  bd[pij * 2 + 1] = b1;
  const float b0f = (float)b0, b1f = (float)b1;
  for (int b = 0; b < NBATCH; b++) {
    size_t base = (size_t)b * (2 * NSQ) + (size_t)pij * 2;
    out[base] = b0f;
    out[base + 1] = b1f;
  }
}

// ---------------- K8b: gumbel sample per (b,pij) ----------------
__global__ __launch_bounds__(256) void k_samp(const double* __restrict__ bd,
                                              float* __restrict__ out) {
  const int gid = blockIdx.x * 256 + threadIdx.x;
  if (gid >= NBATCH * NSQ) return;
  const int b = gid / NSQ;
  const int pij = gid - b * NSQ;
  const int i = pij / NNODE, j = pij - i * NNODE;
  const double b0 = bd[pij * 2], b1 = bd[pij * 2 + 1];
  uint32_t base = (uint32_t)b * (2u * NSQ) + (uint32_t)pij * 2u;
  float u0 = uniform_part(base);
  float u1 = uniform_part(base + 1u);
  double g0 = -log(-log((double)u0 + 1e-20) + 1e-20);
  double g1 = -log(-log((double)u1 + 1e-20) + 1e-20);
  float v = ((b0 + g0) >= (b1 + g1)) ? 1.0f : 0.0f;
  if (i == j) v = 0.f;
  out[O_SAMP + (size_t)b * NSQ + pij] = v;
}

extern "C" void kernel_launch(void* const* d_in, const int* in_sizes, int n_in,
                              void* d_out, int out_size, void* d_ws, size_t ws_size,
                              hipStream_t stream) {
  const float* hid = (const float*)d_in[0];
  const float* nf = (const float*)d_in[1];
  const float* c1w = (const float*)d_in[2];
  const float* c1b = (const float*)d_in[3];
  const float* c2w = (const float*)d_in[4];
  const float* c2b = (const float*)d_in[5];
  const float* g1 = (const float*)d_in[6];
  const float* b1 = (const float*)d_in[7];
  const float* g2 = (const float*)d_in[8];
  const float* b2 = (const float*)d_in[9];
  const float* fcw = (const float*)d_in[10];
  const float* fcb = (const float*)d_in[11];
  const float* g3 = (const float*)d_in[12];
  const float* b3 = (const float*)d_in[13];
  // d_in[14], d_in[15]: fc_mean_w / fc_mean_b are dead code in the reference
  const float* wout = (const float*)d_in[16];
  const float* bout = (const float*)d_in[17];
  const float* wc = (const float*)d_in[18];
  const float* cbb = (const float*)d_in[19];
  float* out = (float*)d_out;
  float* ws = (float*)d_ws;

  float* w_norm = ws + 0;                       // 3312 f
  float* w_sim = ws + 8192;                     // 685584 f
  float* w_p1 = ws + 704512;                    // 3008 f
  float* w_p2 = ws + 712704;                    // 158976 f (dead after k_red2)
  double* w_bd = (double*)(ws + 712704);        // 85698 d (reuses w_p2 region)
  double* w_foldd = (double*)(ws + 900096);     // 48 d
  float* w_part = ws + 1048576;                 // 125*4*100*52 = 2,600,000 f -> ends 3,648,576
  double* w_xd = (double*)(ws + 3648576);       // 20700 d -> ends 3,689,976
  double* w_psd = (double*)(ws + 3690000);      // 20700 d -> ends 3,731,400
  double* w_prd = (double*)(ws + 3731400);      // 20700 d -> ends 3,772,800 (~15.1 MB)

  // sim / knn branch
  k_copynorm<<<NBATCH * NNODE, 256, 0, stream>>>(hid, out, w_norm);
  k_sim<<<dim3(16, NBATCH), 512, 0, stream>>>(hid, w_norm, w_sim);
  k_topk<<<NBATCH, 1024, 0, stream>>>(w_sim, out);

  // conv -> fc -> edge branch
  k_c1stats<<<188, 256, 0, stream>>>(nf, c1w, c1b, w_p1);
  k_red1<<<1, 64, 0, stream>>>(w_p1, g1, b1, w_foldd);
  k_c2stats<<<dim3(24, NNODE), 256, 0, stream>>>(nf, c1w, c1b, c2w, c2b, w_foldd, w_p2);
  k_red2<<<1, 256, 0, stream>>>(w_p2, g2, b2, w_foldd);
  k_gemm<<<dim3(NKS, 4), 512, 0, stream>>>(nf, c1w, c1b, c2w, c2b, w_foldd, fcw, w_part);
  k_bn3<<<EMBD, 256, 0, stream>>>(w_part, fcb, g3, b3, w_xd);
  k_pspr<<<NNODE, 128, 0, stream>>>(w_xd, wout, w_psd, w_prd);
  k_edge<<<(NSQ + 255) / 256, 256, 0, stream>>>(w_psd, w_prd, bout, wc, cbb, w_bd, out);
  k_samp<<<(NBATCH * NSQ + 255) / 256, 256, 0, stream>>>(w_bd, out);
}

// Round 12
// 2729.514 us; speedup vs baseline: 4.0259x; 1.1068x over previous
//
#include <hip/hip_runtime.h>
#include <stdint.h>
#include <math.h>

#define NBATCH 16
#define NNODE 207
#define TLEN 23990
#define EMBD 100
#define L1LEN 23981   // T-9
#define L2LEN 23972   // T-18
#define DIMFC 383552  // 16*L2
#define DMEAN 16128   // P*D
#define NSQ 42849     // N*N
#define KSEL 2070     // K*N
#define BNEPS 1e-5f
#define NKS 125       // split-K chunks for k_gemm (l-chunk 192 = 24*8)
#define KHALF 8064    // k_sim split-K half

// output offsets (floats)
#define O_HID  1371168ull
#define O_KNN  54787104ull
#define O_SAMP 55472688ull

__device__ __forceinline__ float waveReduce(float v) {
#pragma unroll
  for (int o = 32; o > 0; o >>= 1) v += __shfl_down(v, o);
  return v;
}

__device__ __forceinline__ double waveReduceD(double v) {
#pragma unroll
  for (int o = 32; o > 0; o >>= 1) v += __shfl_down(v, o);
  return v;
}

__device__ __forceinline__ unsigned int sortableKey(float f) {
  unsigned int u = __float_as_uint(f);
  return (u & 0x80000000u) ? ~u : (u | 0x80000000u);
}

// JAX threefry2x32-20 with key (0, 42)
__device__ __forceinline__ void threefry(uint32_t x0, uint32_t x1, uint32_t& o0, uint32_t& o1) {
  const uint32_t k0 = 0u, k1 = 42u;
  const uint32_t k2 = k0 ^ k1 ^ 0x1BD11BDAu;
  x0 += k0; x1 += k1;
#define TFR(r) { x0 += x1; x1 = (x1 << r) | (x1 >> (32 - r)); x1 ^= x0; }
  TFR(13) TFR(15) TFR(26) TFR(6)   x0 += k1; x1 += k2 + 1u;
  TFR(17) TFR(29) TFR(16) TFR(24)  x0 += k2; x1 += k0 + 2u;
  TFR(13) TFR(15) TFR(26) TFR(6)   x0 += k0; x1 += k1 + 3u;
  TFR(17) TFR(29) TFR(16) TFR(24)  x0 += k1; x1 += k2 + 4u;
  TFR(13) TFR(15) TFR(26) TFR(6)   x0 += k2; x1 += k0 + 5u;
#undef TFR
  o0 = x0; o1 = x1;
}

// jax_threefry_partitionable bit stream: element i -> threefry(key,(0,i)), XOR-fold.
__device__ __forceinline__ float uniform_part(uint32_t m) {
  uint32_t o0, o1;
  threefry(0u, m, o0, o1);
  uint32_t bits = o0 ^ o1;
  return __uint_as_float((bits >> 9) | 0x3f800000u) - 1.0f;
}

// ---------------- K9: copy hidden -> out, row sumsq -> norms ----------------
__global__ __launch_bounds__(256) void k_copynorm(const float* __restrict__ h,
                                                  float* __restrict__ out,
                                                  float* __restrict__ norms) {
  const size_t row = blockIdx.x; // 0..3311
  const float4* src = reinterpret_cast<const float4*>(h + row * (size_t)DMEAN);
  float4* dst = reinterpret_cast<float4*>(out + O_HID + row * (size_t)DMEAN);
  float s = 0.f;
  for (int i = threadIdx.x; i < DMEAN / 4; i += 256) {
    float4 v = src[i];
    dst[i] = v;
    s += v.x * v.x + v.y * v.y + v.z * v.z + v.w * v.w;
  }
  __shared__ float red[4];
  float w = waveReduce(s);
  if ((threadIdx.x & 63) == 0) red[threadIdx.x >> 6] = w;
  __syncthreads();
  if (threadIdx.x == 0) norms[row] = sqrtf(red[0] + red[1] + red[2] + red[3]);
}

// ---------------- K10: sim partials = h @ h^T (A from global broadcast, B in LDS, split-K x2) ----------------
__global__ __launch_bounds__(256) void k_sim(const float* __restrict__ h,
                                             float* __restrict__ simp) {
  const int b = blockIdx.y;
  const int tile = blockIdx.x & 15;
  const int ks = blockIdx.x >> 4;     // 0/1 k-half
  const int ti = tile >> 2, tj = tile & 3;
  __shared__ float sB[32][64];
  const int tx = threadIdx.x & 15, ty = threadIdx.x >> 4;
  const float* hb = h + (size_t)b * NNODE * DMEAN;
  const int r0 = ti * 64 + ty * 4;
  const float* ap0 = hb + (size_t)min(r0 + 0, NNODE - 1) * DMEAN;
  const float* ap1 = hb + (size_t)min(r0 + 1, NNODE - 1) * DMEAN;
  const float* ap2 = hb + (size_t)min(r0 + 2, NNODE - 1) * DMEAN;
  const float* ap3 = hb + (size_t)min(r0 + 3, NNODE - 1) * DMEAN;
  const int scol = threadIdx.x >> 2;       // staging col 0..63
  const int sk = (threadIdx.x & 3) * 8;    // staging k offset
  const bool bvalid = (tj * 64 + scol) < NNODE;
  const float* bp = hb + (size_t)min(tj * 64 + scol, NNODE - 1) * DMEAN;
  float acc[4][4];
#pragma unroll
  for (int p = 0; p < 4; p++)
#pragma unroll
    for (int q = 0; q < 4; q++) acc[p][q] = 0.f;
  const int kbeg = ks * KHALF;
  const int kend = kbeg + KHALF;
  for (int k0 = kbeg; k0 < kend; k0 += 32) {
    __syncthreads();
    {
      float4 v1 = make_float4(0.f, 0.f, 0.f, 0.f), v2 = v1;
      if (bvalid) {
        v1 = *reinterpret_cast<const float4*>(bp + k0 + sk);
        v2 = *reinterpret_cast<const float4*>(bp + k0 + sk + 4);
      }
      sB[sk + 0][scol] = v1.x;
      sB[sk + 1][scol] = v1.y;
      sB[sk + 2][scol] = v1.z;
      sB[sk + 3][scol] = v1.w;
      sB[sk + 4][scol] = v2.x;
      sB[sk + 5][scol] = v2.y;
      sB[sk + 6][scol] = v2.z;
      sB[sk + 7][scol] = v2.w;
    }
    __syncthreads();
#pragma unroll
    for (int g = 0; g < 8; g++) {
      const int kk = k0 + g * 4;
      const float4 a0 = *reinterpret_cast<const float4*>(ap0 + kk);
      const float4 a1 = *reinterpret_cast<const float4*>(ap1 + kk);
      const float4 a2 = *reinterpret_cast<const float4*>(ap2 + kk);
      const float4 a3 = *reinterpret_cast<const float4*>(ap3 + kk);
      const float4 b0 = *reinterpret_cast<const float4*>(&sB[g * 4 + 0][tx * 4]);
      const float4 b1 = *reinterpret_cast<const float4*>(&sB[g * 4 + 1][tx * 4]);
      const float4 b2 = *reinterpret_cast<const float4*>(&sB[g * 4 + 2][tx * 4]);
      const float4 b3 = *reinterpret_cast<const float4*>(&sB[g * 4 + 3][tx * 4]);
      // s = 0 (k = kk)
      acc[0][0] = fmaf(a0.x, b0.x, acc[0][0]); acc[0][1] = fmaf(a0.x, b0.y, acc[0][1]);
      acc[0][2] = fmaf(a0.x, b0.z, acc[0][2]); acc[0][3] = fmaf(a0.x, b0.w, acc[0][3]);
      acc[1][0] = fmaf(a1.x, b0.x, acc[1][0]); acc[1][1] = fmaf(a1.x, b0.y, acc[1][1]);
      acc[1][2] = fmaf(a1.x, b0.z, acc[1][2]); acc[1][3] = fmaf(a1.x, b0.w, acc[1][3]);
      acc[2][0] = fmaf(a2.x, b0.x, acc[2][0]); acc[2][1] = fmaf(a2.x, b0.y, acc[2][1]);
      acc[2][2] = fmaf(a2.x, b0.z, acc[2][2]); acc[2][3] = fmaf(a2.x, b0.w, acc[2][3]);
      acc[3][0] = fmaf(a3.x, b0.x, acc[3][0]); acc[3][1] = fmaf(a3.x, b0.y, acc[3][1]);
      acc[3][2] = fmaf(a3.x, b0.z, acc[3][2]); acc[3][3] = fmaf(a3.x, b0.w, acc[3][3]);
      // s = 1
      acc[0][0] = fmaf(a0.y, b1.x, acc[0][0]); acc[0][1] = fmaf(a0.y, b1.y, acc[0][1]);
      acc[0][2] = fmaf(a0.y, b1.z, acc[0][2]); acc[0][3] = fmaf(a0.y, b1.w, acc[0][3]);
      acc[1][0] = fmaf(a1.y, b1.x, acc[1][0]); acc[1][1] = fmaf(a1.y, b1.y, acc[1][1]);
      acc[1][2] = fmaf(a1.y, b1.z, acc[1][2]); acc[1][3] = fmaf(a1.y, b1.w, acc[1][3]);
      acc[2][0] = fmaf(a2.y, b1.x, acc[2][0]); acc[2][1] = fmaf(a2.y, b1.y, acc[2][1]);
      acc[2][2] = fmaf(a2.y, b1.z, acc[2][2]); acc[2][3] = fmaf(a2.y, b1.w, acc[2][3]);
      acc[3][0] = fmaf(a3.y, b1.x, acc[3][0]); acc[3][1] = fmaf(a3.y, b1.y, acc[3][1]);
      acc[3][2] = fmaf(a3.y, b1.z, acc[3][2]); acc[3][3] = fmaf(a3.y, b1.w, acc[3][3]);
      // s = 2
      acc[0][0] = fmaf(a0.z, b2.x, acc[0][0]); acc[0][1] = fmaf(a0.z, b2.y, acc[0][1]);
      acc[0][2] = fmaf(a0.z, b2.z, acc[0][2]); acc[0][3] = fmaf(a0.z, b2.w, acc[0][3]);
      acc[1][0] = fmaf(a1.z, b2.x, acc[1][0]); acc[1][1] = fmaf(a1.z, b2.y, acc[1][1]);
      acc[1][2] = fmaf(a1.z, b2.z, acc[1][2]); acc[1][3] = fmaf(a1.z, b2.w, acc[1][3]);
      acc[2][0] = fmaf(a2.z, b2.x, acc[2][0]); acc[2][1] = fmaf(a2.z, b2.y, acc[2][1]);
      acc[2][2] = fmaf(a2.z, b2.z, acc[2][2]); acc[2][3] = fmaf(a2.z, b2.w, acc[2][3]);
      acc[3][0] = fmaf(a3.z, b2.x, acc[3][0]); acc[3][1] = fmaf(a3.z, b2.y, acc[3][1]);
      acc[3][2] = fmaf(a3.z, b2.z, acc[3][2]); acc[3][3] = fmaf(a3.z, b2.w, acc[3][3]);
      // s = 3
      acc[0][0] = fmaf(a0.w, b3.x, acc[0][0]); acc[0][1] = fmaf(a0.w, b3.y, acc[0][1]);
      acc[0][2] = fmaf(a0.w, b3.z, acc[0][2]); acc[0][3] = fmaf(a0.w, b3.w, acc[0][3]);
      acc[1][0] = fmaf(a1.w, b3.x, acc[1][0]); acc[1][1] = fmaf(a1.w, b3.y, acc[1][1]);
      acc[1][2] = fmaf(a1.w, b3.z, acc[1][2]); acc[1][3] = fmaf(a1.w, b3.w, acc[1][3]);
      acc[2][0] = fmaf(a2.w, b3.x, acc[2][0]); acc[2][1] = fmaf(a2.w, b3.y, acc[2][1]);
      acc[2][2] = fmaf(a2.w, b3.z, acc[2][2]); acc[2][3] = fmaf(a2.w, b3.w, acc[2][3]);
      acc[3][0] = fmaf(a3.w, b3.x, acc[3][0]); acc[3][1] = fmaf(a3.w, b3.y, acc[3][1]);
      acc[3][2] = fmaf(a3.w, b3.z, acc[3][2]); acc[3][3] = fmaf(a3.w, b3.w, acc[3][3]);
    }
  }
  float* op = simp + ((size_t)ks * NBATCH + b) * NSQ;
#pragma unroll
  for (int p = 0; p < 4; p++) {
    int ii = r0 + p;
    if (ii < NNODE) {
#pragma unroll
      for (int q = 0; q < 4; q++) {
        int jj = tj * 64 + tx * 4 + q;
        if (jj < NNODE) op[ii * NNODE + jj] = acc[p][q];
      }
    }
  }
}

// ---------------- K10b: combine halves + normalize: sim = (p0+p1)/(d_i*d_j) ----------------
__global__ __launch_bounds__(256) void k_simc(const float* __restrict__ simp,
                                              const float* __restrict__ norms,
                                              float* __restrict__ sim) {
  const int gid = blockIdx.x * 256 + threadIdx.x;
  if (gid >= NBATCH * NSQ) return;
  const int b = gid / NSQ;
  const int rem = gid - b * NSQ;
  const int i = rem / NNODE, j = rem - i * NNODE;
  float s = simp[gid] + simp[(size_t)NBATCH * NSQ + gid];
  float di = norms[b * NNODE + i] + 1e-10f;
  float dj = norms[b * NNODE + j] + 1e-10f;
  sim[gid] = s / (di * dj);
}

// ---------------- K11: exact top-k (radix select + index-ordered tie fill), 1024 thr ----------------
__global__ __launch_bounds__(1024) void k_topk(const float* __restrict__ sim,
                                               float* __restrict__ out) {
  const int b = blockIdx.x;
  const float* s = sim + (size_t)b * NSQ;
  float* knn = out + O_KNN + (size_t)b * NSQ;
  __shared__ unsigned int hist[256];
  __shared__ unsigned int cnts[1024];
  __shared__ unsigned int sh_prefix, sh_kneed;
  if (threadIdx.x == 0) { sh_prefix = 0u; sh_kneed = KSEL; }
  __syncthreads();
  const int lo = threadIdx.x * 42;
  const int hi = min(lo + 42, NSQ);
  for (int pass = 0; pass < 4; pass++) {
    const int shift = 24 - pass * 8;
    if (threadIdx.x < 256) hist[threadIdx.x] = 0u;
    __syncthreads();
    unsigned int pref = sh_prefix;
    unsigned int hmask = (pass == 0) ? 0u : (0xFFFFFFFFu << (shift + 8));
    for (int i = lo; i < hi; i++) {
      unsigned int key = sortableKey(s[i]);
      if ((key & hmask) == pref) atomicAdd(&hist[(key >> shift) & 255], 1u);
    }
    __syncthreads();
    if (threadIdx.x == 0) {
      unsigned int need = sh_kneed, cum = 0;
      for (int bkt = 255; bkt >= 0; bkt--) {
        unsigned int c = hist[bkt];
        if (cum + c >= need) {
          sh_prefix = pref | ((unsigned int)bkt << shift);
          sh_kneed = need - cum;
          break;
        }
        cum += c;
      }
    }
    __syncthreads();
  }
  const unsigned int kth = sh_prefix;
  const unsigned int need_eq = sh_kneed;
  unsigned int myeq = 0;
  for (int i = lo; i < hi; i++) {
    float v = s[i];
    unsigned int key = sortableKey(v);
    float o = 0.f;
    if (key > kth) {
      int ii = i / NNODE, jj = i - ii * NNODE;
      o = (v != 0.f && ii != jj) ? 1.f : 0.f;
    } else if (key == kth) {
      myeq++;
    }
    knn[i] = o;
  }
  cnts[threadIdx.x] = myeq;
  __syncthreads();
  if (threadIdx.x == 0) {
    unsigned int run = 0;
    for (int t = 0; t < 1024; t++) { unsigned int c = cnts[t]; cnts[t] = run; run += c; }
  }
  __syncthreads();
  unsigned int rank = cnts[threadIdx.x];
  for (int i = lo; i < hi && rank < need_eq; i++) {
    float v = s[i];
    if (sortableKey(v) == kth) {
      if (rank < need_eq) {
        int ii = i / NNODE, jj = i - ii * NNODE;
        knn[i] = (v != 0.f && ii != jj) ? 1.f : 0.f;
      }
      rank++;
    }
  }
}

// ---------------- K1: conv1+relu stats partials ----------------
__global__ __launch_bounds__(256) void k_c1stats(const float* __restrict__ nf,
                                                 const float* __restrict__ c1w,
                                                 const float* __restrict__ c1b,
                                                 float* __restrict__ part1) {
  __shared__ float sw[80], sb[8];
  if (threadIdx.x < 80) sw[threadIdx.x] = c1w[threadIdx.x];
  if (threadIdx.x < 8) sb[threadIdx.x] = c1b[threadIdx.x];
  __syncthreads();
  const int t0 = blockIdx.x * 128;
  const int cnt = min(128, L1LEN - t0);
  float s[8], sq[8];
#pragma unroll
  for (int c = 0; c < 8; c++) { s[c] = 0.f; sq[c] = 0.f; }
  for (int idx = threadIdx.x; idx < cnt * NNODE; idx += 256) {
    int tl = idx / NNODE;
    int n = idx - tl * NNODE;
    const float* p = nf + (size_t)(t0 + tl) * NNODE + n;
    float in[10];
#pragma unroll
    for (int k = 0; k < 10; k++) in[k] = p[k * NNODE];
#pragma unroll
    for (int c = 0; c < 8; c++) {
      float a = sb[c];
#pragma unroll
      for (int k = 0; k < 10; k++) a = fmaf(sw[c * 10 + k], in[k], a);
      a = fmaxf(a, 0.f);
      s[c] += a;
      sq[c] = fmaf(a, a, sq[c]);
    }
  }
  __shared__ float red[4][16];
  int lane = threadIdx.x & 63, wv = threadIdx.x >> 6;
#pragma unroll
  for (int c = 0; c < 8; c++) {
    float a = waveReduce(s[c]);
    float q = waveReduce(sq[c]);
    if (lane == 0) { red[wv][c * 2] = a; red[wv][c * 2 + 1] = q; }
  }
  __syncthreads();
  if (threadIdx.x < 16)
    part1[blockIdx.x * 16 + threadIdx.x] =
        red[0][threadIdx.x] + red[1][threadIdx.x] + red[2][threadIdx.x] + red[3][threadIdx.x];
}

// ---------------- K2: reduce bn1 stats (f64) -> a1/be1 doubles ----------------
__global__ void k_red1(const float* __restrict__ part1, const float* __restrict__ g1,
                       const float* __restrict__ b1, double* __restrict__ foldd) {
  __shared__ double sums[16];
  if (threadIdx.x < 16) {
    double s = 0.0;
    for (int i = 0; i < 188; i++) s += (double)part1[i * 16 + threadIdx.x];
    sums[threadIdx.x] = s;
  }
  __syncthreads();
  if (threadIdx.x < 8) {
    const double cnt = 207.0 * 23981.0;
    int c = threadIdx.x;
    double m = sums[c * 2] / cnt;
    double ex2 = sums[c * 2 + 1] / cnt;
    double var = ex2 - m * m;
    double sc = (double)g1[c] / sqrt(var + (double)BNEPS);
    foldd[c] = sc;            // a1
    foldd[8 + c] = (double)b1[c] - m * sc;  // be1
  }
}

// ---------------- K3: conv2+relu stats partials ----------------
__global__ __launch_bounds__(256) void k_c2stats(const float* __restrict__ nf,
                                                 const float* __restrict__ c1w,
                                                 const float* __restrict__ c1b,
                                                 const float* __restrict__ c2w,
                                                 const float* __restrict__ c2b,
                                                 const double* __restrict__ foldd,
                                                 float* __restrict__ part2) {
  const int n = blockIdx.y;
  const int l0 = blockIdx.x * 1024;
  const int len = min(1024, L2LEN - l0);
  __shared__ float s_nf[1042];
  __shared__ float s_o1[8][1034];
  __shared__ float s_w2t[1280];
  __shared__ float s_b2[16];
  __shared__ float s_c1w[80], s_c1b[8];
  __shared__ float s_a1[8], s_be1[8];
  for (int i = threadIdx.x; i < 1280; i += 256) {
    int co = i / 80, r = i - co * 80;
    s_w2t[r * 16 + co] = c2w[i];
  }
  if (threadIdx.x < 16) s_b2[threadIdx.x] = c2b[threadIdx.x];
  if (threadIdx.x < 80) s_c1w[threadIdx.x] = c1w[threadIdx.x];
  if (threadIdx.x < 8) {
    s_c1b[threadIdx.x] = c1b[threadIdx.x];
    s_a1[threadIdx.x] = (float)foldd[threadIdx.x];
    s_be1[threadIdx.x] = (float)foldd[8 + threadIdx.x];
  }
  __syncthreads();
  const int nfl = len + 18;
  for (int i = threadIdx.x; i < nfl; i += 256) s_nf[i] = nf[(size_t)(l0 + i) * NNODE + n];
  __syncthreads();
  const int o1l = len + 9;
  for (int i = threadIdx.x; i < 8 * o1l; i += 256) {
    int c = i / o1l, t = i - c * o1l;
    float a = s_c1b[c];
#pragma unroll
    for (int k = 0; k < 10; k++) a = fmaf(s_c1w[c * 10 + k], s_nf[t + k], a);
    s_o1[c][t] = fmaxf(a, 0.f) * s_a1[c] + s_be1[c];
  }
  __syncthreads();
  const int co = threadIdx.x & 15, lg = threadIdx.x >> 4;
  float sum = 0.f, ssq = 0.f;
  for (int pass = 0; pass < 4; pass++) {
    int lb = pass * 256 + lg * 16;
    if (lb >= len) continue;
    int nl = min(16, len - lb);
    float y[16];
#pragma unroll
    for (int l = 0; l < 16; l++) y[l] = s_b2[co];
#pragma unroll
    for (int ci = 0; ci < 8; ci++) {
      float win[25];
#pragma unroll
      for (int w = 0; w < 25; w++) win[w] = s_o1[ci][lb + w];
#pragma unroll
      for (int k = 0; k < 10; k++) {
        float wv = s_w2t[(ci * 10 + k) * 16 + co];
#pragma unroll
        for (int l = 0; l < 16; l++) y[l] = fmaf(wv, win[l + k], y[l]);
      }
    }
#pragma unroll
    for (int l = 0; l < 16; l++) {
      if (l < nl) {
        float v = fmaxf(y[l], 0.f);
        sum += v;
        ssq = fmaf(v, v, ssq);
      }
    }
  }
  __shared__ float rs[16][16], rq[16][16];
  rs[lg][co] = sum;
  rq[lg][co] = ssq;
  __syncthreads();
  if (threadIdx.x < 16) {
    float a = 0.f, q = 0.f;
    for (int g = 0; g < 16; g++) { a += rs[g][threadIdx.x]; q += rq[g][threadIdx.x]; }
    int blk = blockIdx.y * gridDim.x + blockIdx.x;
    part2[blk * 32 + threadIdx.x * 2] = a;
    part2[blk * 32 + threadIdx.x * 2 + 1] = q;
  }
}

// ---------------- K4: reduce bn2 stats (f64) -> s2/t2 doubles ----------------
__global__ void k_red2(const float* __restrict__ part2, const float* __restrict__ g2,
                       const float* __restrict__ b2, double* __restrict__ foldd) {
  __shared__ double acc8[8][32];
  const int grp = threadIdx.x >> 5, v = threadIdx.x & 31;
  double s = 0.0;
  for (int i = grp; i < 4968; i += 8) s += (double)part2[i * 32 + v];
  acc8[grp][v] = s;
  __syncthreads();
  if (threadIdx.x < 32) {
    double t = 0.0;
    for (int g = 0; g < 8; g++) t += acc8[g][threadIdx.x];
    acc8[0][threadIdx.x] = t;
  }
  __syncthreads();
  if (threadIdx.x < 16) {
    const double cnt = 207.0 * 23972.0;
    int c = threadIdx.x;
    double m = acc8[0][c * 2] / cnt;
    double ex2 = acc8[0][c * 2 + 1] / cnt;
    double var = ex2 - m * m;
    double sc = (double)g2[c] / sqrt(var + (double)BNEPS);
    foldd[16 + c] = sc;                       // s2
    foldd[32 + c] = (double)b2[c] - m * sc;   // t2
  }
}

// ---------------- K5: fused conv1->conv2->bn2->fc GEMM (balanced 500 blocks, dbuf fc) ----------------
__global__ __launch_bounds__(512, 2) void k_gemm(const float* __restrict__ nf,
                                                 const float* __restrict__ c1w,
                                                 const float* __restrict__ c1b,
                                                 const float* __restrict__ c2w,
                                                 const float* __restrict__ c2b,
                                                 const double* __restrict__ foldd,
                                                 const float* __restrict__ fcw,
                                                 float* __restrict__ part) {
  const int ks = blockIdx.x;  // 0..124 l-chunk of 192
  const int nt = blockIdx.y;  // 0..3  n-tile of 52
  const int l0 = ks * 192;
  const int n0 = nt * 52;

  __shared__ float s_nf[26][52];
  __shared__ float s_o1[8][17][52];   // bn1-applied conv1 (f32)
  __shared__ float s_x2[16][8][64];   // bn2-applied conv2 (f32)
  __shared__ float s_wT[2][112][10];  // fc weights [buf][e][kk]
  __shared__ float s_w2t[1280];
  __shared__ float s_c1w[80], s_c1b[8], s_c2b[16];
  __shared__ float s_a1f[8], s_be1f[8], s_s2f[16], s_t2f[16];

  for (int i = threadIdx.x; i < 1280; i += 512) {
    int co = i / 80, r = i - co * 80;
    s_w2t[r * 16 + co] = c2w[i];
  }
  if (threadIdx.x < 80) s_c1w[threadIdx.x] = c1w[threadIdx.x];
  if (threadIdx.x < 8) {
    s_c1b[threadIdx.x] = c1b[threadIdx.x];
    s_a1f[threadIdx.x] = (float)foldd[threadIdx.x];
    s_be1f[threadIdx.x] = (float)foldd[8 + threadIdx.x];
  }
  if (threadIdx.x < 16) {
    s_c2b[threadIdx.x] = c2b[threadIdx.x];
    s_s2f[threadIdx.x] = (float)foldd[16 + threadIdx.x];
    s_t2f[threadIdx.x] = (float)foldd[32 + threadIdx.x];
  }

  double acc[7][2];
#pragma unroll
  for (int m = 0; m < 7; m++)
#pragma unroll
    for (int q = 0; q < 2; q++) acc[m][q] = 0.0;

  const int te = threadIdx.x & 15;   // e-lane
  const int tn = threadIdx.x >> 4;   // 0..31
  const int nl = threadIdx.x & 63;   // conv2 node lane
  const int c0 = (threadIdx.x >> 6) & 7;  // conv2 co base
  const bool doload = threadIdx.x < 448;  // fc staging lanes
  const int e_ld = threadIdx.x >> 2;      // 0..111
  const int k2 = (threadIdx.x & 3) * 2;   // 0,2,4,6

  for (int ls = 0; ls < 24; ls++) {
    const int lb = l0 + ls * 8;
    if (lb >= L2LEN) break;
    const bool lfull = (lb + 8 <= L2LEN);
    for (int i = threadIdx.x; i < 26 * 52; i += 512) {
      int r = i / 52, cc = i - r * 52;
      int t = lb + r, n = n0 + cc;
      float v = 0.f;
      if (t < TLEN && n < NNODE) v = nf[(size_t)t * NNODE + n];
      s_nf[r][cc] = v;
    }
    __syncthreads();
    // conv1 + bn1 (f32)
    for (int i = threadIdx.x; i < 8 * 17 * 52; i += 512) {
      int c = i / (17 * 52);
      int rem = i - c * 17 * 52;
      int t = rem / 52, n = rem - t * 52;
      float a = s_c1b[c];
#pragma unroll
      for (int k = 0; k < 10; k++) a = fmaf(s_c1w[c * 10 + k], s_nf[t + k][n], a);
      s_o1[c][t][n] = fmaxf(a, 0.f) * s_a1f[c] + s_be1f[c];
    }
    __syncthreads();
    // conv2 + relu + bn2 (f32, named scalars, shared 17-wide window)
    {
      const bool valid = (nl < 52) && (n0 + nl < NNODE);
      if (valid) {
        const float bA = s_c2b[c0], bB = s_c2b[c0 + 8];
        float y00 = bA, y01 = bA, y02 = bA, y03 = bA;
        float y10 = bA, y11 = bA, y12 = bA, y13 = bA;
        float y20 = bB, y21 = bB, y22 = bB, y23 = bB;
        float y30 = bB, y31 = bB, y32 = bB, y33 = bB;
        for (int ci = 0; ci < 8; ci++) {
          float ww0 = s_o1[ci][0][nl],  ww1 = s_o1[ci][1][nl],  ww2 = s_o1[ci][2][nl];
          float ww3 = s_o1[ci][3][nl],  ww4 = s_o1[ci][4][nl],  ww5 = s_o1[ci][5][nl];
          float ww6 = s_o1[ci][6][nl],  ww7 = s_o1[ci][7][nl],  ww8 = s_o1[ci][8][nl];
          float ww9 = s_o1[ci][9][nl],  wwa = s_o1[ci][10][nl], wwb = s_o1[ci][11][nl];
          float wwc = s_o1[ci][12][nl], wwd = s_o1[ci][13][nl], wwe = s_o1[ci][14][nl];
          float wwf = s_o1[ci][15][nl], wwg = s_o1[ci][16][nl];
          const float* wpA = &s_w2t[ci * 160 + c0];
          const float* wpB = wpA + 8;
          float v, u;
#define C2STEP(K, A0, A1, A2, A3, B0, B1, B2, B3)                                   \
          v = wpA[(K) * 16]; u = wpB[(K) * 16];                                     \
          y00 = fmaf(v, A0, y00); y01 = fmaf(v, A1, y01);                           \
          y02 = fmaf(v, A2, y02); y03 = fmaf(v, A3, y03);                           \
          y10 = fmaf(v, B0, y10); y11 = fmaf(v, B1, y11);                           \
          y12 = fmaf(v, B2, y12); y13 = fmaf(v, B3, y13);                           \
          y20 = fmaf(u, A0, y20); y21 = fmaf(u, A1, y21);                           \
          y22 = fmaf(u, A2, y22); y23 = fmaf(u, A3, y23);                           \
          y30 = fmaf(u, B0, y30); y31 = fmaf(u, B1, y31);                           \
          y32 = fmaf(u, B2, y32); y33 = fmaf(u, B3, y33);
          C2STEP(0, ww0, ww1, ww2, ww3, ww4, ww5, ww6, ww7)
          C2STEP(1, ww1, ww2, ww3, ww4, ww5, ww6, ww7, ww8)
          C2STEP(2, ww2, ww3, ww4, ww5, ww6, ww7, ww8, ww9)
          C2STEP(3, ww3, ww4, ww5, ww6, ww7, ww8, ww9, wwa)
          C2STEP(4, ww4, ww5, ww6, ww7, ww8, ww9, wwa, wwb)
          C2STEP(5, ww5, ww6, ww7, ww8, ww9, wwa, wwb, wwc)
          C2STEP(6, ww6, ww7, ww8, ww9, wwa, wwb, wwc, wwd)
          C2STEP(7, ww7, ww8, ww9, wwa, wwb, wwc, wwd, wwe)
          C2STEP(8, ww8, ww9, wwa, wwb, wwc, wwd, wwe, wwf)
          C2STEP(9, ww9, wwa, wwb, wwc, wwd, wwe, wwf, wwg)
#undef C2STEP
        }
        const float scA = s_s2f[c0], tbA = s_t2f[c0];
        const float scB = s_s2f[c0 + 8], tbB = s_t2f[c0 + 8];
        s_x2[c0][0][nl] = (lb + 0 < L2LEN) ? fmaf(fmaxf(y00, 0.f), scA, tbA) : 0.f;
        s_x2[c0][1][nl] = (lb + 1 < L2LEN) ? fmaf(fmaxf(y01, 0.f), scA, tbA) : 0.f;
        s_x2[c0][2][nl] = (lb + 2 < L2LEN) ? fmaf(fmaxf(y02, 0.f), scA, tbA) : 0.f;
        s_x2[c0][3][nl] = (lb + 3 < L2LEN) ? fmaf(fmaxf(y03, 0.f), scA, tbA) : 0.f;
        s_x2[c0][4][nl] = (lb + 4 < L2LEN) ? fmaf(fmaxf(y10, 0.f), scA, tbA) : 0.f;
        s_x2[c0][5][nl] = (lb + 5 < L2LEN) ? fmaf(fmaxf(y11, 0.f), scA, tbA) : 0.f;
        s_x2[c0][6][nl] = (lb + 6 < L2LEN) ? fmaf(fmaxf(y12, 0.f), scA, tbA) : 0.f;
        s_x2[c0][7][nl] = (lb + 7 < L2LEN) ? fmaf(fmaxf(y13, 0.f), scA, tbA) : 0.f;
        s_x2[c0 + 8][0][nl] = (lb + 0 < L2LEN) ? fmaf(fmaxf(y20, 0.f), scB, tbB) : 0.f;
        s_x2[c0 + 8][1][nl] = (lb + 1 < L2LEN) ? fmaf(fmaxf(y21, 0.f), scB, tbB) : 0.f;
        s_x2[c0 + 8][2][nl] = (lb + 2 < L2LEN) ? fmaf(fmaxf(y22, 0.f), scB, tbB) : 0.f;
        s_x2[c0 + 8][3][nl] = (lb + 3 < L2LEN) ? fmaf(fmaxf(y23, 0.f), scB, tbB) : 0.f;
        s_x2[c0 + 8][4][nl] = (lb + 4 < L2LEN) ? fmaf(fmaxf(y30, 0.f), scB, tbB) : 0.f;
        s_x2[c0 + 8][5][nl] = (lb + 5 < L2LEN) ? fmaf(fmaxf(y31, 0.f), scB, tbB) : 0.f;
        s_x2[c0 + 8][6][nl] = (lb + 6 < L2LEN) ? fmaf(fmaxf(y32, 0.f), scB, tbB) : 0.f;
        s_x2[c0 + 8][7][nl] = (lb + 7 < L2LEN) ? fmaf(fmaxf(y33, 0.f), scB, tbB) : 0.f;
      } else {
#pragma unroll
        for (int l = 0; l < 8; l++) {
          s_x2[c0][l][nl] = 0.f;
          s_x2[c0 + 8][l][nl] = 0.f;
        }
      }
    }
    // prologue: load fc weights for c=0 (overlaps conv2 barrier)
    float2 wld = make_float2(0.f, 0.f);
    if (doload && e_ld < EMBD) {
      const float* fp = fcw + (size_t)e_ld * DIMFC + lb + k2;  // c = 0
      if (lfull) wld = *reinterpret_cast<const float2*>(fp);
      else {
        wld.x = (lb + k2 < L2LEN) ? fp[0] : 0.f;
        wld.y = (lb + k2 + 1 < L2LEN) ? fp[1] : 0.f;
      }
    }
    __syncthreads();  // s_x2 visible
    if (doload) *reinterpret_cast<float2*>(&s_wT[0][e_ld][k2]) = wld;
    // fc c-loop: 1 barrier per c, next-c weights prefetched during compute
    for (int c = 0; c < 16; c++) {
      __syncthreads();  // s_wT[c&1] ready; prev readers of s_wT[(c+1)&1] done
      float2 wnext = make_float2(0.f, 0.f);
      if (c < 15 && doload && e_ld < EMBD) {
        const float* fp = fcw + (size_t)e_ld * DIMFC + (size_t)(c + 1) * L2LEN + lb + k2;
        if (lfull) wnext = *reinterpret_cast<const float2*>(fp);
        else {
          wnext.x = (lb + k2 < L2LEN) ? fp[0] : 0.f;
          wnext.y = (lb + k2 + 1 < L2LEN) ? fp[1] : 0.f;
        }
      }
      const int bsel = c & 1;
      const float2 xv0 = *reinterpret_cast<const float2*>(&s_x2[c][0][tn * 2]);
      const float2 xv1 = *reinterpret_cast<const float2*>(&s_x2[c][1][tn * 2]);
      const float2 xv2 = *reinterpret_cast<const float2*>(&s_x2[c][2][tn * 2]);
      const float2 xv3 = *reinterpret_cast<const float2*>(&s_x2[c][3][tn * 2]);
      const float2 xv4 = *reinterpret_cast<const float2*>(&s_x2[c][4][tn * 2]);
      const float2 xv5 = *reinterpret_cast<const float2*>(&s_x2[c][5][tn * 2]);
      const float2 xv6 = *reinterpret_cast<const float2*>(&s_x2[c][6][tn * 2]);
      const float2 xv7 = *reinterpret_cast<const float2*>(&s_x2[c][7][tn * 2]);
#pragma unroll
      for (int m = 0; m < 7; m++) {
        const float* wp = &s_wT[bsel][te + 16 * m][0];
        const float2 wv01 = *reinterpret_cast<const float2*>(&wp[0]);
        const float2 wv23 = *reinterpret_cast<const float2*>(&wp[2]);
        const float2 wv45 = *reinterpret_cast<const float2*>(&wp[4]);
        const float2 wv67 = *reinterpret_cast<const float2*>(&wp[6]);
        float a0 = 0.f, a1 = 0.f;
        a0 = fmaf(wv01.x, xv0.x, a0); a1 = fmaf(wv01.x, xv0.y, a1);
        a0 = fmaf(wv01.y, xv1.x, a0); a1 = fmaf(wv01.y, xv1.y, a1);
        a0 = fmaf(wv23.x, xv2.x, a0); a1 = fmaf(wv23.x, xv2.y, a1);
        a0 = fmaf(wv23.y, xv3.x, a0); a1 = fmaf(wv23.y, xv3.y, a1);
        a0 = fmaf(wv45.x, xv4.x, a0); a1 = fmaf(wv45.x, xv4.y, a1);
        a0 = fmaf(wv45.y, xv5.x, a0); a1 = fmaf(wv45.y, xv5.y, a1);
        a0 = fmaf(wv67.x, xv6.x, a0); a1 = fmaf(wv67.x, xv6.y, a1);
        a0 = fmaf(wv67.y, xv7.x, a0); a1 = fmaf(wv67.y, xv7.y, a1);
        acc[m][0] += (double)a0;
        acc[m][1] += (double)a1;
      }
      if (c < 15 && doload)
        *reinterpret_cast<float2*>(&s_wT[(c + 1) & 1][e_ld][k2]) = wnext;
    }
  }
  for (int m = 0; m < 7; m++) {
    int e = te + 16 * m;
    if (e < EMBD) {
      for (int q = 0; q < 2; q++) {
        int nl2 = tn * 2 + q;
        if (nl2 < 52) part[(((size_t)ks * 4 + nt) * 100 + e) * 52 + nl2] = (float)acc[m][q];
      }
    }
  }
}

// ---------------- K6: reduce split-K (f64), +bias, relu, bn3 -> x (f64) ----------------
__global__ __launch_bounds__(256) void k_bn3(const float* __restrict__ part,
                                             const float* __restrict__ fcb,
                                             const float* __restrict__ g3,
                                             const float* __restrict__ b3,
                                             double* __restrict__ xd) {
  const int e = blockIdx.x;
  const int n = threadIdx.x;
  double v = 0.0;
  if (n < NNODE) {
    int nt = n / 52, nl = n - nt * 52;
    const size_t stride = 4 * 100 * 52;
    const float* p = part + ((size_t)nt * 100 + e) * 52 + nl;
    for (int ks = 0; ks < NKS; ks++) v += (double)p[ks * stride];
    v = fmax(v + (double)fcb[e], 0.0);
  }
  __shared__ double redA[4], redB[4];
  __shared__ double s_m, s_sd;
  int lane = threadIdx.x & 63, wid = threadIdx.x >> 6;
  double w = waveReduceD(v);
  if (lane == 0) redA[wid] = w;
  __syncthreads();
  if (threadIdx.x == 0) s_m = (redA[0] + redA[1] + redA[2] + redA[3]) / 207.0;
  __syncthreads();
  double m = s_m;
  double d = (n < NNODE) ? (v - m) : 0.0;
  double wq = waveReduceD(d * d);
  if (lane == 0) redB[wid] = wq;
  __syncthreads();
  if (threadIdx.x == 0) s_sd = sqrt((redB[0] + redB[1] + redB[2] + redB[3]) / 207.0 + (double)BNEPS);
  __syncthreads();
  if (n < NNODE) xd[n * 100 + e] = (v - m) / s_sd * (double)g3[e] + (double)b3[e];
}

// ---------------- K7: ps = x@Ws^T (stored transposed [e][n]), pr = x@Wr^T (f64) ----------------
__global__ void k_pspr(const double* __restrict__ xd, const float* __restrict__ wout,
                       double* __restrict__ psdT, double* __restrict__ prd) {
  const int n = blockIdx.x;
  __shared__ double sx[100];
  if (threadIdx.x < 100) sx[threadIdx.x] = xd[n * 100 + threadIdx.x];
  __syncthreads();
  const int e = threadIdx.x;
  if (e < 100) {
    double a = 0.0, b = 0.0;
    for (int j = 0; j < 100; j++) {
      double xv = sx[j];
      a = fma(xv, (double)wout[e * 200 + j], a);
      b = fma(xv, (double)wout[e * 200 + 100 + j], b);
    }
    psdT[e * NNODE + n] = a;   // transposed for coalesced k_edge reads
    prd[n * 100 + e] = b;
  }
}

// ---------------- K8a: edge logits b0/b1 per pij (f64) + bern output ----------------
__global__ __launch_bounds__(256) void k_edge(const double* __restrict__ psdT,
                                              const double* __restrict__ prd,
                                              const float* __restrict__ bo,
                                              const float* __restrict__ wc,
                                              const float* __restrict__ cb,
                                              double* __restrict__ bd,
                                              float* __restrict__ out) {
  const int pij = blockIdx.x * 256 + threadIdx.x;
  if (pij >= NSQ) return;
  const int i = pij / NNODE, j = pij - i * NNODE;
  const double* pri = prd + i * 100;
  double b0 = 0.0, b1 = 0.0;
  for (int e = 0; e < 100; e++) {
    double ed = fmax(pri[e] + psdT[e * NNODE + j] + (double)bo[e], 0.0);
    b0 = fma(ed, (double)wc[e], b0);
    b1 = fma(ed, (double)wc[100 + e], b1);
  }
  b0 += (double)cb[0];
  b1 += (double)cb[1];
  bd[pij * 2] = b0;
  bd[pij * 2 + 1] = b1;
  const float b0f = (float)b0, b1f = (float)b1;
  for (int b = 0; b < NBATCH; b++) {
    size_t base = (size_t)b * (2 * NSQ) + (size_t)pij * 2;
    out[base] = b0f;
    out[base + 1] = b1f;
  }
}

// ---------------- K8b: gumbel sample per (b,pij) ----------------
__global__ __launch_bounds__(256) void k_samp(const double* __restrict__ bd,
                                              float* __restrict__ out) {
  const int gid = blockIdx.x * 256 + threadIdx.x;
  if (gid >= NBATCH * NSQ) return;
  const int b = gid / NSQ;
  const int pij = gid - b * NSQ;
  const int i = pij / NNODE, j = pij - i * NNODE;
  const double b0 = bd[pij * 2], b1 = bd[pij * 2 + 1];
  uint32_t base = (uint32_t)b * (2u * NSQ) + (uint32_t)pij * 2u;
  float u0 = uniform_part(base);
  float u1 = uniform_part(base + 1u);
  double g0 = -log(-log((double)u0 + 1e-20) + 1e-20);
  double g1 = -log(-log((double)u1 + 1e-20) + 1e-20);
  float v = ((b0 + g0) >= (b1 + g1)) ? 1.0f : 0.0f;
  if (i == j) v = 0.f;
  out[O_SAMP + (size_t)b * NSQ + pij] = v;
}

extern "C" void kernel_launch(void* const* d_in, const int* in_sizes, int n_in,
                              void* d_out, int out_size, void* d_ws, size_t ws_size,
                              hipStream_t stream) {
  const float* hid = (const float*)d_in[0];
  const float* nf = (const float*)d_in[1];
  const float* c1w = (const float*)d_in[2];
  const float* c1b = (const float*)d_in[3];
  const float* c2w = (const float*)d_in[4];
  const float* c2b = (const float*)d_in[5];
  const float* g1 = (const float*)d_in[6];
  const float* b1 = (const float*)d_in[7];
  const float* g2 = (const float*)d_in[8];
  const float* b2 = (const float*)d_in[9];
  const float* fcw = (const float*)d_in[10];
  const float* fcb = (const float*)d_in[11];
  const float* g3 = (const float*)d_in[12];
  const float* b3 = (const float*)d_in[13];
  // d_in[14], d_in[15]: fc_mean_w / fc_mean_b are dead code in the reference
  const float* wout = (const float*)d_in[16];
  const float* bout = (const float*)d_in[17];
  const float* wc = (const float*)d_in[18];
  const float* cbb = (const float*)d_in[19];
  float* out = (float*)d_out;
  float* ws = (float*)d_ws;

  float* w_norm = ws + 0;                       // 3312 f
  float* w_sim = ws + 8192;                     // 685584 f
  float* w_p1 = ws + 704512;                    // 3008 f
  float* w_p2 = ws + 712704;                    // 158976 f (dead after k_red2)
  double* w_bd = (double*)(ws + 712704);        // 85698 d (reuses w_p2 region)
  double* w_foldd = (double*)(ws + 900096);     // 48 d
  float* w_part = ws + 1048576;                 // 2,600,000 f -> ends 3,648,576
  double* w_xd = (double*)(ws + 3648576);       // 20700 d
  double* w_psdT = (double*)(ws + 3690000);     // 20700 d (transposed [e][n])
  double* w_prd = (double*)(ws + 3731400);      // 20700 d -> ends 3,772,800
  float* w_simp = ws + 3772800;                 // 2*16*NSQ = 1,371,168 f -> ends 5,143,968 (~20.6 MB)

  // sim / knn branch
  k_copynorm<<<NBATCH * NNODE, 256, 0, stream>>>(hid, out, w_norm);
  k_sim<<<dim3(32, NBATCH), 256, 0, stream>>>(hid, w_simp);
  k_simc<<<(NBATCH * NSQ + 255) / 256, 256, 0, stream>>>(w_simp, w_norm, w_sim);
  k_topk<<<NBATCH, 1024, 0, stream>>>(w_sim, out);

  // conv -> fc -> edge branch
  k_c1stats<<<188, 256, 0, stream>>>(nf, c1w, c1b, w_p1);
  k_red1<<<1, 64, 0, stream>>>(w_p1, g1, b1, w_foldd);
  k_c2stats<<<dim3(24, NNODE), 256, 0, stream>>>(nf, c1w, c1b, c2w, c2b, w_foldd, w_p2);
  k_red2<<<1, 256, 0, stream>>>(w_p2, g2, b2, w_foldd);
  k_gemm<<<dim3(NKS, 4), 512, 0, stream>>>(nf, c1w, c1b, c2w, c2b, w_foldd, fcw, w_part);
  k_bn3<<<EMBD, 256, 0, stream>>>(w_part, fcb, g3, b3, w_xd);
  k_pspr<<<NNODE, 128, 0, stream>>>(w_xd, wout, w_psdT, w_prd);
  k_edge<<<(NSQ + 255) / 256, 256, 0, stream>>>(w_psdT, w_prd, bout, wc, cbb, w_bd, out);
  k_samp<<<(NBATCH * NSQ + 255) / 256, 256, 0, stream>>>(w_bd, out);
}

// Round 13
// 2558.652 us; speedup vs baseline: 4.2947x; 1.0668x over previous
//
#include <hip/hip_runtime.h>
#include <stdint.h>
#include <math.h>

#define NBATCH 16
#define NNODE 207
#define TLEN 23990
#define EMBD 100
#define L1LEN 23981   // T-9
#define L2LEN 23972   // T-18
#define DIMFC 383552  // 16*L2
#define DMEAN 16128   // P*D
#define NSQ 42849     // N*N
#define KSEL 2070     // K*N
#define BNEPS 1e-5f
#define NKS 125       // split-K chunks for k_gemm (l-chunk 192 = 24*8)
#define KHALF 8064    // k_sim split-K half

// output offsets (floats)
#define O_HID  1371168ull
#define O_KNN  54787104ull
#define O_SAMP 55472688ull

__device__ __forceinline__ float waveReduce(float v) {
#pragma unroll
  for (int o = 32; o > 0; o >>= 1) v += __shfl_down(v, o);
  return v;
}

__device__ __forceinline__ double waveReduceD(double v) {
#pragma unroll
  for (int o = 32; o > 0; o >>= 1) v += __shfl_down(v, o);
  return v;
}

__device__ __forceinline__ unsigned int sortableKey(float f) {
  unsigned int u = __float_as_uint(f);
  return (u & 0x80000000u) ? ~u : (u | 0x80000000u);
}

// JAX threefry2x32-20 with key (0, 42)
__device__ __forceinline__ void threefry(uint32_t x0, uint32_t x1, uint32_t& o0, uint32_t& o1) {
  const uint32_t k0 = 0u, k1 = 42u;
  const uint32_t k2 = k0 ^ k1 ^ 0x1BD11BDAu;
  x0 += k0; x1 += k1;
#define TFR(r) { x0 += x1; x1 = (x1 << r) | (x1 >> (32 - r)); x1 ^= x0; }
  TFR(13) TFR(15) TFR(26) TFR(6)   x0 += k1; x1 += k2 + 1u;
  TFR(17) TFR(29) TFR(16) TFR(24)  x0 += k2; x1 += k0 + 2u;
  TFR(13) TFR(15) TFR(26) TFR(6)   x0 += k0; x1 += k1 + 3u;
  TFR(17) TFR(29) TFR(16) TFR(24)  x0 += k1; x1 += k2 + 4u;
  TFR(13) TFR(15) TFR(26) TFR(6)   x0 += k2; x1 += k0 + 5u;
#undef TFR
  o0 = x0; o1 = x1;
}

// jax_threefry_partitionable bit stream: element i -> threefry(key,(0,i)), XOR-fold.
__device__ __forceinline__ float uniform_part(uint32_t m) {
  uint32_t o0, o1;
  threefry(0u, m, o0, o1);
  uint32_t bits = o0 ^ o1;
  return __uint_as_float((bits >> 9) | 0x3f800000u) - 1.0f;
}

// ---------------- K9: copy hidden -> out, row sumsq -> norms ----------------
__global__ __launch_bounds__(256) void k_copynorm(const float* __restrict__ h,
                                                  float* __restrict__ out,
                                                  float* __restrict__ norms) {
  const size_t row = blockIdx.x; // 0..3311
  const float4* src = reinterpret_cast<const float4*>(h + row * (size_t)DMEAN);
  float4* dst = reinterpret_cast<float4*>(out + O_HID + row * (size_t)DMEAN);
  float s = 0.f;
  for (int i = threadIdx.x; i < DMEAN / 4; i += 256) {
    float4 v = src[i];
    dst[i] = v;
    s += v.x * v.x + v.y * v.y + v.z * v.z + v.w * v.w;
  }
  __shared__ float red[4];
  float w = waveReduce(s);
  if ((threadIdx.x & 63) == 0) red[threadIdx.x >> 6] = w;
  __syncthreads();
  if (threadIdx.x == 0) norms[row] = sqrtf(red[0] + red[1] + red[2] + red[3]);
}

// ---------------- K10: sim partials = h @ h^T (A from global broadcast, B in LDS, split-K x2) ----------------
__global__ __launch_bounds__(256) void k_sim(const float* __restrict__ h,
                                             float* __restrict__ simp) {
  const int b = blockIdx.y;
  const int tile = blockIdx.x & 15;
  const int ks = blockIdx.x >> 4;     // 0/1 k-half
  const int ti = tile >> 2, tj = tile & 3;
  __shared__ float sB[32][64];
  const int tx = threadIdx.x & 15, ty = threadIdx.x >> 4;
  const float* hb = h + (size_t)b * NNODE * DMEAN;
  const int r0 = ti * 64 + ty * 4;
  const float* ap0 = hb + (size_t)min(r0 + 0, NNODE - 1) * DMEAN;
  const float* ap1 = hb + (size_t)min(r0 + 1, NNODE - 1) * DMEAN;
  const float* ap2 = hb + (size_t)min(r0 + 2, NNODE - 1) * DMEAN;
  const float* ap3 = hb + (size_t)min(r0 + 3, NNODE - 1) * DMEAN;
  const int scol = threadIdx.x >> 2;       // staging col 0..63
  const int sk = (threadIdx.x & 3) * 8;    // staging k offset
  const bool bvalid = (tj * 64 + scol) < NNODE;
  const float* bp = hb + (size_t)min(tj * 64 + scol, NNODE - 1) * DMEAN;
  float acc[4][4];
#pragma unroll
  for (int p = 0; p < 4; p++)
#pragma unroll
    for (int q = 0; q < 4; q++) acc[p][q] = 0.f;
  const int kbeg = ks * KHALF;
  const int kend = kbeg + KHALF;
  for (int k0 = kbeg; k0 < kend; k0 += 32) {
    __syncthreads();
    {
      float4 v1 = make_float4(0.f, 0.f, 0.f, 0.f), v2 = v1;
      if (bvalid) {
        v1 = *reinterpret_cast<const float4*>(bp + k0 + sk);
        v2 = *reinterpret_cast<const float4*>(bp + k0 + sk + 4);
      }
      sB[sk + 0][scol] = v1.x;
      sB[sk + 1][scol] = v1.y;
      sB[sk + 2][scol] = v1.z;
      sB[sk + 3][scol] = v1.w;
      sB[sk + 4][scol] = v2.x;
      sB[sk + 5][scol] = v2.y;
      sB[sk + 6][scol] = v2.z;
      sB[sk + 7][scol] = v2.w;
    }
    __syncthreads();
#pragma unroll
    for (int g = 0; g < 8; g++) {
      const int kk = k0 + g * 4;
      const float4 a0 = *reinterpret_cast<const float4*>(ap0 + kk);
      const float4 a1 = *reinterpret_cast<const float4*>(ap1 + kk);
      const float4 a2 = *reinterpret_cast<const float4*>(ap2 + kk);
      const float4 a3 = *reinterpret_cast<const float4*>(ap3 + kk);
      const float4 b0 = *reinterpret_cast<const float4*>(&sB[g * 4 + 0][tx * 4]);
      const float4 b1 = *reinterpret_cast<const float4*>(&sB[g * 4 + 1][tx * 4]);
      const float4 b2 = *reinterpret_cast<const float4*>(&sB[g * 4 + 2][tx * 4]);
      const float4 b3 = *reinterpret_cast<const float4*>(&sB[g * 4 + 3][tx * 4]);
      // s = 0 (k = kk)
      acc[0][0] = fmaf(a0.x, b0.x, acc[0][0]); acc[0][1] = fmaf(a0.x, b0.y, acc[0][1]);
      acc[0][2] = fmaf(a0.x, b0.z, acc[0][2]); acc[0][3] = fmaf(a0.x, b0.w, acc[0][3]);
      acc[1][0] = fmaf(a1.x, b0.x, acc[1][0]); acc[1][1] = fmaf(a1.x, b0.y, acc[1][1]);
      acc[1][2] = fmaf(a1.x, b0.z, acc[1][2]); acc[1][3] = fmaf(a1.x, b0.w, acc[1][3]);
      acc[2][0] = fmaf(a2.x, b0.x, acc[2][0]); acc[2][1] = fmaf(a2.x, b0.y, acc[2][1]);
      acc[2][2] = fmaf(a2.x, b0.z, acc[2][2]); acc[2][3] = fmaf(a2.x, b0.w, acc[2][3]);
      acc[3][0] = fmaf(a3.x, b0.x, acc[3][0]); acc[3][1] = fmaf(a3.x, b0.y, acc[3][1]);
      acc[3][2] = fmaf(a3.x, b0.z, acc[3][2]); acc[3][3] = fmaf(a3.x, b0.w, acc[3][3]);
      // s = 1
      acc[0][0] = fmaf(a0.y, b1.x, acc[0][0]); acc[0][1] = fmaf(a0.y, b1.y, acc[0][1]);
      acc[0][2] = fmaf(a0.y, b1.z, acc[0][2]); acc[0][3] = fmaf(a0.y, b1.w, acc[0][3]);
      acc[1][0] = fmaf(a1.y, b1.x, acc[1][0]); acc[1][1] = fmaf(a1.y, b1.y, acc[1][1]);
      acc[1][2] = fmaf(a1.y, b1.z, acc[1][2]); acc[1][3] = fmaf(a1.y, b1.w, acc[1][3]);
      acc[2][0] = fmaf(a2.y, b1.x, acc[2][0]); acc[2][1] = fmaf(a2.y, b1.y, acc[2][1]);
      acc[2][2] = fmaf(a2.y, b1.z, acc[2][2]); acc[2][3] = fmaf(a2.y, b1.w, acc[2][3]);
      acc[3][0] = fmaf(a3.y, b1.x, acc[3][0]); acc[3][1] = fmaf(a3.y, b1.y, acc[3][1]);
      acc[3][2] = fmaf(a3.y, b1.z, acc[3][2]); acc[3][3] = fmaf(a3.y, b1.w, acc[3][3]);
      // s = 2
      acc[0][0] = fmaf(a0.z, b2.x, acc[0][0]); acc[0][1] = fmaf(a0.z, b2.y, acc[0][1]);
      acc[0][2] = fmaf(a0.z, b2.z, acc[0][2]); acc[0][3] = fmaf(a0.z, b2.w, acc[0][3]);
      acc[1][0] = fmaf(a1.z, b2.x, acc[1][0]); acc[1][1] = fmaf(a1.z, b2.y, acc[1][1]);
      acc[1][2] = fmaf(a1.z, b2.z, acc[1][2]); acc[1][3] = fmaf(a1.z, b2.w, acc[1][3]);
      acc[2][0] = fmaf(a2.z, b2.x, acc[2][0]); acc[2][1] = fmaf(a2.z, b2.y, acc[2][1]);
      acc[2][2] = fmaf(a2.z, b2.z, acc[2][2]); acc[2][3] = fmaf(a2.z, b2.w, acc[2][3]);
      acc[3][0] = fmaf(a3.z, b2.x, acc[3][0]); acc[3][1] = fmaf(a3.z, b2.y, acc[3][1]);
      acc[3][2] = fmaf(a3.z, b2.z, acc[3][2]); acc[3][3] = fmaf(a3.z, b2.w, acc[3][3]);
      // s = 3
      acc[0][0] = fmaf(a0.w, b3.x, acc[0][0]); acc[0][1] = fmaf(a0.w, b3.y, acc[0][1]);
      acc[0][2] = fmaf(a0.w, b3.z, acc[0][2]); acc[0][3] = fmaf(a0.w, b3.w, acc[0][3]);
      acc[1][0] = fmaf(a1.w, b3.x, acc[1][0]); acc[1][1] = fmaf(a1.w, b3.y, acc[1][1]);
      acc[1][2] = fmaf(a1.w, b3.z, acc[1][2]); acc[1][3] = fmaf(a1.w, b3.w, acc[1][3]);
      acc[2][0] = fmaf(a2.w, b3.x, acc[2][0]); acc[2][1] = fmaf(a2.w, b3.y, acc[2][1]);
      acc[2][2] = fmaf(a2.w, b3.z, acc[2][2]); acc[2][3] = fmaf(a2.w, b3.w, acc[2][3]);
      acc[3][0] = fmaf(a3.w, b3.x, acc[3][0]); acc[3][1] = fmaf(a3.w, b3.y, acc[3][1]);
      acc[3][2] = fmaf(a3.w, b3.z, acc[3][2]); acc[3][3] = fmaf(a3.w, b3.w, acc[3][3]);
    }
  }
  float* op = simp + ((size_t)ks * NBATCH + b) * NSQ;
#pragma unroll
  for (int p = 0; p < 4; p++) {
    int ii = r0 + p;
    if (ii < NNODE) {
#pragma unroll
      for (int q = 0; q < 4; q++) {
        int jj = tj * 64 + tx * 4 + q;
        if (jj < NNODE) op[ii * NNODE + jj] = acc[p][q];
      }
    }
  }
}

// ---------------- K10b: combine halves + normalize: sim = (p0+p1)/(d_i*d_j) ----------------
__global__ __launch_bounds__(256) void k_simc(const float* __restrict__ simp,
                                              const float* __restrict__ norms,
                                              float* __restrict__ sim) {
  const int gid = blockIdx.x * 256 + threadIdx.x;
  if (gid >= NBATCH * NSQ) return;
  const int b = gid / NSQ;
  const int rem = gid - b * NSQ;
  const int i = rem / NNODE, j = rem - i * NNODE;
  float s = simp[gid] + simp[(size_t)NBATCH * NSQ + gid];
  float di = norms[b * NNODE + i] + 1e-10f;
  float dj = norms[b * NNODE + j] + 1e-10f;
  sim[gid] = s / (di * dj);
}

// ---------------- K11: exact top-k (radix select + index-ordered tie fill), 1024 thr ----------------
__global__ __launch_bounds__(1024) void k_topk(const float* __restrict__ sim,
                                               float* __restrict__ out) {
  const int b = blockIdx.x;
  const float* s = sim + (size_t)b * NSQ;
  float* knn = out + O_KNN + (size_t)b * NSQ;
  __shared__ unsigned int hist[256];
  __shared__ unsigned int cnts[1024];
  __shared__ unsigned int sh_prefix, sh_kneed;
  if (threadIdx.x == 0) { sh_prefix = 0u; sh_kneed = KSEL; }
  __syncthreads();
  const int lo = threadIdx.x * 42;
  const int hi = min(lo + 42, NSQ);
  for (int pass = 0; pass < 4; pass++) {
    const int shift = 24 - pass * 8;
    if (threadIdx.x < 256) hist[threadIdx.x] = 0u;
    __syncthreads();
    unsigned int pref = sh_prefix;
    unsigned int hmask = (pass == 0) ? 0u : (0xFFFFFFFFu << (shift + 8));
    for (int i = lo; i < hi; i++) {
      unsigned int key = sortableKey(s[i]);
      if ((key & hmask) == pref) atomicAdd(&hist[(key >> shift) & 255], 1u);
    }
    __syncthreads();
    if (threadIdx.x == 0) {
      unsigned int need = sh_kneed, cum = 0;
      for (int bkt = 255; bkt >= 0; bkt--) {
        unsigned int c = hist[bkt];
        if (cum + c >= need) {
          sh_prefix = pref | ((unsigned int)bkt << shift);
          sh_kneed = need - cum;
          break;
        }
        cum += c;
      }
    }
    __syncthreads();
  }
  const unsigned int kth = sh_prefix;
  const unsigned int need_eq = sh_kneed;
  unsigned int myeq = 0;
  for (int i = lo; i < hi; i++) {
    float v = s[i];
    unsigned int key = sortableKey(v);
    float o = 0.f;
    if (key > kth) {
      int ii = i / NNODE, jj = i - ii * NNODE;
      o = (v != 0.f && ii != jj) ? 1.f : 0.f;
    } else if (key == kth) {
      myeq++;
    }
    knn[i] = o;
  }
  cnts[threadIdx.x] = myeq;
  __syncthreads();
  if (threadIdx.x == 0) {
    unsigned int run = 0;
    for (int t = 0; t < 1024; t++) { unsigned int c = cnts[t]; cnts[t] = run; run += c; }
  }
  __syncthreads();
  unsigned int rank = cnts[threadIdx.x];
  for (int i = lo; i < hi && rank < need_eq; i++) {
    float v = s[i];
    if (sortableKey(v) == kth) {
      if (rank < need_eq) {
        int ii = i / NNODE, jj = i - ii * NNODE;
        knn[i] = (v != 0.f && ii != jj) ? 1.f : 0.f;
      }
      rank++;
    }
  }
}

// ---------------- K1: conv1+relu stats partials ----------------
__global__ __launch_bounds__(256) void k_c1stats(const float* __restrict__ nf,
                                                 const float* __restrict__ c1w,
                                                 const float* __restrict__ c1b,
                                                 float* __restrict__ part1) {
  __shared__ float sw[80], sb[8];
  if (threadIdx.x < 80) sw[threadIdx.x] = c1w[threadIdx.x];
  if (threadIdx.x < 8) sb[threadIdx.x] = c1b[threadIdx.x];
  __syncthreads();
  const int t0 = blockIdx.x * 128;
  const int cnt = min(128, L1LEN - t0);
  float s[8], sq[8];
#pragma unroll
  for (int c = 0; c < 8; c++) { s[c] = 0.f; sq[c] = 0.f; }
  for (int idx = threadIdx.x; idx < cnt * NNODE; idx += 256) {
    int tl = idx / NNODE;
    int n = idx - tl * NNODE;
    const float* p = nf + (size_t)(t0 + tl) * NNODE + n;
    float in[10];
#pragma unroll
    for (int k = 0; k < 10; k++) in[k] = p[k * NNODE];
#pragma unroll
    for (int c = 0; c < 8; c++) {
      float a = sb[c];
#pragma unroll
      for (int k = 0; k < 10; k++) a = fmaf(sw[c * 10 + k], in[k], a);
      a = fmaxf(a, 0.f);
      s[c] += a;
      sq[c] = fmaf(a, a, sq[c]);
    }
  }
  __shared__ float red[4][16];
  int lane = threadIdx.x & 63, wv = threadIdx.x >> 6;
#pragma unroll
  for (int c = 0; c < 8; c++) {
    float a = waveReduce(s[c]);
    float q = waveReduce(sq[c]);
    if (lane == 0) { red[wv][c * 2] = a; red[wv][c * 2 + 1] = q; }
  }
  __syncthreads();
  if (threadIdx.x < 16)
    part1[blockIdx.x * 16 + threadIdx.x] =
        red[0][threadIdx.x] + red[1][threadIdx.x] + red[2][threadIdx.x] + red[3][threadIdx.x];
}

// ---------------- K2: reduce bn1 stats (f64) -> a1/be1 doubles ----------------
__global__ void k_red1(const float* __restrict__ part1, const float* __restrict__ g1,
                       const float* __restrict__ b1, double* __restrict__ foldd) {
  __shared__ double sums[16];
  if (threadIdx.x < 16) {
    double s = 0.0;
    for (int i = 0; i < 188; i++) s += (double)part1[i * 16 + threadIdx.x];
    sums[threadIdx.x] = s;
  }
  __syncthreads();
  if (threadIdx.x < 8) {
    const double cnt = 207.0 * 23981.0;
    int c = threadIdx.x;
    double m = sums[c * 2] / cnt;
    double ex2 = sums[c * 2 + 1] / cnt;
    double var = ex2 - m * m;
    double sc = (double)g1[c] / sqrt(var + (double)BNEPS);
    foldd[c] = sc;            // a1
    foldd[8 + c] = (double)b1[c] - m * sc;  // be1
  }
}

// ---------------- K3: conv2+relu stats partials ----------------
__global__ __launch_bounds__(256) void k_c2stats(const float* __restrict__ nf,
                                                 const float* __restrict__ c1w,
                                                 const float* __restrict__ c1b,
                                                 const float* __restrict__ c2w,
                                                 const float* __restrict__ c2b,
                                                 const double* __restrict__ foldd,
                                                 float* __restrict__ part2) {
  const int n = blockIdx.y;
  const int l0 = blockIdx.x * 1024;
  const int len = min(1024, L2LEN - l0);
  __shared__ float s_nf[1042];
  __shared__ float s_o1[8][1034];
  __shared__ float s_w2t[1280];
  __shared__ float s_b2[16];
  __shared__ float s_c1w[80], s_c1b[8];
  __shared__ float s_a1[8], s_be1[8];
  for (int i = threadIdx.x; i < 1280; i += 256) {
    int co = i / 80, r = i - co * 80;
    s_w2t[r * 16 + co] = c2w[i];
  }
  if (threadIdx.x < 16) s_b2[threadIdx.x] = c2b[threadIdx.x];
  if (threadIdx.x < 80) s_c1w[threadIdx.x] = c1w[threadIdx.x];
  if (threadIdx.x < 8) {
    s_c1b[threadIdx.x] = c1b[threadIdx.x];
    s_a1[threadIdx.x] = (float)foldd[threadIdx.x];
    s_be1[threadIdx.x] = (float)foldd[8 + threadIdx.x];
  }
  __syncthreads();
  const int nfl = len + 18;
  for (int i = threadIdx.x; i < nfl; i += 256) s_nf[i] = nf[(size_t)(l0 + i) * NNODE + n];
  __syncthreads();
  const int o1l = len + 9;
  for (int i = threadIdx.x; i < 8 * o1l; i += 256) {
    int c = i / o1l, t = i - c * o1l;
    float a = s_c1b[c];
#pragma unroll
    for (int k = 0; k < 10; k++) a = fmaf(s_c1w[c * 10 + k], s_nf[t + k], a);
    s_o1[c][t] = fmaxf(a, 0.f) * s_a1[c] + s_be1[c];
  }
  __syncthreads();
  const int co = threadIdx.x & 15, lg = threadIdx.x >> 4;
  float sum = 0.f, ssq = 0.f;
  for (int pass = 0; pass < 4; pass++) {
    int lb = pass * 256 + lg * 16;
    if (lb >= len) continue;
    int nl = min(16, len - lb);
    float y[16];
#pragma unroll
    for (int l = 0; l < 16; l++) y[l] = s_b2[co];
#pragma unroll
    for (int ci = 0; ci < 8; ci++) {
      float win[25];
#pragma unroll
      for (int w = 0; w < 25; w++) win[w] = s_o1[ci][lb + w];
#pragma unroll
      for (int k = 0; k < 10; k++) {
        float wv = s_w2t[(ci * 10 + k) * 16 + co];
#pragma unroll
        for (int l = 0; l < 16; l++) y[l] = fmaf(wv, win[l + k], y[l]);
      }
    }
#pragma unroll
    for (int l = 0; l < 16; l++) {
      if (l < nl) {
        float v = fmaxf(y[l], 0.f);
        sum += v;
        ssq = fmaf(v, v, ssq);
      }
    }
  }
  __shared__ float rs[16][16], rq[16][16];
  rs[lg][co] = sum;
  rq[lg][co] = ssq;
  __syncthreads();
  if (threadIdx.x < 16) {
    float a = 0.f, q = 0.f;
    for (int g = 0; g < 16; g++) { a += rs[g][threadIdx.x]; q += rq[g][threadIdx.x]; }
    int blk = blockIdx.y * gridDim.x + blockIdx.x;
    part2[blk * 32 + threadIdx.x * 2] = a;
    part2[blk * 32 + threadIdx.x * 2 + 1] = q;
  }
}

// ---------------- K4: reduce bn2 stats (f64) -> s2/t2 doubles ----------------
__global__ void k_red2(const float* __restrict__ part2, const float* __restrict__ g2,
                       const float* __restrict__ b2, double* __restrict__ foldd) {
  __shared__ double acc8[8][32];
  const int grp = threadIdx.x >> 5, v = threadIdx.x & 31;
  double s = 0.0;
  for (int i = grp; i < 4968; i += 8) s += (double)part2[i * 32 + v];
  acc8[grp][v] = s;
  __syncthreads();
  if (threadIdx.x < 32) {
    double t = 0.0;
    for (int g = 0; g < 8; g++) t += acc8[g][threadIdx.x];
    acc8[0][threadIdx.x] = t;
  }
  __syncthreads();
  if (threadIdx.x < 16) {
    const double cnt = 207.0 * 23972.0;
    int c = threadIdx.x;
    double m = acc8[0][c * 2] / cnt;
    double ex2 = acc8[0][c * 2 + 1] / cnt;
    double var = ex2 - m * m;
    double sc = (double)g2[c] / sqrt(var + (double)BNEPS);
    foldd[16 + c] = sc;                       // s2
    foldd[32 + c] = (double)b2[c] - m * sc;   // t2
  }
}

// ---------------- K5: fused conv1->conv2->bn2->fc GEMM (fc 7x4 tiles, exact-n coverage) ----------------
__global__ __launch_bounds__(512, 2) void k_gemm(const float* __restrict__ nf,
                                                 const float* __restrict__ c1w,
                                                 const float* __restrict__ c1b,
                                                 const float* __restrict__ c2w,
                                                 const float* __restrict__ c2b,
                                                 const double* __restrict__ foldd,
                                                 const float* __restrict__ fcw,
                                                 float* __restrict__ part) {
  const int ks = blockIdx.x;  // 0..124 l-chunk of 192
  const int nt = blockIdx.y;  // 0..3  n-tile of 52
  const int l0 = ks * 192;
  const int n0 = nt * 52;

  __shared__ float s_nf[26][52];
  __shared__ float s_o1[8][17][52];   // bn1-applied conv1 (f32)
  __shared__ float s_x2[16][8][64];   // bn2-applied conv2 (f32)
  __shared__ float s_wT[2][112][10];  // fc weights [buf][e][kk]
  __shared__ float s_w2t[1280];
  __shared__ float s_c1w[80], s_c1b[8], s_c2b[16];
  __shared__ float s_a1f[8], s_be1f[8], s_s2f[16], s_t2f[16];

  for (int i = threadIdx.x; i < 1280; i += 512) {
    int co = i / 80, r = i - co * 80;
    s_w2t[r * 16 + co] = c2w[i];
  }
  if (threadIdx.x < 80) s_c1w[threadIdx.x] = c1w[threadIdx.x];
  if (threadIdx.x < 8) {
    s_c1b[threadIdx.x] = c1b[threadIdx.x];
    s_a1f[threadIdx.x] = (float)foldd[threadIdx.x];
    s_be1f[threadIdx.x] = (float)foldd[8 + threadIdx.x];
  }
  if (threadIdx.x < 16) {
    s_c2b[threadIdx.x] = c2b[threadIdx.x];
    s_s2f[threadIdx.x] = (float)foldd[16 + threadIdx.x];
    s_t2f[threadIdx.x] = (float)foldd[32 + threadIdx.x];
  }

  double acc[7][4];  // e = te+16m, n = tn4*4+q (fc-active threads only; static indexing)
#pragma unroll
  for (int m = 0; m < 7; m++)
#pragma unroll
    for (int q = 0; q < 4; q++) acc[m][q] = 0.0;

  const int te = threadIdx.x & 15;        // fc e-lane
  const int tn4 = threadIdx.x >> 4;       // fc n-group (valid < 13)
  const bool fc_act = threadIdx.x < 208;  // 16 te x 13 tn4
  const int nl = threadIdx.x & 63;        // conv2 node lane
  const int c0 = (threadIdx.x >> 6) & 7;  // conv2 co base
  const bool doload = threadIdx.x < 448;  // fc staging lanes
  const int e_ld = threadIdx.x >> 2;      // 0..111
  const int k2 = (threadIdx.x & 3) * 2;   // 0,2,4,6

  for (int ls = 0; ls < 24; ls++) {
    const int lb = l0 + ls * 8;
    if (lb >= L2LEN) break;
    const bool lfull = (lb + 8 <= L2LEN);
    for (int i = threadIdx.x; i < 26 * 52; i += 512) {
      int r = i / 52, cc = i - r * 52;
      int t = lb + r, n = n0 + cc;
      float v = 0.f;
      if (t < TLEN && n < NNODE) v = nf[(size_t)t * NNODE + n];
      s_nf[r][cc] = v;
    }
    __syncthreads();
    // conv1 + bn1 (f32)
    for (int i = threadIdx.x; i < 8 * 17 * 52; i += 512) {
      int c = i / (17 * 52);
      int rem = i - c * 17 * 52;
      int t = rem / 52, n = rem - t * 52;
      float a = s_c1b[c];
#pragma unroll
      for (int k = 0; k < 10; k++) a = fmaf(s_c1w[c * 10 + k], s_nf[t + k][n], a);
      s_o1[c][t][n] = fmaxf(a, 0.f) * s_a1f[c] + s_be1f[c];
    }
    __syncthreads();
    // conv2 + relu + bn2 (f32, named scalars, shared 17-wide window)
    {
      const bool valid = (nl < 52) && (n0 + nl < NNODE);
      if (valid) {
        const float bA = s_c2b[c0], bB = s_c2b[c0 + 8];
        float y00 = bA, y01 = bA, y02 = bA, y03 = bA;
        float y10 = bA, y11 = bA, y12 = bA, y13 = bA;
        float y20 = bB, y21 = bB, y22 = bB, y23 = bB;
        float y30 = bB, y31 = bB, y32 = bB, y33 = bB;
        for (int ci = 0; ci < 8; ci++) {
          float ww0 = s_o1[ci][0][nl],  ww1 = s_o1[ci][1][nl],  ww2 = s_o1[ci][2][nl];
          float ww3 = s_o1[ci][3][nl],  ww4 = s_o1[ci][4][nl],  ww5 = s_o1[ci][5][nl];
          float ww6 = s_o1[ci][6][nl],  ww7 = s_o1[ci][7][nl],  ww8 = s_o1[ci][8][nl];
          float ww9 = s_o1[ci][9][nl],  wwa = s_o1[ci][10][nl], wwb = s_o1[ci][11][nl];
          float wwc = s_o1[ci][12][nl], wwd = s_o1[ci][13][nl], wwe = s_o1[ci][14][nl];
          float wwf = s_o1[ci][15][nl], wwg = s_o1[ci][16][nl];
          const float* wpA = &s_w2t[ci * 160 + c0];
          const float* wpB = wpA + 8;
          float v, u;
#define C2STEP(K, A0, A1, A2, A3, B0, B1, B2, B3)                                   \
          v = wpA[(K) * 16]; u = wpB[(K) * 16];                                     \
          y00 = fmaf(v, A0, y00); y01 = fmaf(v, A1, y01);                           \
          y02 = fmaf(v, A2, y02); y03 = fmaf(v, A3, y03);                           \
          y10 = fmaf(v, B0, y10); y11 = fmaf(v, B1, y11);                           \
          y12 = fmaf(v, B2, y12); y13 = fmaf(v, B3, y13);                           \
          y20 = fmaf(u, A0, y20); y21 = fmaf(u, A1, y21);                           \
          y22 = fmaf(u, A2, y22); y23 = fmaf(u, A3, y23);                           \
          y30 = fmaf(u, B0, y30); y31 = fmaf(u, B1, y31);                           \
          y32 = fmaf(u, B2, y32); y33 = fmaf(u, B3, y33);
          C2STEP(0, ww0, ww1, ww2, ww3, ww4, ww5, ww6, ww7)
          C2STEP(1, ww1, ww2, ww3, ww4, ww5, ww6, ww7, ww8)
          C2STEP(2, ww2, ww3, ww4, ww5, ww6, ww7, ww8, ww9)
          C2STEP(3, ww3, ww4, ww5, ww6, ww7, ww8, ww9, wwa)
          C2STEP(4, ww4, ww5, ww6, ww7, ww8, ww9, wwa, wwb)
          C2STEP(5, ww5, ww6, ww7, ww8, ww9, wwa, wwb, wwc)
          C2STEP(6, ww6, ww7, ww8, ww9, wwa, wwb, wwc, wwd)
          C2STEP(7, ww7, ww8, ww9, wwa, wwb, wwc, wwd, wwe)
          C2STEP(8, ww8, ww9, wwa, wwb, wwc, wwd, wwe, wwf)
          C2STEP(9, ww9, wwa, wwb, wwc, wwd, wwe, wwf, wwg)
#undef C2STEP
        }
        const float scA = s_s2f[c0], tbA = s_t2f[c0];
        const float scB = s_s2f[c0 + 8], tbB = s_t2f[c0 + 8];
        s_x2[c0][0][nl] = (lb + 0 < L2LEN) ? fmaf(fmaxf(y00, 0.f), scA, tbA) : 0.f;
        s_x2[c0][1][nl] = (lb + 1 < L2LEN) ? fmaf(fmaxf(y01, 0.f), scA, tbA) : 0.f;
        s_x2[c0][2][nl] = (lb + 2 < L2LEN) ? fmaf(fmaxf(y02, 0.f), scA, tbA) : 0.f;
        s_x2[c0][3][nl] = (lb + 3 < L2LEN) ? fmaf(fmaxf(y03, 0.f), scA, tbA) : 0.f;
        s_x2[c0][4][nl] = (lb + 4 < L2LEN) ? fmaf(fmaxf(y10, 0.f), scA, tbA) : 0.f;
        s_x2[c0][5][nl] = (lb + 5 < L2LEN) ? fmaf(fmaxf(y11, 0.f), scA, tbA) : 0.f;
        s_x2[c0][6][nl] = (lb + 6 < L2LEN) ? fmaf(fmaxf(y12, 0.f), scA, tbA) : 0.f;
        s_x2[c0][7][nl] = (lb + 7 < L2LEN) ? fmaf(fmaxf(y13, 0.f), scA, tbA) : 0.f;
        s_x2[c0 + 8][0][nl] = (lb + 0 < L2LEN) ? fmaf(fmaxf(y20, 0.f), scB, tbB) : 0.f;
        s_x2[c0 + 8][1][nl] = (lb + 1 < L2LEN) ? fmaf(fmaxf(y21, 0.f), scB, tbB) : 0.f;
        s_x2[c0 + 8][2][nl] = (lb + 2 < L2LEN) ? fmaf(fmaxf(y22, 0.f), scB, tbB) : 0.f;
        s_x2[c0 + 8][3][nl] = (lb + 3 < L2LEN) ? fmaf(fmaxf(y23, 0.f), scB, tbB) : 0.f;
        s_x2[c0 + 8][4][nl] = (lb + 4 < L2LEN) ? fmaf(fmaxf(y30, 0.f), scB, tbB) : 0.f;
        s_x2[c0 + 8][5][nl] = (lb + 5 < L2LEN) ? fmaf(fmaxf(y31, 0.f), scB, tbB) : 0.f;
        s_x2[c0 + 8][6][nl] = (lb + 6 < L2LEN) ? fmaf(fmaxf(y32, 0.f), scB, tbB) : 0.f;
        s_x2[c0 + 8][7][nl] = (lb + 7 < L2LEN) ? fmaf(fmaxf(y33, 0.f), scB, tbB) : 0.f;
      } else {
#pragma unroll
        for (int l = 0; l < 8; l++) {
          s_x2[c0][l][nl] = 0.f;
          s_x2[c0 + 8][l][nl] = 0.f;
        }
      }
    }
    // prologue: load fc weights for c=0 (overlaps conv2 barrier)
    float2 wld = make_float2(0.f, 0.f);
    if (doload && e_ld < EMBD) {
      const float* fp = fcw + (size_t)e_ld * DIMFC + lb + k2;  // c = 0
      if (lfull) wld = *reinterpret_cast<const float2*>(fp);
      else {
        wld.x = (lb + k2 < L2LEN) ? fp[0] : 0.f;
        wld.y = (lb + k2 + 1 < L2LEN) ? fp[1] : 0.f;
      }
    }
    __syncthreads();  // s_x2 visible
    if (doload) *reinterpret_cast<float2*>(&s_wT[0][e_ld][k2]) = wld;
    // fc c-loop: 1 barrier per c, next-c weights prefetched during compute
    for (int c = 0; c < 16; c++) {
      __syncthreads();  // s_wT[c&1] ready; prev readers of s_wT[(c+1)&1] done
      float2 wnext = make_float2(0.f, 0.f);
      if (c < 15 && doload && e_ld < EMBD) {
        const float* fp = fcw + (size_t)e_ld * DIMFC + (size_t)(c + 1) * L2LEN + lb + k2;
        if (lfull) wnext = *reinterpret_cast<const float2*>(fp);
        else {
          wnext.x = (lb + k2 < L2LEN) ? fp[0] : 0.f;
          wnext.y = (lb + k2 + 1 < L2LEN) ? fp[1] : 0.f;
        }
      }
      if (fc_act) {
        const int bsel = c & 1;
        const float4 xv0 = *reinterpret_cast<const float4*>(&s_x2[c][0][tn4 * 4]);
        const float4 xv1 = *reinterpret_cast<const float4*>(&s_x2[c][1][tn4 * 4]);
        const float4 xv2 = *reinterpret_cast<const float4*>(&s_x2[c][2][tn4 * 4]);
        const float4 xv3 = *reinterpret_cast<const float4*>(&s_x2[c][3][tn4 * 4]);
        const float4 xv4 = *reinterpret_cast<const float4*>(&s_x2[c][4][tn4 * 4]);
        const float4 xv5 = *reinterpret_cast<const float4*>(&s_x2[c][5][tn4 * 4]);
        const float4 xv6 = *reinterpret_cast<const float4*>(&s_x2[c][6][tn4 * 4]);
        const float4 xv7 = *reinterpret_cast<const float4*>(&s_x2[c][7][tn4 * 4]);
#pragma unroll
        for (int m = 0; m < 7; m++) {
          const float* wp = &s_wT[bsel][te + 16 * m][0];
          const float2 wv01 = *reinterpret_cast<const float2*>(&wp[0]);
          const float2 wv23 = *reinterpret_cast<const float2*>(&wp[2]);
          const float2 wv45 = *reinterpret_cast<const float2*>(&wp[4]);
          const float2 wv67 = *reinterpret_cast<const float2*>(&wp[6]);
          float a0 = 0.f, a1 = 0.f, a2 = 0.f, a3 = 0.f;
          a0 = fmaf(wv01.x, xv0.x, a0); a1 = fmaf(wv01.x, xv0.y, a1);
          a2 = fmaf(wv01.x, xv0.z, a2); a3 = fmaf(wv01.x, xv0.w, a3);
          a0 = fmaf(wv01.y, xv1.x, a0); a1 = fmaf(wv01.y, xv1.y, a1);
          a2 = fmaf(wv01.y, xv1.z, a2); a3 = fmaf(wv01.y, xv1.w, a3);
          a0 = fmaf(wv23.x, xv2.x, a0); a1 = fmaf(wv23.x, xv2.y, a1);
          a2 = fmaf(wv23.x, xv2.z, a2); a3 = fmaf(wv23.x, xv2.w, a3);
          a0 = fmaf(wv23.y, xv3.x, a0); a1 = fmaf(wv23.y, xv3.y, a1);
          a2 = fmaf(wv23.y, xv3.z, a2); a3 = fmaf(wv23.y, xv3.w, a3);
          a0 = fmaf(wv45.x, xv4.x, a0); a1 = fmaf(wv45.x, xv4.y, a1);
          a2 = fmaf(wv45.x, xv4.z, a2); a3 = fmaf(wv45.x, xv4.w, a3);
          a0 = fmaf(wv45.y, xv5.x, a0); a1 = fmaf(wv45.y, xv5.y, a1);
          a2 = fmaf(wv45.y, xv5.z, a2); a3 = fmaf(wv45.y, xv5.w, a3);
          a0 = fmaf(wv67.x, xv6.x, a0); a1 = fmaf(wv67.x, xv6.y, a1);
          a2 = fmaf(wv67.x, xv6.z, a2); a3 = fmaf(wv67.x, xv6.w, a3);
          a0 = fmaf(wv67.y, xv7.x, a0); a1 = fmaf(wv67.y, xv7.y, a1);
          a2 = fmaf(wv67.y, xv7.z, a2); a3 = fmaf(wv67.y, xv7.w, a3);
          acc[m][0] += (double)a0;
          acc[m][1] += (double)a1;
          acc[m][2] += (double)a2;
          acc[m][3] += (double)a3;
        }
      }
      if (c < 15 && doload)
        *reinterpret_cast<float2*>(&s_wT[(c + 1) & 1][e_ld][k2]) = wnext;
    }
  }
  if (fc_act) {
    for (int m = 0; m < 7; m++) {
      int e = te + 16 * m;
      if (e < EMBD) {
        for (int q = 0; q < 4; q++) {
          int nl2 = tn4 * 4 + q;
          part[(((size_t)ks * 4 + nt) * 100 + e) * 52 + nl2] = (float)acc[m][q];
        }
      }
    }
  }
}

// ---------------- K6: reduce split-K (f64), +bias, relu, bn3 -> x (f64) ----------------
__global__ __launch_bounds__(256) void k_bn3(const float* __restrict__ part,
                                             const float* __restrict__ fcb,
                                             const float* __restrict__ g3,
                                             const float* __restrict__ b3,
                                             double* __restrict__ xd) {
  const int e = blockIdx.x;
  const int n = threadIdx.x;
  double v = 0.0;
  if (n < NNODE) {
    int nt = n / 52, nl = n - nt * 52;
    const size_t stride = 4 * 100 * 52;
    const float* p = part + ((size_t)nt * 100 + e) * 52 + nl;
    for (int ks = 0; ks < NKS; ks++) v += (double)p[ks * stride];
    v = fmax(v + (double)fcb[e], 0.0);
  }
  __shared__ double redA[4], redB[4];
  __shared__ double s_m, s_sd;
  int lane = threadIdx.x & 63, wid = threadIdx.x >> 6;
  double w = waveReduceD(v);
  if (lane == 0) redA[wid] = w;
  __syncthreads();
  if (threadIdx.x == 0) s_m = (redA[0] + redA[1] + redA[2] + redA[3]) / 207.0;
  __syncthreads();
  double m = s_m;
  double d = (n < NNODE) ? (v - m) : 0.0;
  double wq = waveReduceD(d * d);
  if (lane == 0) redB[wid] = wq;
  __syncthreads();
  if (threadIdx.x == 0) s_sd = sqrt((redB[0] + redB[1] + redB[2] + redB[3]) / 207.0 + (double)BNEPS);
  __syncthreads();
  if (n < NNODE) xd[n * 100 + e] = (v - m) / s_sd * (double)g3[e] + (double)b3[e];
}

// ---------------- K7: ps = x@Ws^T (stored transposed [e][n]), pr = x@Wr^T (f64) ----------------
__global__ void k_pspr(const double* __restrict__ xd, const float* __restrict__ wout,
                       double* __restrict__ psdT, double* __restrict__ prd) {
  const int n = blockIdx.x;
  __shared__ double sx[100];
  if (threadIdx.x < 100) sx[threadIdx.x] = xd[n * 100 + threadIdx.x];
  __syncthreads();
  const int e = threadIdx.x;
  if (e < 100) {
    double a = 0.0, b = 0.0;
    for (int j = 0; j < 100; j++) {
      double xv = sx[j];
      a = fma(xv, (double)wout[e * 200 + j], a);
      b = fma(xv, (double)wout[e * 200 + 100 + j], b);
    }
    psdT[e * NNODE + n] = a;   // transposed for coalesced k_edge reads
    prd[n * 100 + e] = b;
  }
}

// ---------------- K8a: edge logits b0/b1 per pij (f64) + bern output ----------------
__global__ __launch_bounds__(256) void k_edge(const double* __restrict__ psdT,
                                              const double* __restrict__ prd,
                                              const float* __restrict__ bo,
                                              const float* __restrict__ wc,
                                              const float* __restrict__ cb,
                                              double* __restrict__ bd,
                                              float* __restrict__ out) {
  const int pij = blockIdx.x * 256 + threadIdx.x;
  if (pij >= NSQ) return;
  const int i = pij / NNODE, j = pij - i * NNODE;
  const double* pri = prd + i * 100;
  double b0 = 0.0, b1 = 0.0;
  for (int e = 0; e < 100; e++) {
    double ed = fmax(pri[e] + psdT[e * NNODE + j] + (double)bo[e], 0.0);
    b0 = fma(ed, (double)wc[e], b0);
    b1 = fma(ed, (double)wc[100 + e], b1);
  }
  b0 += (double)cb[0];
  b1 += (double)cb[1];
  bd[pij * 2] = b0;
  bd[pij * 2 + 1] = b1;
  const float b0f = (float)b0, b1f = (float)b1;
  for (int b = 0; b < NBATCH; b++) {
    size_t base = (size_t)b * (2 * NSQ) + (size_t)pij * 2;
    out[base] = b0f;
    out[base + 1] = b1f;
  }
}

// ---------------- K8b: gumbel sample per (b,pij) ----------------
__global__ __launch_bounds__(256) void k_samp(const double* __restrict__ bd,
                                              float* __restrict__ out) {
  const int gid = blockIdx.x * 256 + threadIdx.x;
  if (gid >= NBATCH * NSQ) return;
  const int b = gid / NSQ;
  const int pij = gid - b * NSQ;
  const int i = pij / NNODE, j = pij - i * NNODE;
  const double b0 = bd[pij * 2], b1 = bd[pij * 2 + 1];
  uint32_t base = (uint32_t)b * (2u * NSQ) + (uint32_t)pij * 2u;
  float u0 = uniform_part(base);
  float u1 = uniform_part(base + 1u);
  double g0 = -log(-log((double)u0 + 1e-20) + 1e-20);
  double g1 = -log(-log((double)u1 + 1e-20) + 1e-20);
  float v = ((b0 + g0) >= (b1 + g1)) ? 1.0f : 0.0f;
  if (i == j) v = 0.f;
  out[O_SAMP + (size_t)b * NSQ + pij] = v;
}

extern "C" void kernel_launch(void* const* d_in, const int* in_sizes, int n_in,
                              void* d_out, int out_size, void* d_ws, size_t ws_size,
                              hipStream_t stream) {
  const float* hid = (const float*)d_in[0];
  const float* nf = (const float*)d_in[1];
  const float* c1w = (const float*)d_in[2];
  const float* c1b = (const float*)d_in[3];
  const float* c2w = (const float*)d_in[4];
  const float* c2b = (const float*)d_in[5];
  const float* g1 = (const float*)d_in[6];
  const float* b1 = (const float*)d_in[7];
  const float* g2 = (const float*)d_in[8];
  const float* b2 = (const float*)d_in[9];
  const float* fcw = (const float*)d_in[10];
  const float* fcb = (const float*)d_in[11];
  const float* g3 = (const float*)d_in[12];
  const float* b3 = (const float*)d_in[13];
  // d_in[14], d_in[15]: fc_mean_w / fc_mean_b are dead code in the reference
  const float* wout = (const float*)d_in[16];
  const float* bout = (const float*)d_in[17];
  const float* wc = (const float*)d_in[18];
  const float* cbb = (const float*)d_in[19];
  float* out = (float*)d_out;
  float* ws = (float*)d_ws;

  float* w_norm = ws + 0;                       // 3312 f
  float* w_sim = ws + 8192;                     // 685584 f
  float* w_p1 = ws + 704512;                    // 3008 f
  float* w_p2 = ws + 712704;                    // 158976 f (dead after k_red2)
  double* w_bd = (double*)(ws + 712704);        // 85698 d (reuses w_p2 region)
  double* w_foldd = (double*)(ws + 900096);     // 48 d
  float* w_part = ws + 1048576;                 // 2,600,000 f -> ends 3,648,576
  double* w_xd = (double*)(ws + 3648576);       // 20700 d
  double* w_psdT = (double*)(ws + 3690000);     // 20700 d (transposed [e][n])
  double* w_prd = (double*)(ws + 3731400);      // 20700 d -> ends 3,772,800
  float* w_simp = ws + 3772800;                 // 2*16*NSQ = 1,371,168 f -> ends 5,143,968

  // sim / knn branch
  k_copynorm<<<NBATCH * NNODE, 256, 0, stream>>>(hid, out, w_norm);
  k_sim<<<dim3(32, NBATCH), 256, 0, stream>>>(hid, w_simp);
  k_simc<<<(NBATCH * NSQ + 255) / 256, 256, 0, stream>>>(w_simp, w_norm, w_sim);
  k_topk<<<NBATCH, 1024, 0, stream>>>(w_sim, out);

  // conv -> fc -> edge branch
  k_c1stats<<<188, 256, 0, stream>>>(nf, c1w, c1b, w_p1);
  k_red1<<<1, 64, 0, stream>>>(w_p1, g1, b1, w_foldd);
  k_c2stats<<<dim3(24, NNODE), 256, 0, stream>>>(nf, c1w, c1b, c2w, c2b, w_foldd, w_p2);
  k_red2<<<1, 256, 0, stream>>>(w_p2, g2, b2, w_foldd);
  k_gemm<<<dim3(NKS, 4), 512, 0, stream>>>(nf, c1w, c1b, c2w, c2b, w_foldd, fcw, w_part);
  k_bn3<<<EMBD, 256, 0, stream>>>(w_part, fcb, g3, b3, w_xd);
  k_pspr<<<NNODE, 128, 0, stream>>>(w_xd, wout, w_psdT, w_prd);
  k_edge<<<(NSQ + 255) / 256, 256, 0, stream>>>(w_psdT, w_prd, bout, wc, cbb, w_bd, out);
  k_samp<<<(NBATCH * NSQ + 255) / 256, 256, 0, stream>>>(w_bd, out);
}

// Round 14
// 2291.718 us; speedup vs baseline: 4.7950x; 1.1165x over previous
//
#include <hip/hip_runtime.h>
#include <stdint.h>
#include <math.h>

#define NBATCH 16
#define NNODE 207
#define TLEN 23990
#define EMBD 100
#define L1LEN 23981   // T-9
#define L2LEN 23972   // T-18
#define DIMFC 383552  // 16*L2
#define DMEAN 16128   // P*D
#define NSQ 42849     // N*N
#define KSEL 2070     // K*N
#define BNEPS 1e-5f
#define NKS 125       // split-K chunks for k_gemm (l-chunk 192 = 24*8)
#define KQ 4032       // k_sim split-K quarter

// output offsets (floats)
#define O_HID  1371168ull
#define O_KNN  54787104ull
#define O_SAMP 55472688ull

__device__ __forceinline__ float waveReduce(float v) {
#pragma unroll
  for (int o = 32; o > 0; o >>= 1) v += __shfl_down(v, o);
  return v;
}

__device__ __forceinline__ double waveReduceD(double v) {
#pragma unroll
  for (int o = 32; o > 0; o >>= 1) v += __shfl_down(v, o);
  return v;
}

__device__ __forceinline__ unsigned int sortableKey(float f) {
  unsigned int u = __float_as_uint(f);
  return (u & 0x80000000u) ? ~u : (u | 0x80000000u);
}

// JAX threefry2x32-20 with key (0, 42)
__device__ __forceinline__ void threefry(uint32_t x0, uint32_t x1, uint32_t& o0, uint32_t& o1) {
  const uint32_t k0 = 0u, k1 = 42u;
  const uint32_t k2 = k0 ^ k1 ^ 0x1BD11BDAu;
  x0 += k0; x1 += k1;
#define TFR(r) { x0 += x1; x1 = (x1 << r) | (x1 >> (32 - r)); x1 ^= x0; }
  TFR(13) TFR(15) TFR(26) TFR(6)   x0 += k1; x1 += k2 + 1u;
  TFR(17) TFR(29) TFR(16) TFR(24)  x0 += k2; x1 += k0 + 2u;
  TFR(13) TFR(15) TFR(26) TFR(6)   x0 += k0; x1 += k1 + 3u;
  TFR(17) TFR(29) TFR(16) TFR(24)  x0 += k1; x1 += k2 + 4u;
  TFR(13) TFR(15) TFR(26) TFR(6)   x0 += k2; x1 += k0 + 5u;
#undef TFR
  o0 = x0; o1 = x1;
}

// jax_threefry_partitionable bit stream: element i -> threefry(key,(0,i)), XOR-fold.
__device__ __forceinline__ float uniform_part(uint32_t m) {
  uint32_t o0, o1;
  threefry(0u, m, o0, o1);
  uint32_t bits = o0 ^ o1;
  return __uint_as_float((bits >> 9) | 0x3f800000u) - 1.0f;
}

// ---------------- K9: copy hidden -> out, row sumsq -> norms ----------------
__global__ __launch_bounds__(256) void k_copynorm(const float* __restrict__ h,
                                                  float* __restrict__ out,
                                                  float* __restrict__ norms) {
  const size_t row = blockIdx.x; // 0..3311
  const float4* src = reinterpret_cast<const float4*>(h + row * (size_t)DMEAN);
  float4* dst = reinterpret_cast<float4*>(out + O_HID + row * (size_t)DMEAN);
  float s = 0.f;
  for (int i = threadIdx.x; i < DMEAN / 4; i += 256) {
    float4 v = src[i];
    dst[i] = v;
    s += v.x * v.x + v.y * v.y + v.z * v.z + v.w * v.w;
  }
  __shared__ float red[4];
  float w = waveReduce(s);
  if ((threadIdx.x & 63) == 0) red[threadIdx.x >> 6] = w;
  __syncthreads();
  if (threadIdx.x == 0) norms[row] = sqrtf(red[0] + red[1] + red[2] + red[3]);
}

// ---------------- K10: sim partials = h @ h^T (triangular tiles, mirror write, K/4 split) ----------------
__global__ __launch_bounds__(256) void k_sim(const float* __restrict__ h,
                                             float* __restrict__ simp) {
  const int b = blockIdx.y;
  const int pid = blockIdx.x % 10;    // triangular tile pair
  const int ksq = blockIdx.x / 10;    // 0..3 k-quarter
  const int ti = (pid < 4) ? 0 : (pid < 7) ? 1 : (pid < 9) ? 2 : 3;
  const int tj = pid - ((ti == 0) ? 0 : (ti == 1) ? 3 : (ti == 2) ? 5 : 6);
  __shared__ float sB[32][64];
  const int tx = threadIdx.x & 15, ty = threadIdx.x >> 4;
  const float* hb = h + (size_t)b * NNODE * DMEAN;
  const int r0 = ti * 64 + ty * 4;
  const float* ap0 = hb + (size_t)min(r0 + 0, NNODE - 1) * DMEAN;
  const float* ap1 = hb + (size_t)min(r0 + 1, NNODE - 1) * DMEAN;
  const float* ap2 = hb + (size_t)min(r0 + 2, NNODE - 1) * DMEAN;
  const float* ap3 = hb + (size_t)min(r0 + 3, NNODE - 1) * DMEAN;
  const int scol = threadIdx.x >> 2;       // staging col 0..63
  const int sk = (threadIdx.x & 3) * 8;    // staging k offset
  const bool bvalid = (tj * 64 + scol) < NNODE;
  const float* bp = hb + (size_t)min(tj * 64 + scol, NNODE - 1) * DMEAN;
  float acc[4][4];
#pragma unroll
  for (int p = 0; p < 4; p++)
#pragma unroll
    for (int q = 0; q < 4; q++) acc[p][q] = 0.f;
  const int kbeg = ksq * KQ;
  const int kend = kbeg + KQ;
  for (int k0 = kbeg; k0 < kend; k0 += 32) {
    __syncthreads();
    {
      float4 v1 = make_float4(0.f, 0.f, 0.f, 0.f), v2 = v1;
      if (bvalid) {
        v1 = *reinterpret_cast<const float4*>(bp + k0 + sk);
        v2 = *reinterpret_cast<const float4*>(bp + k0 + sk + 4);
      }
      sB[sk + 0][scol] = v1.x;
      sB[sk + 1][scol] = v1.y;
      sB[sk + 2][scol] = v1.z;
      sB[sk + 3][scol] = v1.w;
      sB[sk + 4][scol] = v2.x;
      sB[sk + 5][scol] = v2.y;
      sB[sk + 6][scol] = v2.z;
      sB[sk + 7][scol] = v2.w;
    }
    __syncthreads();
#pragma unroll
    for (int g = 0; g < 8; g++) {
      const int kk = k0 + g * 4;
      const float4 a0 = *reinterpret_cast<const float4*>(ap0 + kk);
      const float4 a1 = *reinterpret_cast<const float4*>(ap1 + kk);
      const float4 a2 = *reinterpret_cast<const float4*>(ap2 + kk);
      const float4 a3 = *reinterpret_cast<const float4*>(ap3 + kk);
      const float4 b0 = *reinterpret_cast<const float4*>(&sB[g * 4 + 0][tx * 4]);
      const float4 b1 = *reinterpret_cast<const float4*>(&sB[g * 4 + 1][tx * 4]);
      const float4 b2 = *reinterpret_cast<const float4*>(&sB[g * 4 + 2][tx * 4]);
      const float4 b3 = *reinterpret_cast<const float4*>(&sB[g * 4 + 3][tx * 4]);
      // s = 0 (k = kk)
      acc[0][0] = fmaf(a0.x, b0.x, acc[0][0]); acc[0][1] = fmaf(a0.x, b0.y, acc[0][1]);
      acc[0][2] = fmaf(a0.x, b0.z, acc[0][2]); acc[0][3] = fmaf(a0.x, b0.w, acc[0][3]);
      acc[1][0] = fmaf(a1.x, b0.x, acc[1][0]); acc[1][1] = fmaf(a1.x, b0.y, acc[1][1]);
      acc[1][2] = fmaf(a1.x, b0.z, acc[1][2]); acc[1][3] = fmaf(a1.x, b0.w, acc[1][3]);
      acc[2][0] = fmaf(a2.x, b0.x, acc[2][0]); acc[2][1] = fmaf(a2.x, b0.y, acc[2][1]);
      acc[2][2] = fmaf(a2.x, b0.z, acc[2][2]); acc[2][3] = fmaf(a2.x, b0.w, acc[2][3]);
      acc[3][0] = fmaf(a3.x, b0.x, acc[3][0]); acc[3][1] = fmaf(a3.x, b0.y, acc[3][1]);
      acc[3][2] = fmaf(a3.x, b0.z, acc[3][2]); acc[3][3] = fmaf(a3.x, b0.w, acc[3][3]);
      // s = 1
      acc[0][0] = fmaf(a0.y, b1.x, acc[0][0]); acc[0][1] = fmaf(a0.y, b1.y, acc[0][1]);
      acc[0][2] = fmaf(a0.y, b1.z, acc[0][2]); acc[0][3] = fmaf(a0.y, b1.w, acc[0][3]);
      acc[1][0] = fmaf(a1.y, b1.x, acc[1][0]); acc[1][1] = fmaf(a1.y, b1.y, acc[1][1]);
      acc[1][2] = fmaf(a1.y, b1.z, acc[1][2]); acc[1][3] = fmaf(a1.y, b1.w, acc[1][3]);
      acc[2][0] = fmaf(a2.y, b1.x, acc[2][0]); acc[2][1] = fmaf(a2.y, b1.y, acc[2][1]);
      acc[2][2] = fmaf(a2.y, b1.z, acc[2][2]); acc[2][3] = fmaf(a2.y, b1.w, acc[2][3]);
      acc[3][0] = fmaf(a3.y, b1.x, acc[3][0]); acc[3][1] = fmaf(a3.y, b1.y, acc[3][1]);
      acc[3][2] = fmaf(a3.y, b1.z, acc[3][2]); acc[3][3] = fmaf(a3.y, b1.w, acc[3][3]);
      // s = 2
      acc[0][0] = fmaf(a0.z, b2.x, acc[0][0]); acc[0][1] = fmaf(a0.z, b2.y, acc[0][1]);
      acc[0][2] = fmaf(a0.z, b2.z, acc[0][2]); acc[0][3] = fmaf(a0.z, b2.w, acc[0][3]);
      acc[1][0] = fmaf(a1.z, b2.x, acc[1][0]); acc[1][1] = fmaf(a1.z, b2.y, acc[1][1]);
      acc[1][2] = fmaf(a1.z, b2.z, acc[1][2]); acc[1][3] = fmaf(a1.z, b2.w, acc[1][3]);
      acc[2][0] = fmaf(a2.z, b2.x, acc[2][0]); acc[2][1] = fmaf(a2.z, b2.y, acc[2][1]);
      acc[2][2] = fmaf(a2.z, b2.z, acc[2][2]); acc[2][3] = fmaf(a2.z, b2.w, acc[2][3]);
      acc[3][0] = fmaf(a3.z, b2.x, acc[3][0]); acc[3][1] = fmaf(a3.z, b2.y, acc[3][1]);
      acc[3][2] = fmaf(a3.z, b2.z, acc[3][2]); acc[3][3] = fmaf(a3.z, b2.w, acc[3][3]);
      // s = 3
      acc[0][0] = fmaf(a0.w, b3.x, acc[0][0]); acc[0][1] = fmaf(a0.w, b3.y, acc[0][1]);
      acc[0][2] = fmaf(a0.w, b3.z, acc[0][2]); acc[0][3] = fmaf(a0.w, b3.w, acc[0][3]);
      acc[1][0] = fmaf(a1.w, b3.x, acc[1][0]); acc[1][1] = fmaf(a1.w, b3.y, acc[1][1]);
      acc[1][2] = fmaf(a1.w, b3.z, acc[1][2]); acc[1][3] = fmaf(a1.w, b3.w, acc[1][3]);
      acc[2][0] = fmaf(a2.w, b3.x, acc[2][0]); acc[2][1] = fmaf(a2.w, b3.y, acc[2][1]);
      acc[2][2] = fmaf(a2.w, b3.z, acc[2][2]); acc[2][3] = fmaf(a2.w, b3.w, acc[2][3]);
      acc[3][0] = fmaf(a3.w, b3.x, acc[3][0]); acc[3][1] = fmaf(a3.w, b3.y, acc[3][1]);
      acc[3][2] = fmaf(a3.w, b3.z, acc[3][2]); acc[3][3] = fmaf(a3.w, b3.w, acc[3][3]);
    }
  }
  float* op = simp + ((size_t)ksq * NBATCH + b) * NSQ;
#pragma unroll
  for (int p = 0; p < 4; p++) {
    int ii = r0 + p;
    if (ii < NNODE) {
#pragma unroll
      for (int q = 0; q < 4; q++) {
        int jj = tj * 64 + tx * 4 + q;
        if (jj < NNODE) {
          op[ii * NNODE + jj] = acc[p][q];
          if (ti != tj) op[jj * NNODE + ii] = acc[p][q];  // exact mirror
        }
      }
    }
  }
}

// ---------------- K10b: combine quarters + normalize: sim = sum(p)/(d_i*d_j) ----------------
__global__ __launch_bounds__(256) void k_simc(const float* __restrict__ simp,
                                              const float* __restrict__ norms,
                                              float* __restrict__ sim) {
  const int gid = blockIdx.x * 256 + threadIdx.x;
  if (gid >= NBATCH * NSQ) return;
  const int b = gid / NSQ;
  const int rem = gid - b * NSQ;
  const int i = rem / NNODE, j = rem - i * NNODE;
  const size_t stride = (size_t)NBATCH * NSQ;
  float s = ((simp[gid] + simp[stride + gid]) + simp[2 * stride + gid]) + simp[3 * stride + gid];
  float di = norms[b * NNODE + i] + 1e-10f;
  float dj = norms[b * NNODE + j] + 1e-10f;
  sim[gid] = s / (di * dj);
}

// ---------------- K11: exact top-k (radix select, per-wave histograms), 1024 thr ----------------
__global__ __launch_bounds__(1024) void k_topk(const float* __restrict__ sim,
                                               float* __restrict__ out) {
  const int b = blockIdx.x;
  const float* s = sim + (size_t)b * NSQ;
  float* knn = out + O_KNN + (size_t)b * NSQ;
  __shared__ unsigned int hist16[16 * 257];  // per-wave rows, padded (bank-rotated)
  __shared__ unsigned int hist[256];
  __shared__ unsigned int cnts[1024];
  __shared__ unsigned int tsum[16];
  __shared__ unsigned int sh_prefix, sh_kneed;
  const int wid = threadIdx.x >> 6;
  if (threadIdx.x == 0) { sh_prefix = 0u; sh_kneed = KSEL; }
  __syncthreads();
  const int lo = threadIdx.x * 42;
  const int hi = min(lo + 42, NSQ);
  for (int pass = 0; pass < 4; pass++) {
    const int shift = 24 - pass * 8;
    for (int i = threadIdx.x; i < 16 * 257; i += 1024) hist16[i] = 0u;
    __syncthreads();
    unsigned int pref = sh_prefix;
    unsigned int hmask = (pass == 0) ? 0u : (0xFFFFFFFFu << (shift + 8));
    for (int i = lo; i < hi; i++) {
      unsigned int key = sortableKey(s[i]);
      if ((key & hmask) == pref) atomicAdd(&hist16[wid * 257 + ((key >> shift) & 255)], 1u);
    }
    __syncthreads();
    if (threadIdx.x < 256) {
      unsigned int t = 0;
      for (int w = 0; w < 16; w++) t += hist16[w * 257 + threadIdx.x];
      hist[threadIdx.x] = t;
    }
    __syncthreads();
    if (threadIdx.x == 0) {
      unsigned int need = sh_kneed, cum = 0;
      for (int bkt = 255; bkt >= 0; bkt--) {
        unsigned int c = hist[bkt];
        if (cum + c >= need) {
          sh_prefix = pref | ((unsigned int)bkt << shift);
          sh_kneed = need - cum;
          break;
        }
        cum += c;
      }
    }
    __syncthreads();
  }
  const unsigned int kth = sh_prefix;
  const unsigned int need_eq = sh_kneed;
  unsigned int myeq = 0;
  for (int i = lo; i < hi; i++) {
    float v = s[i];
    unsigned int key = sortableKey(v);
    float o = 0.f;
    if (key > kth) {
      int ii = i / NNODE, jj = i - ii * NNODE;
      o = (v != 0.f && ii != jj) ? 1.f : 0.f;
    } else if (key == kth) {
      myeq++;
    }
    knn[i] = o;
  }
  cnts[threadIdx.x] = myeq;
  __syncthreads();
  // 3-phase exclusive scan over 1024 in index order
  if (threadIdx.x < 16) {
    unsigned int run = 0;
    for (int k = 0; k < 64; k++) {
      unsigned int c = cnts[threadIdx.x * 64 + k];
      cnts[threadIdx.x * 64 + k] = run;
      run += c;
    }
    tsum[threadIdx.x] = run;
  }
  __syncthreads();
  if (threadIdx.x == 0) {
    unsigned int run = 0;
    for (int w = 0; w < 16; w++) { unsigned int c = tsum[w]; tsum[w] = run; run += c; }
  }
  __syncthreads();
  unsigned int rank = cnts[threadIdx.x] + tsum[wid >> 2 == 0 ? threadIdx.x >> 6 : threadIdx.x >> 6];
  for (int i = lo; i < hi && rank < need_eq; i++) {
    float v = s[i];
    if (sortableKey(v) == kth) {
      if (rank < need_eq) {
        int ii = i / NNODE, jj = i - ii * NNODE;
        knn[i] = (v != 0.f && ii != jj) ? 1.f : 0.f;
      }
      rank++;
    }
  }
}

// ---------------- K1: conv1+relu stats partials ----------------
__global__ __launch_bounds__(256) void k_c1stats(const float* __restrict__ nf,
                                                 const float* __restrict__ c1w,
                                                 const float* __restrict__ c1b,
                                                 float* __restrict__ part1) {
  __shared__ float sw[80], sb[8];
  if (threadIdx.x < 80) sw[threadIdx.x] = c1w[threadIdx.x];
  if (threadIdx.x < 8) sb[threadIdx.x] = c1b[threadIdx.x];
  __syncthreads();
  const int t0 = blockIdx.x * 128;
  const int cnt = min(128, L1LEN - t0);
  float s[8], sq[8];
#pragma unroll
  for (int c = 0; c < 8; c++) { s[c] = 0.f; sq[c] = 0.f; }
  for (int idx = threadIdx.x; idx < cnt * NNODE; idx += 256) {
    int tl = idx / NNODE;
    int n = idx - tl * NNODE;
    const float* p = nf + (size_t)(t0 + tl) * NNODE + n;
    float in[10];
#pragma unroll
    for (int k = 0; k < 10; k++) in[k] = p[k * NNODE];
#pragma unroll
    for (int c = 0; c < 8; c++) {
      float a = sb[c];
#pragma unroll
      for (int k = 0; k < 10; k++) a = fmaf(sw[c * 10 + k], in[k], a);
      a = fmaxf(a, 0.f);
      s[c] += a;
      sq[c] = fmaf(a, a, sq[c]);
    }
  }
  __shared__ float red[4][16];
  int lane = threadIdx.x & 63, wv = threadIdx.x >> 6;
#pragma unroll
  for (int c = 0; c < 8; c++) {
    float a = waveReduce(s[c]);
    float q = waveReduce(sq[c]);
    if (lane == 0) { red[wv][c * 2] = a; red[wv][c * 2 + 1] = q; }
  }
  __syncthreads();
  if (threadIdx.x < 16)
    part1[blockIdx.x * 16 + threadIdx.x] =
        red[0][threadIdx.x] + red[1][threadIdx.x] + red[2][threadIdx.x] + red[3][threadIdx.x];
}

// ---------------- K2: reduce bn1 stats (f64) -> a1/be1 doubles ----------------
__global__ void k_red1(const float* __restrict__ part1, const float* __restrict__ g1,
                       const float* __restrict__ b1, double* __restrict__ foldd) {
  __shared__ double sums[16];
  if (threadIdx.x < 16) {
    double s = 0.0;
    for (int i = 0; i < 188; i++) s += (double)part1[i * 16 + threadIdx.x];
    sums[threadIdx.x] = s;
  }
  __syncthreads();
  if (threadIdx.x < 8) {
    const double cnt = 207.0 * 23981.0;
    int c = threadIdx.x;
    double m = sums[c * 2] / cnt;
    double ex2 = sums[c * 2 + 1] / cnt;
    double var = ex2 - m * m;
    double sc = (double)g1[c] / sqrt(var + (double)BNEPS);
    foldd[c] = sc;            // a1
    foldd[8 + c] = (double)b1[c] - m * sc;  // be1
  }
}

// ---------------- K3: conv2+relu stats partials ----------------
__global__ __launch_bounds__(256) void k_c2stats(const float* __restrict__ nf,
                                                 const float* __restrict__ c1w,
                                                 const float* __restrict__ c1b,
                                                 const float* __restrict__ c2w,
                                                 const float* __restrict__ c2b,
                                                 const double* __restrict__ foldd,
                                                 float* __restrict__ part2) {
  const int n = blockIdx.y;
  const int l0 = blockIdx.x * 1024;
  const int len = min(1024, L2LEN - l0);
  __shared__ float s_nf[1042];
  __shared__ float s_o1[8][1034];
  __shared__ float s_w2t[1280];
  __shared__ float s_b2[16];
  __shared__ float s_c1w[80], s_c1b[8];
  __shared__ float s_a1[8], s_be1[8];
  for (int i = threadIdx.x; i < 1280; i += 256) {
    int co = i / 80, r = i - co * 80;
    s_w2t[r * 16 + co] = c2w[i];
  }
  if (threadIdx.x < 16) s_b2[threadIdx.x] = c2b[threadIdx.x];
  if (threadIdx.x < 80) s_c1w[threadIdx.x] = c1w[threadIdx.x];
  if (threadIdx.x < 8) {
    s_c1b[threadIdx.x] = c1b[threadIdx.x];
    s_a1[threadIdx.x] = (float)foldd[threadIdx.x];
    s_be1[threadIdx.x] = (float)foldd[8 + threadIdx.x];
  }
  __syncthreads();
  const int nfl = len + 18;
  for (int i = threadIdx.x; i < nfl; i += 256) s_nf[i] = nf[(size_t)(l0 + i) * NNODE + n];
  __syncthreads();
  const int o1l = len + 9;
  for (int i = threadIdx.x; i < 8 * o1l; i += 256) {
    int c = i / o1l, t = i - c * o1l;
    float a = s_c1b[c];
#pragma unroll
    for (int k = 0; k < 10; k++) a = fmaf(s_c1w[c * 10 + k], s_nf[t + k], a);
    s_o1[c][t] = fmaxf(a, 0.f) * s_a1[c] + s_be1[c];
  }
  __syncthreads();
  const int co = threadIdx.x & 15, lg = threadIdx.x >> 4;
  float sum = 0.f, ssq = 0.f;
  for (int pass = 0; pass < 4; pass++) {
    int lb = pass * 256 + lg * 16;
    if (lb >= len) continue;
    int nl = min(16, len - lb);
    float y[16];
#pragma unroll
    for (int l = 0; l < 16; l++) y[l] = s_b2[co];
#pragma unroll
    for (int ci = 0; ci < 8; ci++) {
      float win[25];
#pragma unroll
      for (int w = 0; w < 25; w++) win[w] = s_o1[ci][lb + w];
#pragma unroll
      for (int k = 0; k < 10; k++) {
        float wv = s_w2t[(ci * 10 + k) * 16 + co];
#pragma unroll
        for (int l = 0; l < 16; l++) y[l] = fmaf(wv, win[l + k], y[l]);
      }
    }
#pragma unroll
    for (int l = 0; l < 16; l++) {
      if (l < nl) {
        float v = fmaxf(y[l], 0.f);
        sum += v;
        ssq = fmaf(v, v, ssq);
      }
    }
  }
  __shared__ float rs[16][16], rq[16][16];
  rs[lg][co] = sum;
  rq[lg][co] = ssq;
  __syncthreads();
  if (threadIdx.x < 16) {
    float a = 0.f, q = 0.f;
    for (int g = 0; g < 16; g++) { a += rs[g][threadIdx.x]; q += rq[g][threadIdx.x]; }
    int blk = blockIdx.y * gridDim.x + blockIdx.x;
    part2[blk * 32 + threadIdx.x * 2] = a;
    part2[blk * 32 + threadIdx.x * 2 + 1] = q;
  }
}

// ---------------- K4: reduce bn2 stats (f64) -> s2/t2 doubles ----------------
__global__ void k_red2(const float* __restrict__ part2, const float* __restrict__ g2,
                       const float* __restrict__ b2, double* __restrict__ foldd) {
  __shared__ double acc8[8][32];
  const int grp = threadIdx.x >> 5, v = threadIdx.x & 31;
  double s = 0.0;
  for (int i = grp; i < 4968; i += 8) s += (double)part2[i * 32 + v];
  acc8[grp][v] = s;
  __syncthreads();
  if (threadIdx.x < 32) {
    double t = 0.0;
    for (int g = 0; g < 8; g++) t += acc8[g][threadIdx.x];
    acc8[0][threadIdx.x] = t;
  }
  __syncthreads();
  if (threadIdx.x < 16) {
    const double cnt = 207.0 * 23972.0;
    int c = threadIdx.x;
    double m = acc8[0][c * 2] / cnt;
    double ex2 = acc8[0][c * 2 + 1] / cnt;
    double var = ex2 - m * m;
    double sc = (double)g2[c] / sqrt(var + (double)BNEPS);
    foldd[16 + c] = sc;                       // s2
    foldd[32 + c] = (double)b2[c] - m * sc;   // t2
  }
}

// ---------------- K5: fused conv1->conv2->bn2->fc GEMM (fc 7x4 tiles, exact-n coverage) ----------------
__global__ __launch_bounds__(512, 2) void k_gemm(const float* __restrict__ nf,
                                                 const float* __restrict__ c1w,
                                                 const float* __restrict__ c1b,
                                                 const float* __restrict__ c2w,
                                                 const float* __restrict__ c2b,
                                                 const double* __restrict__ foldd,
                                                 const float* __restrict__ fcw,
                                                 float* __restrict__ part) {
  const int ks = blockIdx.x;  // 0..124 l-chunk of 192
  const int nt = blockIdx.y;  // 0..3  n-tile of 52
  const int l0 = ks * 192;
  const int n0 = nt * 52;

  __shared__ float s_nf[26][52];
  __shared__ float s_o1[8][17][52];   // bn1-applied conv1 (f32)
  __shared__ float s_x2[16][8][64];   // bn2-applied conv2 (f32)
  __shared__ float s_wT[2][112][10];  // fc weights [buf][e][kk]
  __shared__ float s_w2t[1280];
  __shared__ float s_c1w[80], s_c1b[8], s_c2b[16];
  __shared__ float s_a1f[8], s_be1f[8], s_s2f[16], s_t2f[16];

  for (int i = threadIdx.x; i < 1280; i += 512) {
    int co = i / 80, r = i - co * 80;
    s_w2t[r * 16 + co] = c2w[i];
  }
  if (threadIdx.x < 80) s_c1w[threadIdx.x] = c1w[threadIdx.x];
  if (threadIdx.x < 8) {
    s_c1b[threadIdx.x] = c1b[threadIdx.x];
    s_a1f[threadIdx.x] = (float)foldd[threadIdx.x];
    s_be1f[threadIdx.x] = (float)foldd[8 + threadIdx.x];
  }
  if (threadIdx.x < 16) {
    s_c2b[threadIdx.x] = c2b[threadIdx.x];
    s_s2f[threadIdx.x] = (float)foldd[16 + threadIdx.x];
    s_t2f[threadIdx.x] = (float)foldd[32 + threadIdx.x];
  }

  double acc[7][4];  // e = te+16m, n = tn4*4+q (fc-active threads only; static indexing)
#pragma unroll
  for (int m = 0; m < 7; m++)
#pragma unroll
    for (int q = 0; q < 4; q++) acc[m][q] = 0.0;

  const int te = threadIdx.x & 15;        // fc e-lane
  const int tn4 = threadIdx.x >> 4;       // fc n-group (valid < 13)
  const bool fc_act = threadIdx.x < 208;  // 16 te x 13 tn4
  const int nl = threadIdx.x & 63;        // conv2 node lane
  const int c0 = (threadIdx.x >> 6) & 7;  // conv2 co base
  const bool doload = threadIdx.x < 448;  // fc staging lanes
  const int e_ld = threadIdx.x >> 2;      // 0..111
  const int k2 = (threadIdx.x & 3) * 2;   // 0,2,4,6

  for (int ls = 0; ls < 24; ls++) {
    const int lb = l0 + ls * 8;
    if (lb >= L2LEN) break;
    const bool lfull = (lb + 8 <= L2LEN);
    for (int i = threadIdx.x; i < 26 * 52; i += 512) {
      int r = i / 52, cc = i - r * 52;
      int t = lb + r, n = n0 + cc;
      float v = 0.f;
      if (t < TLEN && n < NNODE) v = nf[(size_t)t * NNODE + n];
      s_nf[r][cc] = v;
    }
    __syncthreads();
    // conv1 + bn1 (f32)
    for (int i = threadIdx.x; i < 8 * 17 * 52; i += 512) {
      int c = i / (17 * 52);
      int rem = i - c * 17 * 52;
      int t = rem / 52, n = rem - t * 52;
      float a = s_c1b[c];
#pragma unroll
      for (int k = 0; k < 10; k++) a = fmaf(s_c1w[c * 10 + k], s_nf[t + k][n], a);
      s_o1[c][t][n] = fmaxf(a, 0.f) * s_a1f[c] + s_be1f[c];
    }
    __syncthreads();
    // conv2 + relu + bn2 (f32, named scalars, shared 17-wide window)
    {
      const bool valid = (nl < 52) && (n0 + nl < NNODE);
      if (valid) {
        const float bA = s_c2b[c0], bB = s_c2b[c0 + 8];
        float y00 = bA, y01 = bA, y02 = bA, y03 = bA;
        float y10 = bA, y11 = bA, y12 = bA, y13 = bA;
        float y20 = bB, y21 = bB, y22 = bB, y23 = bB;
        float y30 = bB, y31 = bB, y32 = bB, y33 = bB;
        for (int ci = 0; ci < 8; ci++) {
          float ww0 = s_o1[ci][0][nl],  ww1 = s_o1[ci][1][nl],  ww2 = s_o1[ci][2][nl];
          float ww3 = s_o1[ci][3][nl],  ww4 = s_o1[ci][4][nl],  ww5 = s_o1[ci][5][nl];
          float ww6 = s_o1[ci][6][nl],  ww7 = s_o1[ci][7][nl],  ww8 = s_o1[ci][8][nl];
          float ww9 = s_o1[ci][9][nl],  wwa = s_o1[ci][10][nl], wwb = s_o1[ci][11][nl];
          float wwc = s_o1[ci][12][nl], wwd = s_o1[ci][13][nl], wwe = s_o1[ci][14][nl];
          float wwf = s_o1[ci][15][nl], wwg = s_o1[ci][16][nl];
          const float* wpA = &s_w2t[ci * 160 + c0];
          const float* wpB = wpA + 8;
          float v, u;
#define C2STEP(K, A0, A1, A2, A3, B0, B1, B2, B3)                                   \
          v = wpA[(K) * 16]; u = wpB[(K) * 16];                                     \
          y00 = fmaf(v, A0, y00); y01 = fmaf(v, A1, y01);                           \
          y02 = fmaf(v, A2, y02); y03 = fmaf(v, A3, y03);                           \
          y10 = fmaf(v, B0, y10); y11 = fmaf(v, B1, y11);                           \
          y12 = fmaf(v, B2, y12); y13 = fmaf(v, B3, y13);                           \
          y20 = fmaf(u, A0, y20); y21 = fmaf(u, A1, y21);                           \
          y22 = fmaf(u, A2, y22); y23 = fmaf(u, A3, y23);                           \
          y30 = fmaf(u, B0, y30); y31 = fmaf(u, B1, y31);                           \
          y32 = fmaf(u, B2, y32); y33 = fmaf(u, B3, y33);
          C2STEP(0, ww0, ww1, ww2, ww3, ww4, ww5, ww6, ww7)
          C2STEP(1, ww1, ww2, ww3, ww4, ww5, ww6, ww7, ww8)
          C2STEP(2, ww2, ww3, ww4, ww5, ww6, ww7, ww8, ww9)
          C2STEP(3, ww3, ww4, ww5, ww6, ww7, ww8, ww9, wwa)
          C2STEP(4, ww4, ww5, ww6, ww7, ww8, ww9, wwa, wwb)
          C2STEP(5, ww5, ww6, ww7, ww8, ww9, wwa, wwb, wwc)
          C2STEP(6, ww6, ww7, ww8, ww9, wwa, wwb, wwc, wwd)
          C2STEP(7, ww7, ww8, ww9, wwa, wwb, wwc, wwd, wwe)
          C2STEP(8, ww8, ww9, wwa, wwb, wwc, wwd, wwe, wwf)
          C2STEP(9, ww9, wwa, wwb, wwc, wwd, wwe, wwf, wwg)
#undef C2STEP
        }
        const float scA = s_s2f[c0], tbA = s_t2f[c0];
        const float scB = s_s2f[c0 + 8], tbB = s_t2f[c0 + 8];
        s_x2[c0][0][nl] = (lb + 0 < L2LEN) ? fmaf(fmaxf(y00, 0.f), scA, tbA) : 0.f;
        s_x2[c0][1][nl] = (lb + 1 < L2LEN) ? fmaf(fmaxf(y01, 0.f), scA, tbA) : 0.f;
        s_x2[c0][2][nl] = (lb + 2 < L2LEN) ? fmaf(fmaxf(y02, 0.f), scA, tbA) : 0.f;
        s_x2[c0][3][nl] = (lb + 3 < L2LEN) ? fmaf(fmaxf(y03, 0.f), scA, tbA) : 0.f;
        s_x2[c0][4][nl] = (lb + 4 < L2LEN) ? fmaf(fmaxf(y10, 0.f), scA, tbA) : 0.f;
        s_x2[c0][5][nl] = (lb + 5 < L2LEN) ? fmaf(fmaxf(y11, 0.f), scA, tbA) : 0.f;
        s_x2[c0][6][nl] = (lb + 6 < L2LEN) ? fmaf(fmaxf(y12, 0.f), scA, tbA) : 0.f;
        s_x2[c0][7][nl] = (lb + 7 < L2LEN) ? fmaf(fmaxf(y13, 0.f), scA, tbA) : 0.f;
        s_x2[c0 + 8][0][nl] = (lb + 0 < L2LEN) ? fmaf(fmaxf(y20, 0.f), scB, tbB) : 0.f;
        s_x2[c0 + 8][1][nl] = (lb + 1 < L2LEN) ? fmaf(fmaxf(y21, 0.f), scB, tbB) : 0.f;
        s_x2[c0 + 8][2][nl] = (lb + 2 < L2LEN) ? fmaf(fmaxf(y22, 0.f), scB, tbB) : 0.f;
        s_x2[c0 + 8][3][nl] = (lb + 3 < L2LEN) ? fmaf(fmaxf(y23, 0.f), scB, tbB) : 0.f;
        s_x2[c0 + 8][4][nl] = (lb + 4 < L2LEN) ? fmaf(fmaxf(y30, 0.f), scB, tbB) : 0.f;
        s_x2[c0 + 8][5][nl] = (lb + 5 < L2LEN) ? fmaf(fmaxf(y31, 0.f), scB, tbB) : 0.f;
        s_x2[c0 + 8][6][nl] = (lb + 6 < L2LEN) ? fmaf(fmaxf(y32, 0.f), scB, tbB) : 0.f;
        s_x2[c0 + 8][7][nl] = (lb + 7 < L2LEN) ? fmaf(fmaxf(y33, 0.f), scB, tbB) : 0.f;
      } else {
#pragma unroll
        for (int l = 0; l < 8; l++) {
          s_x2[c0][l][nl] = 0.f;
          s_x2[c0 + 8][l][nl] = 0.f;
        }
      }
    }
    // prologue: load fc weights for c=0 (overlaps conv2 barrier)
    float2 wld = make_float2(0.f, 0.f);
    if (doload && e_ld < EMBD) {
      const float* fp = fcw + (size_t)e_ld * DIMFC + lb + k2;  // c = 0
      if (lfull) wld = *reinterpret_cast<const float2*>(fp);
      else {
        wld.x = (lb + k2 < L2LEN) ? fp[0] : 0.f;
        wld.y = (lb + k2 + 1 < L2LEN) ? fp[1] : 0.f;
      }
    }
    __syncthreads();  // s_x2 visible
    if (doload) *reinterpret_cast<float2*>(&s_wT[0][e_ld][k2]) = wld;
    // fc c-loop: 1 barrier per c, next-c weights prefetched during compute
    for (int c = 0; c < 16; c++) {
      __syncthreads();  // s_wT[c&1] ready; prev readers of s_wT[(c+1)&1] done
      float2 wnext = make_float2(0.f, 0.f);
      if (c < 15 && doload && e_ld < EMBD) {
        const float* fp = fcw + (size_t)e_ld * DIMFC + (size_t)(c + 1) * L2LEN + lb + k2;
        if (lfull) wnext = *reinterpret_cast<const float2*>(fp);
        else {
          wnext.x = (lb + k2 < L2LEN) ? fp[0] : 0.f;
          wnext.y = (lb + k2 + 1 < L2LEN) ? fp[1] : 0.f;
        }
      }
      if (fc_act) {
        const int bsel = c & 1;
        const float4 xv0 = *reinterpret_cast<const float4*>(&s_x2[c][0][tn4 * 4]);
        const float4 xv1 = *reinterpret_cast<const float4*>(&s_x2[c][1][tn4 * 4]);
        const float4 xv2 = *reinterpret_cast<const float4*>(&s_x2[c][2][tn4 * 4]);
        const float4 xv3 = *reinterpret_cast<const float4*>(&s_x2[c][3][tn4 * 4]);
        const float4 xv4 = *reinterpret_cast<const float4*>(&s_x2[c][4][tn4 * 4]);
        const float4 xv5 = *reinterpret_cast<const float4*>(&s_x2[c][5][tn4 * 4]);
        const float4 xv6 = *reinterpret_cast<const float4*>(&s_x2[c][6][tn4 * 4]);
        const float4 xv7 = *reinterpret_cast<const float4*>(&s_x2[c][7][tn4 * 4]);
#pragma unroll
        for (int m = 0; m < 7; m++) {
          const float* wp = &s_wT[bsel][te + 16 * m][0];
          const float2 wv01 = *reinterpret_cast<const float2*>(&wp[0]);
          const float2 wv23 = *reinterpret_cast<const float2*>(&wp[2]);
          const float2 wv45 = *reinterpret_cast<const float2*>(&wp[4]);
          const float2 wv67 = *reinterpret_cast<const float2*>(&wp[6]);
          float a0 = 0.f, a1 = 0.f, a2 = 0.f, a3 = 0.f;
          a0 = fmaf(wv01.x, xv0.x, a0); a1 = fmaf(wv01.x, xv0.y, a1);
          a2 = fmaf(wv01.x, xv0.z, a2); a3 = fmaf(wv01.x, xv0.w, a3);
          a0 = fmaf(wv01.y, xv1.x, a0); a1 = fmaf(wv01.y, xv1.y, a1);
          a2 = fmaf(wv01.y, xv1.z, a2); a3 = fmaf(wv01.y, xv1.w, a3);
          a0 = fmaf(wv23.x, xv2.x, a0); a1 = fmaf(wv23.x, xv2.y, a1);
          a2 = fmaf(wv23.x, xv2.z, a2); a3 = fmaf(wv23.x, xv2.w, a3);
          a0 = fmaf(wv23.y, xv3.x, a0); a1 = fmaf(wv23.y, xv3.y, a1);
          a2 = fmaf(wv23.y, xv3.z, a2); a3 = fmaf(wv23.y, xv3.w, a3);
          a0 = fmaf(wv45.x, xv4.x, a0); a1 = fmaf(wv45.x, xv4.y, a1);
          a2 = fmaf(wv45.x, xv4.z, a2); a3 = fmaf(wv45.x, xv4.w, a3);
          a0 = fmaf(wv45.y, xv5.x, a0); a1 = fmaf(wv45.y, xv5.y, a1);
          a2 = fmaf(wv45.y, xv5.z, a2); a3 = fmaf(wv45.y, xv5.w, a3);
          a0 = fmaf(wv67.x, xv6.x, a0); a1 = fmaf(wv67.x, xv6.y, a1);
          a2 = fmaf(wv67.x, xv6.z, a2); a3 = fmaf(wv67.x, xv6.w, a3);
          a0 = fmaf(wv67.y, xv7.x, a0); a1 = fmaf(wv67.y, xv7.y, a1);
          a2 = fmaf(wv67.y, xv7.z, a2); a3 = fmaf(wv67.y, xv7.w, a3);
          acc[m][0] += (double)a0;
          acc[m][1] += (double)a1;
          acc[m][2] += (double)a2;
          acc[m][3] += (double)a3;
        }
      }
      if (c < 15 && doload)
        *reinterpret_cast<float2*>(&s_wT[(c + 1) & 1][e_ld][k2]) = wnext;
    }
  }
  if (fc_act) {
    for (int m = 0; m < 7; m++) {
      int e = te + 16 * m;
      if (e < EMBD) {
        for (int q = 0; q < 4; q++) {
          int nl2 = tn4 * 4 + q;
          part[(((size_t)ks * 4 + nt) * 100 + e) * 52 + nl2] = (float)acc[m][q];
        }
      }
    }
  }
}

// ---------------- K6: reduce split-K (f64), +bias, relu, bn3 -> x (f64) ----------------
__global__ __launch_bounds__(256) void k_bn3(const float* __restrict__ part,
                                             const float* __restrict__ fcb,
                                             const float* __restrict__ g3,
                                             const float* __restrict__ b3,
                                             double* __restrict__ xd) {
  const int e = blockIdx.x;
  const int n = threadIdx.x;
  double v = 0.0;
  if (n < NNODE) {
    int nt = n / 52, nl = n - nt * 52;
    const size_t stride = 4 * 100 * 52;
    const float* p = part + ((size_t)nt * 100 + e) * 52 + nl;
    for (int ks = 0; ks < NKS; ks++) v += (double)p[ks * stride];
    v = fmax(v + (double)fcb[e], 0.0);
  }
  __shared__ double redA[4], redB[4];
  __shared__ double s_m, s_sd;
  int lane = threadIdx.x & 63, wid = threadIdx.x >> 6;
  double w = waveReduceD(v);
  if (lane == 0) redA[wid] = w;
  __syncthreads();
  if (threadIdx.x == 0) s_m = (redA[0] + redA[1] + redA[2] + redA[3]) / 207.0;
  __syncthreads();
  double m = s_m;
  double d = (n < NNODE) ? (v - m) : 0.0;
  double wq = waveReduceD(d * d);
  if (lane == 0) redB[wid] = wq;
  __syncthreads();
  if (threadIdx.x == 0) s_sd = sqrt((redB[0] + redB[1] + redB[2] + redB[3]) / 207.0 + (double)BNEPS);
  __syncthreads();
  if (n < NNODE) xd[n * 100 + e] = (v - m) / s_sd * (double)g3[e] + (double)b3[e];
}

// ---------------- K7: ps = x@Ws^T (stored transposed [e][n]), pr = x@Wr^T (f64) ----------------
__global__ void k_pspr(const double* __restrict__ xd, const float* __restrict__ wout,
                       double* __restrict__ psdT, double* __restrict__ prd) {
  const int n = blockIdx.x;
  __shared__ double sx[100];
  if (threadIdx.x < 100) sx[threadIdx.x] = xd[n * 100 + threadIdx.x];
  __syncthreads();
  const int e = threadIdx.x;
  if (e < 100) {
    double a = 0.0, b = 0.0;
    for (int j = 0; j < 100; j++) {
      double xv = sx[j];
      a = fma(xv, (double)wout[e * 200 + j], a);
      b = fma(xv, (double)wout[e * 200 + 100 + j], b);
    }
    psdT[e * NNODE + n] = a;   // transposed for coalesced k_edge reads
    prd[n * 100 + e] = b;
  }
}

// ---------------- K8a: edge logits b0/b1 per pij (f64) + bern output ----------------
__global__ __launch_bounds__(256) void k_edge(const double* __restrict__ psdT,
                                              const double* __restrict__ prd,
                                              const float* __restrict__ bo,
                                              const float* __restrict__ wc,
                                              const float* __restrict__ cb,
                                              double* __restrict__ bd,
                                              float* __restrict__ out) {
  const int pij = blockIdx.x * 256 + threadIdx.x;
  if (pij >= NSQ) return;
  const int i = pij / NNODE, j = pij - i * NNODE;
  const double* pri = prd + i * 100;
  double b0 = 0.0, b1 = 0.0;
  for (int e = 0; e < 100; e++) {
    double ed = fmax(pri[e] + psdT[e * NNODE + j] + (double)bo[e], 0.0);
    b0 = fma(ed, (double)wc[e], b0);
    b1 = fma(ed, (double)wc[100 + e], b1);
  }
  b0 += (double)cb[0];
  b1 += (double)cb[1];
  bd[pij * 2] = b0;
  bd[pij * 2 + 1] = b1;
  const float b0f = (float)b0, b1f = (float)b1;
  for (int b = 0; b < NBATCH; b++) {
    size_t base = (size_t)b * (2 * NSQ) + (size_t)pij * 2;
    out[base] = b0f;
    out[base + 1] = b1f;
  }
}

// ---------------- K8b: gumbel sample per (b,pij) ----------------
__global__ __launch_bounds__(256) void k_samp(const double* __restrict__ bd,
                                              float* __restrict__ out) {
  const int gid = blockIdx.x * 256 + threadIdx.x;
  if (gid >= NBATCH * NSQ) return;
  const int b = gid / NSQ;
  const int pij = gid - b * NSQ;
  const int i = pij / NNODE, j = pij - i * NNODE;
  const double b0 = bd[pij * 2], b1 = bd[pij * 2 + 1];
  uint32_t base = (uint32_t)b * (2u * NSQ) + (uint32_t)pij * 2u;
  float u0 = uniform_part(base);
  float u1 = uniform_part(base + 1u);
  double g0 = -log(-log((double)u0 + 1e-20) + 1e-20);
  double g1 = -log(-log((double)u1 + 1e-20) + 1e-20);
  float v = ((b0 + g0) >= (b1 + g1)) ? 1.0f : 0.0f;
  if (i == j) v = 0.f;
  out[O_SAMP + (size_t)b * NSQ + pij] = v;
}

extern "C" void kernel_launch(void* const* d_in, const int* in_sizes, int n_in,
                              void* d_out, int out_size, void* d_ws, size_t ws_size,
                              hipStream_t stream) {
  const float* hid = (const float*)d_in[0];
  const float* nf = (const float*)d_in[1];
  const float* c1w = (const float*)d_in[2];
  const float* c1b = (const float*)d_in[3];
  const float* c2w = (const float*)d_in[4];
  const float* c2b = (const float*)d_in[5];
  const float* g1 = (const float*)d_in[6];
  const float* b1 = (const float*)d_in[7];
  const float* g2 = (const float*)d_in[8];
  const float* b2 = (const float*)d_in[9];
  const float* fcw = (const float*)d_in[10];
  const float* fcb = (const float*)d_in[11];
  const float* g3 = (const float*)d_in[12];
  const float* b3 = (const float*)d_in[13];
  // d_in[14], d_in[15]: fc_mean_w / fc_mean_b are dead code in the reference
  const float* wout = (const float*)d_in[16];
  const float* bout = (const float*)d_in[17];
  const float* wc = (const float*)d_in[18];
  const float* cbb = (const float*)d_in[19];
  float* out = (float*)d_out;
  float* ws = (float*)d_ws;

  float* w_norm = ws + 0;                       // 3312 f
  float* w_sim = ws + 8192;                     // 685584 f -> ends 693,776
  float* w_p1 = ws + 704512;                    // 3008 f
  float* w_p2 = ws + 712704;                    // 158976 f (dead after k_red2)
  double* w_bd = (double*)(ws + 712704);        // 85698 d (reuses w_p2 region)
  double* w_foldd = (double*)(ws + 900096);     // 48 d
  float* w_simp = ws + 1048576;                 // 4*16*NSQ = 2,742,336 f (dead after k_simc)
  float* w_part = ws + 1048576;                 // 2,600,000 f (aliases simp; temporally disjoint)
  double* w_xd = (double*)(ws + 3791000);       // 20700 d -> ends 3,832,400
  double* w_psdT = (double*)(ws + 3832400);     // 20700 d -> ends 3,873,800
  double* w_prd = (double*)(ws + 3873800);      // 20700 d -> ends 3,915,200 (~15.7 MB)

  // sim / knn branch
  k_copynorm<<<NBATCH * NNODE, 256, 0, stream>>>(hid, out, w_norm);
  k_sim<<<dim3(40, NBATCH), 256, 0, stream>>>(hid, w_simp);
  k_simc<<<(NBATCH * NSQ + 255) / 256, 256, 0, stream>>>(w_simp, w_norm, w_sim);
  k_topk<<<NBATCH, 1024, 0, stream>>>(w_sim, out);

  // conv -> fc -> edge branch
  k_c1stats<<<188, 256, 0, stream>>>(nf, c1w, c1b, w_p1);
  k_red1<<<1, 64, 0, stream>>>(w_p1, g1, b1, w_foldd);
  k_c2stats<<<dim3(24, NNODE), 256, 0, stream>>>(nf, c1w, c1b, c2w, c2b, w_foldd, w_p2);
  k_red2<<<1, 256, 0, stream>>>(w_p2, g2, b2, w_foldd);
  k_gemm<<<dim3(NKS, 4), 512, 0, stream>>>(nf, c1w, c1b, c2w, c2b, w_foldd, fcw, w_part);
  k_bn3<<<EMBD, 256, 0, stream>>>(w_part, fcb, g3, b3, w_xd);
  k_pspr<<<NNODE, 128, 0, stream>>>(w_xd, wout, w_psdT, w_prd);
  k_edge<<<(NSQ + 255) / 256, 256, 0, stream>>>(w_psdT, w_prd, bout, wc, cbb, w_bd, out);
  k_samp<<<(NBATCH * NSQ + 255) / 256, 256, 0, stream>>>(w_bd, out);
}